// Round 5
// baseline (333.028 us; speedup 1.0000x reference)
//
#include <hip/hip_runtime.h>
#include <math.h>

constexpr int kB  = 16;
constexpr int kS  = 256;
constexpr int kD  = 1024;
constexpr int kH  = 16;
constexpr float kScale = 0.125f;  // 1/sqrt(64)

using bf16x8  = __attribute__((ext_vector_type(8))) short;
using bf16x4  = __attribute__((ext_vector_type(4))) short;
using floatx4 = __attribute__((ext_vector_type(4))) float;
typedef unsigned short u16;

__device__ __forceinline__ u16 f2bf(float x) {
  union { float f; unsigned u; } v; v.f = x;
  unsigned r = v.u + 0x7fffu + ((v.u >> 16) & 1u);
  return (u16)(r >> 16);
}
__device__ __forceinline__ float bf2f(u16 h) {
  union { unsigned u; float f; } v; v.u = ((unsigned)h) << 16;
  return v.f;
}

#define MFMA16(a, b, c) __builtin_amdgcn_mfma_f32_16x16x32_bf16((a), (b), (c), 0, 0, 0)
#define GLL16(gp, lp)                                                        \
  __builtin_amdgcn_global_load_lds(                                          \
      (const __attribute__((address_space(1))) unsigned int*)(gp),           \
      (__attribute__((address_space(3))) unsigned int*)(lp), 16, 0, 0)

// ---------------- pack + table: xA=[x;table], W3=[Wq;Wv;Wk], Wo, b3 ----------
__global__ __launch_bounds__(256) void pack_k(
    const float* __restrict__ x, const float* __restrict__ Wq,
    const float* __restrict__ Wk, const float* __restrict__ Wv,
    const float* __restrict__ Wo,
    const float* __restrict__ bq, const float* __restrict__ bk,
    const float* __restrict__ bv,
    u16* __restrict__ xA, u16* __restrict__ W3b, u16* __restrict__ Wob,
    float* __restrict__ b3) {
  size_t i = ((size_t)blockIdx.x * 256 + threadIdx.x) * 4;
  const size_t NX = (size_t)4194304, NW = (size_t)1048576;
  const size_t BEND = NX + 4 * NW + 3072;
  const float* src;
  u16* dst;
  size_t o;
  if (i < NX) {
    src = x; dst = xA; o = i;
  } else if (i < NX + 3 * NW) {
    size_t j = i - NX;
    int sel = (int)(j >> 20);
    o = j & (NW - 1);
    src = sel == 0 ? Wq : sel == 1 ? Wv : Wk;
    dst = W3b + (size_t)sel * NW;
  } else if (i < NX + 4 * NW) {
    o = i - NX - 3 * NW;
    src = Wo; dst = Wob;
  } else if (i < BEND) {
    size_t j = i - NX - 4 * NW;
    int sel = (int)(j >> 10);
    o = j & 1023;
    src = sel == 0 ? bq : sel == 1 ? bv : bk;
    *reinterpret_cast<float4*>(b3 + j) = *reinterpret_cast<const float4*>(src + o);
    return;
  } else if (i < BEND + 262144) {
    // sinusoid table rows p in [0,256), pos = p-255 -> xA rows 4096..4351
    size_t j = i - BEND;
    int p = (int)(j >> 10);
    int ibase = (int)(j & 1023);
    ushort4 r;
    u16* rr = (u16*)&r;
#pragma unroll
    for (int c = 0; c < 4; ++c) {
      int idx = ibase + c;
      float ex = (float)(2 * (idx / 2)) * (1.0f / 1024.0f);
      float scale = exp2f(ex * -13.287712379549449f);  // 10000^-ex
      float angle = (float)(p - 255) * scale;
      rr[c] = f2bf((idx & 1) ? cosf(angle) : sinf(angle));
    }
    *reinterpret_cast<ushort4*>(xA + NX + j) = r;
    return;
  } else {
    return;
  }
  float4 v = *reinterpret_cast<const float4*>(src + o);
  ushort4 r;
  r.x = f2bf(v.x); r.y = f2bf(v.y); r.z = f2bf(v.z); r.w = f2bf(v.w);
  *reinterpret_cast<ushort4*>(dst + o) = r;
}

// ---------------- rank-16 fold of Wr with u/v: W3b rows 3072..3103, b3 tail ------
__global__ __launch_bounds__(256) void uv_fold_k(
    const float* __restrict__ Wr, const float* __restrict__ br,
    const float* __restrict__ ub, const float* __restrict__ vb,
    u16* __restrict__ W3b, float* __restrict__ b3) {
  int gid = blockIdx.x * 256 + threadIdx.x;  // 32768
  int j = gid >> 10, c = gid & 1023;
  int h = j & 15;
  const float* bvec = (j < 16 ? ub : vb) + h * 64;
  const float* wcol = Wr + (size_t)(h * 64) * 1024 + c;
  float a = 0.f;
#pragma unroll
  for (int d = 0; d < 64; ++d) a += bvec[d] * wcol[(size_t)d * 1024];
  W3b[(size_t)(3072 + j) * 1024 + c] = f2bf(a);
  if (gid < 128) {
    float s = 0.f;
    if (gid < 32) {
      const float* bv2 = (gid < 16 ? ub : vb) + (gid & 15) * 64;
      const float* brp = br + (gid & 15) * 64;
      for (int d = 0; d < 64; ++d) s += bv2[d] * brp[d];
    }
    b3[3072 + gid] = s;
  }
}

// ---------------- legacy 128x128 bf16 MFMA GEMM (used for out-proj) ----------
template <int OUT_MODE>
__global__ __launch_bounds__(256) void gemm_k(
    const u16* __restrict__ A, const u16* __restrict__ W,
    const float* __restrict__ bias, void* __restrict__ Cv,
    int M, int N, int K, float* __restrict__ utb, float* __restrict__ dtb,
    int mTiles, int nTiles) {
  const int xcd = blockIdx.x & 7;
  const int li  = blockIdx.x >> 3;
  const int r0   = (xcd * mTiles) >> 3;
  const int rcnt = (((xcd + 1) * mTiles) >> 3) - r0;
  if (li >= rcnt * nTiles) return;   // uniform early-out (padded grid)
  const int bm = (r0 + li % rcnt) * 128;
  const int bn = (li / rcnt) * 128;

  __shared__ u16 Alds[128 * 64];
  __shared__ u16 Blds[128 * 64];
  const int t = threadIdx.x, w = t >> 6, l = t & 63;
  const int l15 = l & 15, quad = l >> 4;
  const int wm = w >> 1, wn = w & 1;
  const int lrow8 = l >> 3;
  const int kslot = l & 7;

  floatx4 acc[4][4] = {};

  for (int k0 = 0; k0 < K; k0 += 64) {
#pragma unroll
    for (int sg = 0; sg < 4; ++sg) {
      int mrow = sg * 32 + w * 8 + lrow8;
      int gk = (kslot ^ (mrow & 7)) << 3;
      GLL16(A + (size_t)(bm + mrow) * K + k0 + gk, Alds + (sg * 32 + w * 8) * 64);
      GLL16(W + (size_t)(bn + mrow) * K + k0 + gk, Blds + (sg * 32 + w * 8) * 64);
    }
    __syncthreads();
#pragma unroll
    for (int c = 0; c < 2; ++c) {
      bf16x8 af[4], bf[4];
#pragma unroll
      for (int mi = 0; mi < 4; ++mi) {
        int am = wm * 64 + mi * 16 + l15;
        af[mi] = *(const bf16x8*)(Alds + am * 64 + (((c * 4 + quad) ^ (am & 7)) << 3));
      }
#pragma unroll
      for (int ni = 0; ni < 4; ++ni) {
        int an = wn * 64 + ni * 16 + l15;
        bf[ni] = *(const bf16x8*)(Blds + an * 64 + (((c * 4 + quad) ^ (an & 7)) << 3));
      }
#pragma unroll
      for (int mi = 0; mi < 4; ++mi)
#pragma unroll
        for (int ni = 0; ni < 4; ++ni)
          acc[mi][ni] = MFMA16(af[mi], bf[ni], acc[mi][ni]);
    }
    __syncthreads();
  }

#pragma unroll
  for (int ni = 0; ni < 4; ++ni) {
    int col = bn + wn * 64 + ni * 16 + l15;
    float bv = bias[col];
#pragma unroll
    for (int mi = 0; mi < 4; ++mi) {
      int mrow = bm + wm * 64 + mi * 16 + quad * 4;
#pragma unroll
      for (int r = 0; r < 4; ++r) {
        float v = acc[mi][ni][r] + bv;
        int row = mrow + r;
        if (OUT_MODE == 0) {
          ((float*)Cv)[(size_t)row * N + col] = v;
        }
      }
    }
  }
}

// ---------------- 256x256 8-phase bf16 MFMA GEMM (T2+T3+T4+T5) ----------------
// (unchanged from round 4 — verified at <58.5 us)
#define PHASE_MFMA(aa, bb, mh, nh, LG)                                         \
  do {                                                                         \
    __builtin_amdgcn_s_barrier();                                              \
    asm volatile("s_waitcnt lgkmcnt(" #LG ")" ::: "memory");                   \
    __builtin_amdgcn_sched_barrier(0);                                         \
    __builtin_amdgcn_s_setprio(1);                                             \
    _Pragma("unroll") for (int kc = 0; kc < 2; ++kc)                           \
        _Pragma("unroll") for (int i = 0; i < 4; ++i)                          \
            _Pragma("unroll") for (int j = 0; j < 2; ++j)                      \
                acc[(mh) * 4 + i][(nh) * 2 + j] = MFMA16(                      \
                    aa[kc][i], bb[kc][j], acc[(mh) * 4 + i][(nh) * 2 + j]);    \
    __builtin_amdgcn_s_setprio(0);                                             \
  } while (0)

__global__ __launch_bounds__(512, 2) void gemm256_k(
    const u16* __restrict__ A, const u16* __restrict__ W,
    const float* __restrict__ bias, u16* __restrict__ Cv,
    int K, float* __restrict__ utb, float* __restrict__ dtb,
    int mTiles, int nTiles) {
  const int nwg = mTiles * nTiles;
  const int qq = nwg >> 3, rr8 = nwg & 7;
  const int xcd = blockIdx.x & 7;
  const int wgid = (xcd < rr8 ? xcd * (qq + 1) : rr8 * (qq + 1) + (xcd - rr8) * qq)
                   + (blockIdx.x >> 3);
  const int bm = (wgid / nTiles) * 256;
  const int bn = (wgid % nTiles) * 256;

  __shared__ u16 lds[2 * 32768];     // 128 KiB: [buf][A 256x64 | B 256x64]

  const int t = threadIdx.x, w = t >> 6, l = t & 63;
  const int l15 = l & 15, quad = l >> 4;
  const int wm = w >> 2, wn = w & 3;

  const int NT = K >> 6;
  floatx4 acc[8][4] = {};

  auto stage = [&](int kt, int h) {
    const u16* srcm = (h < 2) ? A : W;
    const int baser = ((h < 2) ? bm : bn) + (h & 1) * 128;
    u16* dst = lds + (kt & 1) * 32768 + h * 8192 + w * 512;
    const int k0 = kt << 6;
#pragma unroll
    for (int j = 0; j < 2; ++j) {
      int sub = w * 8 + (l >> 3) + j * 64;
      int gk = ((l & 7) ^ (sub & 7)) << 3;
      GLL16(srcm + (size_t)(baser + sub) * K + k0 + gk, dst + j * 4096);
    }
  };

  bf16x8 a0[2][4], a1[2][4], b0[2][2], b1[2][2];

  auto readA = [&](bf16x8 (&aa)[2][4], const u16* LA, int hh) {
#pragma unroll
    for (int i = 0; i < 4; ++i) {
      int am = wm * 128 + hh * 64 + i * 16 + l15;
      const u16* p = LA + am * 64;
      aa[0][i] = *(const bf16x8*)(p + ((quad ^ (am & 7)) << 3));
      aa[1][i] = *(const bf16x8*)(p + (((4 + quad) ^ (am & 7)) << 3));
    }
  };
  auto readB = [&](bf16x8 (&bb)[2][2], const u16* LB, int hh) {
#pragma unroll
    for (int j = 0; j < 2; ++j) {
      int an = wn * 64 + hh * 32 + j * 16 + l15;
      const u16* p = LB + an * 64;
      bb[0][j] = *(const bf16x8*)(p + ((quad ^ (an & 7)) << 3));
      bb[1][j] = *(const bf16x8*)(p + (((4 + quad) ^ (an & 7)) << 3));
    }
  };

  stage(0, 2); stage(0, 3); stage(0, 0); stage(0, 1);
  stage(1, 2); stage(1, 3); stage(1, 0);
  asm volatile("s_waitcnt vmcnt(6)" ::: "memory");
  __builtin_amdgcn_s_barrier();
  readA(a0, lds, 0);
  readB(b0, lds + 16384, 0);

  for (int kt = 0; kt < NT; ++kt) {
    const u16* LA = lds + (kt & 1) * 32768;
    const u16* LB = LA + 16384;

    readB(b1, LB, 1);
    if (kt + 1 < NT) stage(kt + 1, 1);
    PHASE_MFMA(a0, b0, 0, 0, 4);
    __builtin_amdgcn_s_barrier();

    readA(a1, LA, 1);
    PHASE_MFMA(a0, b1, 0, 1, 8);
    __builtin_amdgcn_s_barrier();

    if (kt + 2 < NT) stage(kt + 2, 2);
    PHASE_MFMA(a1, b0, 1, 0, 0);
    __builtin_amdgcn_s_barrier();

    if (kt + 2 < NT) {
      stage(kt + 2, 3); stage(kt + 2, 0);
      asm volatile("s_waitcnt vmcnt(6)" ::: "memory");
    } else {
      asm volatile("s_waitcnt vmcnt(0)" ::: "memory");
    }
    __builtin_amdgcn_s_barrier();
    asm volatile("s_waitcnt lgkmcnt(0)" ::: "memory");
    __builtin_amdgcn_sched_barrier(0);
    if (kt + 1 < NT) {
      const u16* LAn = lds + ((kt + 1) & 1) * 32768;
      readA(a0, LAn, 0);
      readB(b0, LAn + 16384, 0);
    }
    __builtin_amdgcn_s_setprio(1);
#pragma unroll
    for (int kc = 0; kc < 2; ++kc)
#pragma unroll
      for (int i = 0; i < 4; ++i)
#pragma unroll
        for (int j = 0; j < 2; ++j)
          acc[4 + i][2 + j] = MFMA16(a1[kc][i], b1[kc][j], acc[4 + i][2 + j]);
    __builtin_amdgcn_s_setprio(0);
    __builtin_amdgcn_s_barrier();
  }

  // ---- epilogue: fp32 LDS bounce -> coalesced stores ----
  float* fl = (float*)lds;   // 128 x 256 fp32 = 128 KiB
#pragma unroll 1
  for (int half = 0; half < 2; ++half) {
    __syncthreads();
    if (wm == half) {
#pragma unroll
      for (int ni = 0; ni < 4; ++ni) {
        float bv = bias[bn + wn * 64 + ni * 16 + l15];
#pragma unroll
        for (int mi = 0; mi < 8; ++mi) {
#pragma unroll
          for (int r = 0; r < 4; ++r) {
            int lr = mi * 16 + quad * 4 + r;
            int c  = wn * 64 + ni * 16 + l15;
            int key = ((r ^ quad) & 3) << 4;
            fl[lr * 256 + (c ^ key)] = acc[mi][ni][r] + bv;
          }
        }
      }
    }
    __syncthreads();
#pragma unroll 1
    for (int cc = 0; cc < 4; ++cc) {
      int col0 = bn + cc * 64;
#pragma unroll
      for (int rr = 0; rr < 4; ++rr) {
        int lr = w * 16 + rr * 4 + quad;
        int key = ((rr ^ quad) & 3) << 4;
        float4 v = *(const float4*)&fl[lr * 256 + ((cc * 64 + (l15 << 2)) ^ key)];
        int grow = bm + half * 128 + lr;
        if (col0 < 3072) {
          ushort4 hv;
          hv.x = f2bf(v.x); hv.y = f2bf(v.y); hv.z = f2bf(v.z); hv.w = f2bf(v.w);
          int matsel = col0 >> 10;
          int hh2 = (col0 >> 6) & 15;
          if (grow < 4096) {
            int bb = grow >> 8, ss = grow & 255;
            *(ushort4*)(Cv + (size_t)matsel * 4194304 +
                        ((size_t)(((bb << 4) + hh2) << 8) + ss) * 64 + (l15 << 2)) = hv;
          } else if (matsel == 2) {
            int pp = grow - 4096;
            *(ushort4*)(Cv + (size_t)3 * 4194304 +
                        ((size_t)((hh2 << 8) + pp)) * 64 + (l15 << 2)) = hv;
          }
        } else if (col0 < 3104) {
#pragma unroll
          for (int e = 0; e < 4; ++e) {
            int col = col0 + (l15 << 2) + e;
            float vv = e == 0 ? v.x : e == 1 ? v.y : e == 2 ? v.z : v.w;
            if (col < 3088) {
              if (grow < 4096)
                utb[((grow >> 8) * 16 + (col - 3072)) * 256 + (grow & 255)] = vv;
            } else if (col < 3104) {
              if (grow >= 4096)
                dtb[(col - 3088) * 256 + (grow - 4096)] = vv;
            }
          }
        }
      }
    }
  }
}

// ---------------- fused attention v2: one block per (b,h) ----------------
// Per s-tile, 3 pipelined phases:
//   P1: PV(st-1) (reads Pl/Rinv from prev phase3) ∥ QK(st) (writes Sc)
//   P2: QR(st): global RPKh (2-stage prefetch), fused += into Sc at
//       z = 16j + l15 + 4*quad + r - 15 (guard z>=0; coverage of [0,s]
//       exactly-once verified algebraically)
//   P3: softmax(st): paired-z (b64 Sc reads), writes bf16 P pairs -> Pl, Rinv
// Strides chosen for zero/minimal bank conflict:
//   Sc[32][266] f32: QK/QR writes 2-way, softmax b64 reads uniform-min
//   Pl[32][268] u16: PV b64 reads perfectly uniform, packed u32 writes 2-way
//   softmax rows = w + 8*(l>>4) (groups spaced 8 rows)
__global__ __launch_bounds__(512, 2) void attn_k(
    const u16* __restrict__ Qh, const u16* __restrict__ Kh,
    const u16* __restrict__ Vh, const u16* __restrict__ RPKh,
    const float* __restrict__ ut, const float* __restrict__ dt,
    u16* __restrict__ vw) {
  __shared__ u16 Klds[256 * 64];              // 32 KB, XOR-swizzled rows
  __shared__ u16 Vt[64][280];                 // 35 KB, V transposed
  __shared__ __align__(16) float Sc[32][266]; // 34 KB fused scores
  __shared__ __align__(16) u16 Pl[32][268];   // 16.8 KB bf16 P
  __shared__ float Ut[256], Dt[256], Rinv[32];

  const int bh = blockIdx.x;         // b*16 + h
  const int h = bh & 15;
  const int b = bh >> 4;
  const size_t bh256 = (size_t)bh << 8;

  const int t = threadIdx.x, w = t >> 6, l = t & 63;
  const int l15 = l & 15, quad = l >> 4;

  // ---- staging: K (GLL16), V^T (LDS transpose), Ut, Dt ----
  {
    const int lrow8 = l >> 3, kslot = l & 7;
#pragma unroll
    for (int i = 0; i < 4; ++i) {
      int row = w * 32 + i * 8 + lrow8;
      int gk = (kslot ^ (row & 7)) << 3;
      GLL16(Kh + (bh256 + row) * 64 + gk, Klds + (w * 32 + i * 8) * 64);
    }
  }
  {
    int z = t & 255, dh = t >> 8;    // dh: 0..1 (wave-uniform)
    const u16* gp = Vh + (bh256 + z) * 64 + dh * 32;
    ushort4 vv[8];
#pragma unroll
    for (int i = 0; i < 8; ++i) vv[i] = *(const ushort4*)(gp + i * 4);
#pragma unroll
    for (int i = 0; i < 8; ++i) {
      Vt[dh * 32 + i * 4 + 0][z] = vv[i].x;
      Vt[dh * 32 + i * 4 + 1][z] = vv[i].y;
      Vt[dh * 32 + i * 4 + 2][z] = vv[i].z;
      Vt[dh * 32 + i * 4 + 3][z] = vv[i].w;
    }
  }
  if (t < 256) Ut[t] = ut[bh256 + t];
  else         Dt[t - 256] = dt[((size_t)h << 8) + (t - 256)];
  __syncthreads();

  bf16x8 qa[2][2];
  const int strip = w >> 2, nt = w & 3;

  // PV helper for tile stp (0..7): reads Pl/Vt/Rinv, stores to vw.
  auto pv_tile = [&](int stp) {
    floatx4 oacc = {};
    for (int kc = 0; kc <= stp; ++kc) {
      const u16* pp = &Pl[strip * 16 + l15][kc * 32 + quad * 8];
      bf16x4 plo = *(const bf16x4*)pp;
      bf16x4 phi = *(const bf16x4*)(pp + 4);
      bf16x8 pa = __builtin_shufflevector(plo, phi, 0, 1, 2, 3, 4, 5, 6, 7);
      bf16x8 vbf = *(const bf16x8*)&Vt[nt * 16 + l15][kc * 32 + quad * 8];
      oacc = MFMA16(pa, vbf, oacc);
    }
#pragma unroll
    for (int r = 0; r < 4; ++r) {
      float ivr = Rinv[strip * 16 + quad * 4 + r];
      int srow = stp * 32 + strip * 16 + quad * 4 + r;
      vw[(size_t)(b * 256 + srow) * 1024 + h * 64 + nt * 16 + l15] =
          f2bf(oacc[r] * ivr);
    }
  };

  for (int st = 0; st < 8; ++st) {
    const int s0 = st * 32;
    const int n0 = 2 * st + 1;       // QK/QR tasks for rt=0
    const int tot = 4 * st + 3;      // total tasks (rt=0 + rt=1)

    // qa for this tile (global; latency hidden under PV below)
#pragma unroll
    for (int rt = 0; rt < 2; ++rt) {
      const u16* qp = Qh + (bh256 + s0 + rt * 16 + l15) * 64 + quad * 8;
      qa[rt][0] = *(const bf16x8*)qp;
      qa[rt][1] = *(const bf16x8*)(qp + 32);
    }

    // ---- phase 1: PV(st-1) ∥ QK(st) ----
    if (st > 0) pv_tile(st - 1);
    for (int i = w; i < tot; i += 8) {
      int rt = (i >= n0) ? 1 : 0;
      int zt = rt ? i - n0 : i;
      const int zr = (zt << 4) + l15;
      const u16* krow = Klds + zr * 64;
      bf16x8 kb0 = *(const bf16x8*)(krow + ((quad ^ (zr & 7)) << 3));
      bf16x8 kb1 = *(const bf16x8*)(krow + (((quad + 4) ^ (zr & 7)) << 3));
      floatx4 acc = {};
      acc = MFMA16(qa[rt][0], kb0, acc);
      acc = MFMA16(qa[rt][1], kb1, acc);
      float u = Ut[zr];
#pragma unroll
      for (int r = 0; r < 4; ++r)
        Sc[rt * 16 + quad * 4 + r][zr] = acc[r] + u;
    }
    __syncthreads();

    // ---- phase 2: QR(st), fused += into Sc (2-stage global prefetch) ----
    {
      int i = w;
      if (i < tot) {
        int rt = (i >= n0) ? 1 : 0, j = rt ? i - n0 : i;
        int pr = 240 - (s0 + rt * 16) + (j << 4) + l15;
        const u16* rp = RPKh + ((size_t)(h << 8) + pr) * 64 + quad * 8;
        bf16x8 rb0 = *(const bf16x8*)rp;
        bf16x8 rb1 = *(const bf16x8*)(rp + 32);
        while (true) {
          int rt_c = rt, j_c = j, pr_c = pr;
          bf16x8 c0 = rb0, c1 = rb1;
          i += 8;
          if (i < tot) {
            rt = (i >= n0) ? 1 : 0; j = rt ? i - n0 : i;
            pr = 240 - (s0 + rt * 16) + (j << 4) + l15;
            const u16* rp2 = RPKh + ((size_t)(h << 8) + pr) * 64 + quad * 8;
            rb0 = *(const bf16x8*)rp2;
            rb1 = *(const bf16x8*)(rp2 + 32);
          }
          floatx4 acc = {};
          acc = MFMA16(qa[rt_c][0], c0, acc);
          acc = MFMA16(qa[rt_c][1], c1, acc);
          float dv = Dt[pr_c];
#pragma unroll
          for (int r = 0; r < 4; ++r) {
            int z = (j_c << 4) + l15 + 4 * quad + r - 15;
            if (z >= 0)
              Sc[rt_c * 16 + 4 * quad + r][z] += acc[r] + dv;
          }
          if (i >= tot) break;
        }
      }
    }
    __syncthreads();

    // ---- phase 3: softmax -> Pl (bf16 pairs), Rinv ----
    {
      const int g = l >> 4;
      const int row = w + 8 * g;     // groups spaced 8 rows (bank-min)
      const int c16 = l & 15;
      const int s = s0 + row;
      const int zfill = 32 * (st + 1);
      float m = -1e30f;
      for (int z0 = 2 * c16; z0 <= s; z0 += 32) {
        float v0 = Sc[row][z0];
        float v1 = Sc[row][z0 + 1];
        m = fmaxf(m, v0);
        if (z0 + 1 <= s) m = fmaxf(m, v1);
      }
      m = fmaxf(m, __shfl_xor(m, 1));
      m = fmaxf(m, __shfl_xor(m, 2));
      m = fmaxf(m, __shfl_xor(m, 4));
      m = fmaxf(m, __shfl_xor(m, 8));
      m *= kScale;
      float sum = 0.f;
      for (int z0 = 2 * c16; z0 < zfill; z0 += 32) {
        float v0 = Sc[row][z0];
        float v1 = Sc[row][z0 + 1];
        float e0 = (z0 <= s) ? __expf(v0 * kScale - m) : 0.f;
        float e1 = (z0 + 1 <= s) ? __expf(v1 * kScale - m) : 0.f;
        sum += e0 + e1;
        unsigned pk = (unsigned)f2bf(e0) | ((unsigned)f2bf(e1) << 16);
        *(unsigned*)&Pl[row][z0] = pk;
      }
      sum += __shfl_xor(sum, 1);
      sum += __shfl_xor(sum, 2);
      sum += __shfl_xor(sum, 4);
      sum += __shfl_xor(sum, 8);
      if (c16 == 0) Rinv[row] = 1.f / sum;
    }
    __syncthreads();
  }

  // ---- epilogue: PV(7) ----
  pv_tile(7);
}

extern "C" void kernel_launch(void* const* d_in, const int* in_sizes, int n_in,
                              void* d_out, int out_size, void* d_ws, size_t ws_size,
                              hipStream_t stream) {
  const float* x  = (const float*)d_in[0];
  const float* Wq = (const float*)d_in[1];
  const float* bq = (const float*)d_in[2];
  const float* Wk = (const float*)d_in[3];
  const float* bk = (const float*)d_in[4];
  const float* Wv = (const float*)d_in[5];
  const float* bv = (const float*)d_in[6];
  const float* Wr = (const float*)d_in[7];
  const float* br = (const float*)d_in[8];
  const float* ub = (const float*)d_in[9];
  const float* vb = (const float*)d_in[10];
  const float* Wo = (const float*)d_in[11];
  const float* bo = (const float*)d_in[12];
  float* out = (float*)d_out;

  char* base = (char*)d_ws;
  size_t off = 0;
  auto alloc = [&](size_t bytes) {
    void* p = base + off;
    off += (bytes + 255) & ~(size_t)255;
    return p;
  };

  const size_t MAT = (size_t)4194304;  // 4096*1024
  u16*   xA    = (u16*)alloc((size_t)4352 * 1024 * 2);       // [x ; table]
  u16*   W3b   = (u16*)alloc((size_t)3328 * 1024 * 2);       // [Wq;Wv;Wk;UV;pad]
  u16*   Wob   = (u16*)alloc((size_t)1024 * 1024 * 2);
  float* b3    = (float*)alloc((size_t)3328 * 4);
  u16*   Ph    = (u16*)alloc((3 * MAT + 262144) * 2);        // Qh,Vh,Kh,RPKh
  float* utb   = (float*)alloc((size_t)65536 * 4);
  float* dtb   = (float*)alloc((size_t)4096 * 4);
  u16*   vwb   = (u16*)alloc((size_t)4096 * 1024 * 2);

  u16* Qh   = Ph;
  u16* Vh   = Ph + MAT;
  u16* Kh   = Ph + 2 * MAT;
  u16* RPKh = Ph + 3 * MAT;

  pack_k<<<dim3(8451), dim3(256), 0, stream>>>(x, Wq, Wk, Wv, Wo, bq, bk, bv,
                                               xA, W3b, Wob, b3);
  uv_fold_k<<<dim3(128), dim3(256), 0, stream>>>(Wr, br, ub, vb, W3b, b3);

  // fused Q|V|K + relpos-K + ut/dt projections: 4352 x 3328(pad) x 1024
  gemm256_k<<<dim3(221), dim3(512), 0, stream>>>(xA, W3b, b3, Ph,
                                                 1024, utb, dtb, 17, 13);

  // fused attention: one block per (b,h)
  attn_k<<<dim3(256), dim3(512), 0, stream>>>(Qh, Kh, Vh, RPKh, utb, dtb, vwb);

  // output projection: 4096 x 1024 x 1024, fp32 out
  gemm_k<0><<<dim3(256), dim3(256), 0, stream>>>(vwb, Wob, bo, out,
                                                 4096, 1024, 1024, nullptr, nullptr,
                                                 32, 8);
}

// Round 6
// 215.427 us; speedup vs baseline: 1.5459x; 1.5459x over previous
//
#include <hip/hip_runtime.h>
#include <math.h>

constexpr int kB  = 16;
constexpr int kS  = 256;
constexpr int kD  = 1024;
constexpr int kH  = 16;
constexpr float kScale = 0.125f;  // 1/sqrt(64)

using bf16x8  = __attribute__((ext_vector_type(8))) short;
using bf16x4  = __attribute__((ext_vector_type(4))) short;
using floatx4 = __attribute__((ext_vector_type(4))) float;
typedef unsigned short u16;

__device__ __forceinline__ u16 f2bf(float x) {
  union { float f; unsigned u; } v; v.f = x;
  unsigned r = v.u + 0x7fffu + ((v.u >> 16) & 1u);
  return (u16)(r >> 16);
}
__device__ __forceinline__ float bf2f(u16 h) {
  union { unsigned u; float f; } v; v.u = ((unsigned)h) << 16;
  return v.f;
}

#define MFMA16(a, b, c) __builtin_amdgcn_mfma_f32_16x16x32_bf16((a), (b), (c), 0, 0, 0)
#define GLL16(gp, lp)                                                        \
  __builtin_amdgcn_global_load_lds(                                          \
      (const __attribute__((address_space(1))) unsigned int*)(gp),           \
      (__attribute__((address_space(3))) unsigned int*)(lp), 16, 0, 0)

// ---------------- pack + table: xA=[x;table], W3=[Wq;Wv;Wk], Wo, b3 ----------
__global__ __launch_bounds__(256) void pack_k(
    const float* __restrict__ x, const float* __restrict__ Wq,
    const float* __restrict__ Wk, const float* __restrict__ Wv,
    const float* __restrict__ Wo,
    const float* __restrict__ bq, const float* __restrict__ bk,
    const float* __restrict__ bv,
    u16* __restrict__ xA, u16* __restrict__ W3b, u16* __restrict__ Wob,
    float* __restrict__ b3) {
  size_t i = ((size_t)blockIdx.x * 256 + threadIdx.x) * 4;
  const size_t NX = (size_t)4194304, NW = (size_t)1048576;
  const size_t BEND = NX + 4 * NW + 3072;
  const float* src;
  u16* dst;
  size_t o;
  if (i < NX) {
    src = x; dst = xA; o = i;
  } else if (i < NX + 3 * NW) {
    size_t j = i - NX;
    int sel = (int)(j >> 20);
    o = j & (NW - 1);
    src = sel == 0 ? Wq : sel == 1 ? Wv : Wk;
    dst = W3b + (size_t)sel * NW;
  } else if (i < NX + 4 * NW) {
    o = i - NX - 3 * NW;
    src = Wo; dst = Wob;
  } else if (i < BEND) {
    size_t j = i - NX - 4 * NW;
    int sel = (int)(j >> 10);
    o = j & 1023;
    src = sel == 0 ? bq : sel == 1 ? bv : bk;
    *reinterpret_cast<float4*>(b3 + j) = *reinterpret_cast<const float4*>(src + o);
    return;
  } else if (i < BEND + 262144) {
    // sinusoid table rows p in [0,256), pos = p-255 -> xA rows 4096..4351
    size_t j = i - BEND;
    int p = (int)(j >> 10);
    int ibase = (int)(j & 1023);
    ushort4 r;
    u16* rr = (u16*)&r;
#pragma unroll
    for (int c = 0; c < 4; ++c) {
      int idx = ibase + c;
      float ex = (float)(2 * (idx / 2)) * (1.0f / 1024.0f);
      float scale = exp2f(ex * -13.287712379549449f);  // 10000^-ex
      float angle = (float)(p - 255) * scale;
      rr[c] = f2bf((idx & 1) ? cosf(angle) : sinf(angle));
    }
    *reinterpret_cast<ushort4*>(xA + NX + j) = r;
    return;
  } else {
    return;
  }
  float4 v = *reinterpret_cast<const float4*>(src + o);
  ushort4 r;
  r.x = f2bf(v.x); r.y = f2bf(v.y); r.z = f2bf(v.z); r.w = f2bf(v.w);
  *reinterpret_cast<ushort4*>(dst + o) = r;
}

// ---------------- rank-16 fold of Wr with u/v: W3b rows 3072..3103, b3 tail ------
__global__ __launch_bounds__(256) void uv_fold_k(
    const float* __restrict__ Wr, const float* __restrict__ br,
    const float* __restrict__ ub, const float* __restrict__ vb,
    u16* __restrict__ W3b, float* __restrict__ b3) {
  int gid = blockIdx.x * 256 + threadIdx.x;  // 32768
  int j = gid >> 10, c = gid & 1023;
  int h = j & 15;
  const float* bvec = (j < 16 ? ub : vb) + h * 64;
  const float* wcol = Wr + (size_t)(h * 64) * 1024 + c;
  float a = 0.f;
#pragma unroll
  for (int d = 0; d < 64; ++d) a += bvec[d] * wcol[(size_t)d * 1024];
  W3b[(size_t)(3072 + j) * 1024 + c] = f2bf(a);
  if (gid < 128) {
    float s = 0.f;
    if (gid < 32) {
      const float* bv2 = (gid < 16 ? ub : vb) + (gid & 15) * 64;
      const float* brp = br + (gid & 15) * 64;
      for (int d = 0; d < 64; ++d) s += bv2[d] * brp[d];
    }
    b3[3072 + gid] = s;
  }
}

// ---------------- legacy 128x128 bf16 MFMA GEMM (used for out-proj) ----------
template <int OUT_MODE>
__global__ __launch_bounds__(256) void gemm_k(
    const u16* __restrict__ A, const u16* __restrict__ W,
    const float* __restrict__ bias, void* __restrict__ Cv,
    int M, int N, int K, float* __restrict__ utb, float* __restrict__ dtb,
    int mTiles, int nTiles) {
  const int xcd = blockIdx.x & 7;
  const int li  = blockIdx.x >> 3;
  const int r0   = (xcd * mTiles) >> 3;
  const int rcnt = (((xcd + 1) * mTiles) >> 3) - r0;
  if (li >= rcnt * nTiles) return;   // uniform early-out (padded grid)
  const int bm = (r0 + li % rcnt) * 128;
  const int bn = (li / rcnt) * 128;

  __shared__ u16 Alds[128 * 64];
  __shared__ u16 Blds[128 * 64];
  const int t = threadIdx.x, w = t >> 6, l = t & 63;
  const int l15 = l & 15, quad = l >> 4;
  const int wm = w >> 1, wn = w & 1;
  const int lrow8 = l >> 3;
  const int kslot = l & 7;

  floatx4 acc[4][4] = {};

  for (int k0 = 0; k0 < K; k0 += 64) {
#pragma unroll
    for (int sg = 0; sg < 4; ++sg) {
      int mrow = sg * 32 + w * 8 + lrow8;
      int gk = (kslot ^ (mrow & 7)) << 3;
      GLL16(A + (size_t)(bm + mrow) * K + k0 + gk, Alds + (sg * 32 + w * 8) * 64);
      GLL16(W + (size_t)(bn + mrow) * K + k0 + gk, Blds + (sg * 32 + w * 8) * 64);
    }
    __syncthreads();
#pragma unroll
    for (int c = 0; c < 2; ++c) {
      bf16x8 af[4], bf[4];
#pragma unroll
      for (int mi = 0; mi < 4; ++mi) {
        int am = wm * 64 + mi * 16 + l15;
        af[mi] = *(const bf16x8*)(Alds + am * 64 + (((c * 4 + quad) ^ (am & 7)) << 3));
      }
#pragma unroll
      for (int ni = 0; ni < 4; ++ni) {
        int an = wn * 64 + ni * 16 + l15;
        bf[ni] = *(const bf16x8*)(Blds + an * 64 + (((c * 4 + quad) ^ (an & 7)) << 3));
      }
#pragma unroll
      for (int mi = 0; mi < 4; ++mi)
#pragma unroll
        for (int ni = 0; ni < 4; ++ni)
          acc[mi][ni] = MFMA16(af[mi], bf[ni], acc[mi][ni]);
    }
    __syncthreads();
  }

#pragma unroll
  for (int ni = 0; ni < 4; ++ni) {
    int col = bn + wn * 64 + ni * 16 + l15;
    float bv = bias[col];
#pragma unroll
    for (int mi = 0; mi < 4; ++mi) {
      int mrow = bm + wm * 64 + mi * 16 + quad * 4;
#pragma unroll
      for (int r = 0; r < 4; ++r) {
        float v = acc[mi][ni][r] + bv;
        int row = mrow + r;
        if (OUT_MODE == 0) {
          ((float*)Cv)[(size_t)row * N + col] = v;
        }
      }
    }
  }
}

// ---------------- 256x256 8-phase bf16 MFMA GEMM (T2+T3+T4+T5) ----------------
// (unchanged — verified at <58.5 us)
#define PHASE_MFMA(aa, bb, mh, nh, LG)                                         \
  do {                                                                         \
    __builtin_amdgcn_s_barrier();                                              \
    asm volatile("s_waitcnt lgkmcnt(" #LG ")" ::: "memory");                   \
    __builtin_amdgcn_sched_barrier(0);                                         \
    __builtin_amdgcn_s_setprio(1);                                             \
    _Pragma("unroll") for (int kc = 0; kc < 2; ++kc)                           \
        _Pragma("unroll") for (int i = 0; i < 4; ++i)                          \
            _Pragma("unroll") for (int j = 0; j < 2; ++j)                      \
                acc[(mh) * 4 + i][(nh) * 2 + j] = MFMA16(                      \
                    aa[kc][i], bb[kc][j], acc[(mh) * 4 + i][(nh) * 2 + j]);    \
    __builtin_amdgcn_s_setprio(0);                                             \
  } while (0)

__global__ __launch_bounds__(512, 2) void gemm256_k(
    const u16* __restrict__ A, const u16* __restrict__ W,
    const float* __restrict__ bias, u16* __restrict__ Cv,
    int K, float* __restrict__ utb, float* __restrict__ dtb,
    int mTiles, int nTiles) {
  const int nwg = mTiles * nTiles;
  const int qq = nwg >> 3, rr8 = nwg & 7;
  const int xcd = blockIdx.x & 7;
  const int wgid = (xcd < rr8 ? xcd * (qq + 1) : rr8 * (qq + 1) + (xcd - rr8) * qq)
                   + (blockIdx.x >> 3);
  const int bm = (wgid / nTiles) * 256;
  const int bn = (wgid % nTiles) * 256;

  __shared__ u16 lds[2 * 32768];     // 128 KiB: [buf][A 256x64 | B 256x64]

  const int t = threadIdx.x, w = t >> 6, l = t & 63;
  const int l15 = l & 15, quad = l >> 4;
  const int wm = w >> 2, wn = w & 3;

  const int NT = K >> 6;
  floatx4 acc[8][4] = {};

  auto stage = [&](int kt, int h) {
    const u16* srcm = (h < 2) ? A : W;
    const int baser = ((h < 2) ? bm : bn) + (h & 1) * 128;
    u16* dst = lds + (kt & 1) * 32768 + h * 8192 + w * 512;
    const int k0 = kt << 6;
#pragma unroll
    for (int j = 0; j < 2; ++j) {
      int sub = w * 8 + (l >> 3) + j * 64;
      int gk = ((l & 7) ^ (sub & 7)) << 3;
      GLL16(srcm + (size_t)(baser + sub) * K + k0 + gk, dst + j * 4096);
    }
  };

  bf16x8 a0[2][4], a1[2][4], b0[2][2], b1[2][2];

  auto readA = [&](bf16x8 (&aa)[2][4], const u16* LA, int hh) {
#pragma unroll
    for (int i = 0; i < 4; ++i) {
      int am = wm * 128 + hh * 64 + i * 16 + l15;
      const u16* p = LA + am * 64;
      aa[0][i] = *(const bf16x8*)(p + ((quad ^ (am & 7)) << 3));
      aa[1][i] = *(const bf16x8*)(p + (((4 + quad) ^ (am & 7)) << 3));
    }
  };
  auto readB = [&](bf16x8 (&bb)[2][2], const u16* LB, int hh) {
#pragma unroll
    for (int j = 0; j < 2; ++j) {
      int an = wn * 64 + hh * 32 + j * 16 + l15;
      const u16* p = LB + an * 64;
      bb[0][j] = *(const bf16x8*)(p + ((quad ^ (an & 7)) << 3));
      bb[1][j] = *(const bf16x8*)(p + (((4 + quad) ^ (an & 7)) << 3));
    }
  };

  stage(0, 2); stage(0, 3); stage(0, 0); stage(0, 1);
  stage(1, 2); stage(1, 3); stage(1, 0);
  asm volatile("s_waitcnt vmcnt(6)" ::: "memory");
  __builtin_amdgcn_s_barrier();
  readA(a0, lds, 0);
  readB(b0, lds + 16384, 0);

  for (int kt = 0; kt < NT; ++kt) {
    const u16* LA = lds + (kt & 1) * 32768;
    const u16* LB = LA + 16384;

    readB(b1, LB, 1);
    if (kt + 1 < NT) stage(kt + 1, 1);
    PHASE_MFMA(a0, b0, 0, 0, 4);
    __builtin_amdgcn_s_barrier();

    readA(a1, LA, 1);
    PHASE_MFMA(a0, b1, 0, 1, 8);
    __builtin_amdgcn_s_barrier();

    if (kt + 2 < NT) stage(kt + 2, 2);
    PHASE_MFMA(a1, b0, 1, 0, 0);
    __builtin_amdgcn_s_barrier();

    if (kt + 2 < NT) {
      stage(kt + 2, 3); stage(kt + 2, 0);
      asm volatile("s_waitcnt vmcnt(6)" ::: "memory");
    } else {
      asm volatile("s_waitcnt vmcnt(0)" ::: "memory");
    }
    __builtin_amdgcn_s_barrier();
    asm volatile("s_waitcnt lgkmcnt(0)" ::: "memory");
    __builtin_amdgcn_sched_barrier(0);
    if (kt + 1 < NT) {
      const u16* LAn = lds + ((kt + 1) & 1) * 32768;
      readA(a0, LAn, 0);
      readB(b0, LAn + 16384, 0);
    }
    __builtin_amdgcn_s_setprio(1);
#pragma unroll
    for (int kc = 0; kc < 2; ++kc)
#pragma unroll
      for (int i = 0; i < 4; ++i)
#pragma unroll
        for (int j = 0; j < 2; ++j)
          acc[4 + i][2 + j] = MFMA16(a1[kc][i], b1[kc][j], acc[4 + i][2 + j]);
    __builtin_amdgcn_s_setprio(0);
    __builtin_amdgcn_s_barrier();
  }

  // ---- epilogue: fp32 LDS bounce -> coalesced stores ----
  float* fl = (float*)lds;   // 128 x 256 fp32 = 128 KiB
#pragma unroll 1
  for (int half = 0; half < 2; ++half) {
    __syncthreads();
    if (wm == half) {
#pragma unroll
      for (int ni = 0; ni < 4; ++ni) {
        float bv = bias[bn + wn * 64 + ni * 16 + l15];
#pragma unroll
        for (int mi = 0; mi < 8; ++mi) {
#pragma unroll
          for (int r = 0; r < 4; ++r) {
            int lr = mi * 16 + quad * 4 + r;
            int c  = wn * 64 + ni * 16 + l15;
            int key = ((r ^ quad) & 3) << 4;
            fl[lr * 256 + (c ^ key)] = acc[mi][ni][r] + bv;
          }
        }
      }
    }
    __syncthreads();
#pragma unroll 1
    for (int cc = 0; cc < 4; ++cc) {
      int col0 = bn + cc * 64;
#pragma unroll
      for (int rr = 0; rr < 4; ++rr) {
        int lr = w * 16 + rr * 4 + quad;
        int key = ((rr ^ quad) & 3) << 4;
        float4 v = *(const float4*)&fl[lr * 256 + ((cc * 64 + (l15 << 2)) ^ key)];
        int grow = bm + half * 128 + lr;
        if (col0 < 3072) {
          ushort4 hv;
          hv.x = f2bf(v.x); hv.y = f2bf(v.y); hv.z = f2bf(v.z); hv.w = f2bf(v.w);
          int matsel = col0 >> 10;
          int hh2 = (col0 >> 6) & 15;
          if (grow < 4096) {
            int bb = grow >> 8, ss = grow & 255;
            *(ushort4*)(Cv + (size_t)matsel * 4194304 +
                        ((size_t)(((bb << 4) + hh2) << 8) + ss) * 64 + (l15 << 2)) = hv;
          } else if (matsel == 2) {
            int pp = grow - 4096;
            *(ushort4*)(Cv + (size_t)3 * 4194304 +
                        ((size_t)((hh2 << 8) + pp)) * 64 + (l15 << 2)) = hv;
          }
        } else if (col0 < 3104) {
#pragma unroll
          for (int e = 0; e < 4; ++e) {
            int col = col0 + (l15 << 2) + e;
            float vv = e == 0 ? v.x : e == 1 ? v.y : e == 2 ? v.z : v.w;
            if (col < 3088) {
              if (grow < 4096)
                utb[((grow >> 8) * 16 + (col - 3072)) * 256 + (grow & 255)] = vv;
            } else if (col < 3104) {
              if (grow >= 4096)
                dtb[(col - 3088) * 256 + (grow - 4096)] = vv;
            }
          }
        }
      }
    }
  }
}

// ---------------- fused attention v3: one block per (b,h) ----------------
// Round-4 proven task-loop skeleton (rt COMPILE-TIME via pragma unroll +
// running cnt — rule #20: no runtime indexing of qa) + the three verified
// v2 improvements:
//   - Sc2 fused into Sc: QR phase does += at z=(j<<4)+l15+4*quad+r-15
//     (separate barrier-phase so QK's writes land first)
//   - P stored bf16 in Pl; PV reads 2x ds_read_b64, no per-element f2bf
//   - conflict-min strides: Sc[32][266] f32, Pl[32][268] u16;
//     softmax rows = w + 8*(l>>4), float2 paired reads
// Phases per s-tile: [PV(st-1) ; QK(st)] / [QR(st) +=] / [softmax -> Pl]
__global__ __launch_bounds__(512, 2) void attn_k(
    const u16* __restrict__ Qh, const u16* __restrict__ Kh,
    const u16* __restrict__ Vh, const u16* __restrict__ RPKh,
    const float* __restrict__ ut, const float* __restrict__ dt,
    u16* __restrict__ vw) {
  __shared__ u16 Klds[256 * 64];              // 32 KB, XOR-swizzled rows
  __shared__ u16 Vt[64][280];                 // 35 KB, V transposed
  __shared__ __align__(16) float Sc[32][266]; // 34 KB fused scores
  __shared__ __align__(16) u16 Pl[32][268];   // 16.8 KB bf16 P
  __shared__ float Ut[256], Dt[256], Rinv[32];

  const int bh = blockIdx.x;         // b*16 + h
  const int h = bh & 15;
  const int b = bh >> 4;
  const size_t bh256 = (size_t)bh << 8;

  const int t = threadIdx.x, w = t >> 6, l = t & 63;
  const int l15 = l & 15, quad = l >> 4;

  // ---- staging: K (GLL16), V^T (LDS transpose), Ut, Dt ----
  {
    const int lrow8 = l >> 3, kslot = l & 7;
#pragma unroll
    for (int i = 0; i < 4; ++i) {
      int row = w * 32 + i * 8 + lrow8;
      int gk = (kslot ^ (row & 7)) << 3;
      GLL16(Kh + (bh256 + row) * 64 + gk, Klds + (w * 32 + i * 8) * 64);
    }
  }
  {
    int z = t & 255, dh = t >> 8;    // dh: 0..1 (wave-uniform)
    const u16* gp = Vh + (bh256 + z) * 64 + dh * 32;
    ushort4 vv[8];
#pragma unroll
    for (int i = 0; i < 8; ++i) vv[i] = *(const ushort4*)(gp + i * 4);
#pragma unroll
    for (int i = 0; i < 8; ++i) {
      Vt[dh * 32 + i * 4 + 0][z] = vv[i].x;
      Vt[dh * 32 + i * 4 + 1][z] = vv[i].y;
      Vt[dh * 32 + i * 4 + 2][z] = vv[i].z;
      Vt[dh * 32 + i * 4 + 3][z] = vv[i].w;
    }
  }
  if (t < 256) Ut[t] = ut[bh256 + t];
  else         Dt[t - 256] = dt[((size_t)h << 8) + (t - 256)];
  __syncthreads();

  bf16x8 qa[2][2];
  const int strip = w >> 2, nt = w & 3;

  // PV for tile stp (0..7): reads Pl/Vt/Rinv, stores to vw.
  auto pv_tile = [&](int stp) {
    floatx4 oacc = {};
    for (int kc = 0; kc <= stp; ++kc) {
      const u16* pp = &Pl[strip * 16 + l15][kc * 32 + quad * 8];
      bf16x4 plo = *(const bf16x4*)pp;
      bf16x4 phi = *(const bf16x4*)(pp + 4);
      bf16x8 pa = __builtin_shufflevector(plo, phi, 0, 1, 2, 3, 4, 5, 6, 7);
      bf16x8 vbf = *(const bf16x8*)&Vt[nt * 16 + l15][kc * 32 + quad * 8];
      oacc = MFMA16(pa, vbf, oacc);
    }
#pragma unroll
    for (int r = 0; r < 4; ++r) {
      float ivr = Rinv[strip * 16 + quad * 4 + r];
      int srow = stp * 32 + strip * 16 + quad * 4 + r;
      vw[(size_t)(b * 256 + srow) * 1024 + h * 64 + nt * 16 + l15] =
          f2bf(oacc[r] * ivr);
    }
  };

  for (int st = 0; st < 8; ++st) {
    const int s0 = st * 32;

    // qa for this tile (global loads; latency hidden under PV below)
#pragma unroll
    for (int rt = 0; rt < 2; ++rt) {
      const u16* qp = Qh + (bh256 + s0 + rt * 16 + l15) * 64 + quad * 8;
      qa[rt][0] = *(const bf16x8*)qp;
      qa[rt][1] = *(const bf16x8*)(qp + 32);
    }

    // ---- phase 1: PV(st-1) ; QK(st) -> Sc ----
    if (st > 0) pv_tile(st - 1);
    {
      int cnt = 0;
#pragma unroll
      for (int rt = 0; rt < 2; ++rt) {
        const int nzt = 2 * st + rt + 1;
        for (int zt = 0; zt < nzt; ++zt, ++cnt) {
          if ((cnt & 7) != w) continue;  // wave-uniform
          const int zr = (zt << 4) + l15;
          const u16* krow = Klds + zr * 64;
          bf16x8 kb0 = *(const bf16x8*)(krow + ((quad ^ (zr & 7)) << 3));
          bf16x8 kb1 = *(const bf16x8*)(krow + (((quad + 4) ^ (zr & 7)) << 3));
          floatx4 acc = {};
          acc = MFMA16(qa[rt][0], kb0, acc);
          acc = MFMA16(qa[rt][1], kb1, acc);
          float u = Ut[zr];
#pragma unroll
          for (int r = 0; r < 4; ++r)
            Sc[rt * 16 + quad * 4 + r][zr] = acc[r] + u;
        }
      }
    }
    __syncthreads();

    // ---- phase 2: QR(st), fused += into Sc ----
    {
      int cnt = 0;
#pragma unroll
      for (int rt = 0; rt < 2; ++rt) {
        const int nzt = 2 * st + rt + 1;
        for (int j = 0; j < nzt; ++j, ++cnt) {
          if ((cnt & 7) != w) continue;  // wave-uniform
          const int pr = 240 - (s0 + rt * 16) + (j << 4) + l15;
          const u16* rp = RPKh + ((size_t)(h << 8) + pr) * 64 + quad * 8;
          bf16x8 rb0 = *(const bf16x8*)rp;
          bf16x8 rb1 = *(const bf16x8*)(rp + 32);
          floatx4 acc = {};
          acc = MFMA16(qa[rt][0], rb0, acc);
          acc = MFMA16(qa[rt][1], rb1, acc);
          float dv = Dt[pr];
#pragma unroll
          for (int r = 0; r < 4; ++r) {
            int z = (j << 4) + l15 + 4 * quad + r - 15;
            if (z >= 0)
              Sc[rt * 16 + 4 * quad + r][z] += acc[r] + dv;
          }
        }
      }
    }
    __syncthreads();

    // ---- phase 3: softmax -> Pl (bf16 pairs), Rinv ----
    {
      const int row = w + 8 * (l >> 4);  // groups spaced 8 rows
      const int c16 = l & 15;
      const int s = s0 + row;
      const int zfill = 32 * (st + 1);
      float m = -1e30f;
      for (int z0 = 2 * c16; z0 <= s; z0 += 32) {
        float2 vv = *(const float2*)&Sc[row][z0];
        m = fmaxf(m, vv.x);
        if (z0 + 1 <= s) m = fmaxf(m, vv.y);
      }
      m = fmaxf(m, __shfl_xor(m, 1));
      m = fmaxf(m, __shfl_xor(m, 2));
      m = fmaxf(m, __shfl_xor(m, 4));
      m = fmaxf(m, __shfl_xor(m, 8));
      m *= kScale;
      float sum = 0.f;
      for (int z0 = 2 * c16; z0 < zfill; z0 += 32) {
        float2 vv = *(const float2*)&Sc[row][z0];
        float e0 = (z0 <= s) ? __expf(vv.x * kScale - m) : 0.f;
        float e1 = (z0 + 1 <= s) ? __expf(vv.y * kScale - m) : 0.f;
        sum += e0 + e1;
        unsigned pk = (unsigned)f2bf(e0) | ((unsigned)f2bf(e1) << 16);
        *(unsigned*)&Pl[row][z0] = pk;
      }
      sum += __shfl_xor(sum, 1);
      sum += __shfl_xor(sum, 2);
      sum += __shfl_xor(sum, 4);
      sum += __shfl_xor(sum, 8);
      if (c16 == 0) Rinv[row] = 1.f / sum;
    }
    __syncthreads();
  }

  // ---- epilogue: PV(7) ----
  pv_tile(7);
}

extern "C" void kernel_launch(void* const* d_in, const int* in_sizes, int n_in,
                              void* d_out, int out_size, void* d_ws, size_t ws_size,
                              hipStream_t stream) {
  const float* x  = (const float*)d_in[0];
  const float* Wq = (const float*)d_in[1];
  const float* bq = (const float*)d_in[2];
  const float* Wk = (const float*)d_in[3];
  const float* bk = (const float*)d_in[4];
  const float* Wv = (const float*)d_in[5];
  const float* bv = (const float*)d_in[6];
  const float* Wr = (const float*)d_in[7];
  const float* br = (const float*)d_in[8];
  const float* ub = (const float*)d_in[9];
  const float* vb = (const float*)d_in[10];
  const float* Wo = (const float*)d_in[11];
  const float* bo = (const float*)d_in[12];
  float* out = (float*)d_out;

  char* base = (char*)d_ws;
  size_t off = 0;
  auto alloc = [&](size_t bytes) {
    void* p = base + off;
    off += (bytes + 255) & ~(size_t)255;
    return p;
  };

  const size_t MAT = (size_t)4194304;  // 4096*1024
  u16*   xA    = (u16*)alloc((size_t)4352 * 1024 * 2);       // [x ; table]
  u16*   W3b   = (u16*)alloc((size_t)3328 * 1024 * 2);       // [Wq;Wv;Wk;UV;pad]
  u16*   Wob   = (u16*)alloc((size_t)1024 * 1024 * 2);
  float* b3    = (float*)alloc((size_t)3328 * 4);
  u16*   Ph    = (u16*)alloc((3 * MAT + 262144) * 2);        // Qh,Vh,Kh,RPKh
  float* utb   = (float*)alloc((size_t)65536 * 4);
  float* dtb   = (float*)alloc((size_t)4096 * 4);
  u16*   vwb   = (u16*)alloc((size_t)4096 * 1024 * 2);

  u16* Qh   = Ph;
  u16* Vh   = Ph + MAT;
  u16* Kh   = Ph + 2 * MAT;
  u16* RPKh = Ph + 3 * MAT;

  pack_k<<<dim3(8451), dim3(256), 0, stream>>>(x, Wq, Wk, Wv, Wo, bq, bk, bv,
                                               xA, W3b, Wob, b3);
  uv_fold_k<<<dim3(128), dim3(256), 0, stream>>>(Wr, br, ub, vb, W3b, b3);

  // fused Q|V|K + relpos-K + ut/dt projections: 4352 x 3328(pad) x 1024
  gemm256_k<<<dim3(221), dim3(512), 0, stream>>>(xA, W3b, b3, Ph,
                                                 1024, utb, dtb, 17, 13);

  // fused attention: one block per (b,h)
  attn_k<<<dim3(256), dim3(512), 0, stream>>>(Qh, Kh, Vh, RPKh, utb, dtb, vwb);

  // output projection: 4096 x 1024 x 1024, fp32 out
  gemm_k<0><<<dim3(256), dim3(256), 0, stream>>>(vwb, Wob, bo, out,
                                                 4096, 1024, 1024, nullptr, nullptr,
                                                 32, 8);
}

// Round 7
// 209.637 us; speedup vs baseline: 1.5886x; 1.0276x over previous
//
#include <hip/hip_runtime.h>
#include <math.h>

constexpr int kB  = 16;
constexpr int kS  = 256;
constexpr int kD  = 1024;
constexpr int kH  = 16;
constexpr float kScale = 0.125f;  // 1/sqrt(64)

using bf16x8  = __attribute__((ext_vector_type(8))) short;
using floatx4 = __attribute__((ext_vector_type(4))) float;
typedef unsigned short u16;

__device__ __forceinline__ u16 f2bf(float x) {
  union { float f; unsigned u; } v; v.f = x;
  unsigned r = v.u + 0x7fffu + ((v.u >> 16) & 1u);
  return (u16)(r >> 16);
}
__device__ __forceinline__ float bf2f(u16 h) {
  union { unsigned u; float f; } v; v.u = ((unsigned)h) << 16;
  return v.f;
}

#define MFMA16(a, b, c) __builtin_amdgcn_mfma_f32_16x16x32_bf16((a), (b), (c), 0, 0, 0)
#define GLL16(gp, lp)                                                        \
  __builtin_amdgcn_global_load_lds(                                          \
      (const __attribute__((address_space(1))) unsigned int*)(gp),           \
      (__attribute__((address_space(3))) unsigned int*)(lp), 16, 0, 0)

// ---------------- pack + table: xA=[x;table], W3=[Wq;Wv;Wk], Wo, b3 ----------
__global__ __launch_bounds__(256) void pack_k(
    const float* __restrict__ x, const float* __restrict__ Wq,
    const float* __restrict__ Wk, const float* __restrict__ Wv,
    const float* __restrict__ Wo,
    const float* __restrict__ bq, const float* __restrict__ bk,
    const float* __restrict__ bv,
    u16* __restrict__ xA, u16* __restrict__ W3b, u16* __restrict__ Wob,
    float* __restrict__ b3) {
  size_t i = ((size_t)blockIdx.x * 256 + threadIdx.x) * 4;
  const size_t NX = (size_t)4194304, NW = (size_t)1048576;
  const size_t BEND = NX + 4 * NW + 3072;
  const float* src;
  u16* dst;
  size_t o;
  if (i < NX) {
    src = x; dst = xA; o = i;
  } else if (i < NX + 3 * NW) {
    size_t j = i - NX;
    int sel = (int)(j >> 20);
    o = j & (NW - 1);
    src = sel == 0 ? Wq : sel == 1 ? Wv : Wk;
    dst = W3b + (size_t)sel * NW;
  } else if (i < NX + 4 * NW) {
    o = i - NX - 3 * NW;
    src = Wo; dst = Wob;
  } else if (i < BEND) {
    size_t j = i - NX - 4 * NW;
    int sel = (int)(j >> 10);
    o = j & 1023;
    src = sel == 0 ? bq : sel == 1 ? bv : bk;
    *reinterpret_cast<float4*>(b3 + j) = *reinterpret_cast<const float4*>(src + o);
    return;
  } else if (i < BEND + 262144) {
    // sinusoid table rows p in [0,256), pos = p-255 -> xA rows 4096..4351
    size_t j = i - BEND;
    int p = (int)(j >> 10);
    int ibase = (int)(j & 1023);
    ushort4 r;
    u16* rr = (u16*)&r;
#pragma unroll
    for (int c = 0; c < 4; ++c) {
      int idx = ibase + c;
      float ex = (float)(2 * (idx / 2)) * (1.0f / 1024.0f);
      float scale = exp2f(ex * -13.287712379549449f);  // 10000^-ex
      float angle = (float)(p - 255) * scale;
      rr[c] = f2bf((idx & 1) ? cosf(angle) : sinf(angle));
    }
    *reinterpret_cast<ushort4*>(xA + NX + j) = r;
    return;
  } else {
    return;
  }
  float4 v = *reinterpret_cast<const float4*>(src + o);
  ushort4 r;
  r.x = f2bf(v.x); r.y = f2bf(v.y); r.z = f2bf(v.z); r.w = f2bf(v.w);
  *reinterpret_cast<ushort4*>(dst + o) = r;
}

// ---------------- rank-16 fold of Wr with u/v: W3b rows 3072..3103, b3 tail ------
__global__ __launch_bounds__(256) void uv_fold_k(
    const float* __restrict__ Wr, const float* __restrict__ br,
    const float* __restrict__ ub, const float* __restrict__ vb,
    u16* __restrict__ W3b, float* __restrict__ b3) {
  int gid = blockIdx.x * 256 + threadIdx.x;  // 32768
  int j = gid >> 10, c = gid & 1023;
  int h = j & 15;
  const float* bvec = (j < 16 ? ub : vb) + h * 64;
  const float* wcol = Wr + (size_t)(h * 64) * 1024 + c;
  float a = 0.f;
#pragma unroll
  for (int d = 0; d < 64; ++d) a += bvec[d] * wcol[(size_t)d * 1024];
  W3b[(size_t)(3072 + j) * 1024 + c] = f2bf(a);
  if (gid < 128) {
    float s = 0.f;
    if (gid < 32) {
      const float* bv2 = (gid < 16 ? ub : vb) + (gid & 15) * 64;
      const float* brp = br + (gid & 15) * 64;
      for (int d = 0; d < 64; ++d) s += bv2[d] * brp[d];
    }
    b3[3072 + gid] = s;
  }
}

// ---------------- legacy 128x128 bf16 MFMA GEMM (used for out-proj) ----------
template <int OUT_MODE>
__global__ __launch_bounds__(256) void gemm_k(
    const u16* __restrict__ A, const u16* __restrict__ W,
    const float* __restrict__ bias, void* __restrict__ Cv,
    int M, int N, int K, float* __restrict__ utb, float* __restrict__ dtb,
    int mTiles, int nTiles) {
  const int xcd = blockIdx.x & 7;
  const int li  = blockIdx.x >> 3;
  const int r0   = (xcd * mTiles) >> 3;
  const int rcnt = (((xcd + 1) * mTiles) >> 3) - r0;
  if (li >= rcnt * nTiles) return;   // uniform early-out (padded grid)
  const int bm = (r0 + li % rcnt) * 128;
  const int bn = (li / rcnt) * 128;

  __shared__ u16 Alds[128 * 64];
  __shared__ u16 Blds[128 * 64];
  const int t = threadIdx.x, w = t >> 6, l = t & 63;
  const int l15 = l & 15, quad = l >> 4;
  const int wm = w >> 1, wn = w & 1;
  const int lrow8 = l >> 3;
  const int kslot = l & 7;

  floatx4 acc[4][4] = {};

  for (int k0 = 0; k0 < K; k0 += 64) {
#pragma unroll
    for (int sg = 0; sg < 4; ++sg) {
      int mrow = sg * 32 + w * 8 + lrow8;
      int gk = (kslot ^ (mrow & 7)) << 3;
      GLL16(A + (size_t)(bm + mrow) * K + k0 + gk, Alds + (sg * 32 + w * 8) * 64);
      GLL16(W + (size_t)(bn + mrow) * K + k0 + gk, Blds + (sg * 32 + w * 8) * 64);
    }
    __syncthreads();
#pragma unroll
    for (int c = 0; c < 2; ++c) {
      bf16x8 af[4], bf[4];
#pragma unroll
      for (int mi = 0; mi < 4; ++mi) {
        int am = wm * 64 + mi * 16 + l15;
        af[mi] = *(const bf16x8*)(Alds + am * 64 + (((c * 4 + quad) ^ (am & 7)) << 3));
      }
#pragma unroll
      for (int ni = 0; ni < 4; ++ni) {
        int an = wn * 64 + ni * 16 + l15;
        bf[ni] = *(const bf16x8*)(Blds + an * 64 + (((c * 4 + quad) ^ (an & 7)) << 3));
      }
#pragma unroll
      for (int mi = 0; mi < 4; ++mi)
#pragma unroll
        for (int ni = 0; ni < 4; ++ni)
          acc[mi][ni] = MFMA16(af[mi], bf[ni], acc[mi][ni]);
    }
    __syncthreads();
  }

#pragma unroll
  for (int ni = 0; ni < 4; ++ni) {
    int col = bn + wn * 64 + ni * 16 + l15;
    float bv = bias[col];
#pragma unroll
    for (int mi = 0; mi < 4; ++mi) {
      int mrow = bm + wm * 64 + mi * 16 + quad * 4;
#pragma unroll
      for (int r = 0; r < 4; ++r) {
        float v = acc[mi][ni][r] + bv;
        int row = mrow + r;
        if (OUT_MODE == 0) {
          ((float*)Cv)[(size_t)row * N + col] = v;
        }
      }
    }
  }
}

// ---------------- 256x256 8-phase bf16 MFMA GEMM (T2+T3+T4+T5) ----------------
// Main loop unchanged (verified). Epilogue: fp32 LDS bounce; V blocks
// (bn in [1024,2048)) now emit TRANSPOSED VT[bh][d][z] (coalesced 16B
// stores) so attn can consume V^T fragments directly from global.
#define PHASE_MFMA(aa, bb, mh, nh, LG)                                         \
  do {                                                                         \
    __builtin_amdgcn_s_barrier();                                              \
    asm volatile("s_waitcnt lgkmcnt(" #LG ")" ::: "memory");                   \
    __builtin_amdgcn_sched_barrier(0);                                         \
    __builtin_amdgcn_s_setprio(1);                                             \
    _Pragma("unroll") for (int kc = 0; kc < 2; ++kc)                           \
        _Pragma("unroll") for (int i = 0; i < 4; ++i)                          \
            _Pragma("unroll") for (int j = 0; j < 2; ++j)                      \
                acc[(mh) * 4 + i][(nh) * 2 + j] = MFMA16(                      \
                    aa[kc][i], bb[kc][j], acc[(mh) * 4 + i][(nh) * 2 + j]);    \
    __builtin_amdgcn_s_setprio(0);                                             \
  } while (0)

__global__ __launch_bounds__(512, 2) void gemm256_k(
    const u16* __restrict__ A, const u16* __restrict__ W,
    const float* __restrict__ bias, u16* __restrict__ Cv,
    int K, float* __restrict__ utb, float* __restrict__ dtb,
    int mTiles, int nTiles) {
  const int nwg = mTiles * nTiles;
  const int qq = nwg >> 3, rr8 = nwg & 7;
  const int xcd = blockIdx.x & 7;
  const int wgid = (xcd < rr8 ? xcd * (qq + 1) : rr8 * (qq + 1) + (xcd - rr8) * qq)
                   + (blockIdx.x >> 3);
  const int bm = (wgid / nTiles) * 256;
  const int bn = (wgid % nTiles) * 256;

  __shared__ u16 lds[2 * 32768];     // 128 KiB: [buf][A 256x64 | B 256x64]

  const int t = threadIdx.x, w = t >> 6, l = t & 63;
  const int l15 = l & 15, quad = l >> 4;
  const int wm = w >> 2, wn = w & 3;

  const int NT = K >> 6;
  floatx4 acc[8][4] = {};

  auto stage = [&](int kt, int h) {
    const u16* srcm = (h < 2) ? A : W;
    const int baser = ((h < 2) ? bm : bn) + (h & 1) * 128;
    u16* dst = lds + (kt & 1) * 32768 + h * 8192 + w * 512;
    const int k0 = kt << 6;
#pragma unroll
    for (int j = 0; j < 2; ++j) {
      int sub = w * 8 + (l >> 3) + j * 64;
      int gk = ((l & 7) ^ (sub & 7)) << 3;
      GLL16(srcm + (size_t)(baser + sub) * K + k0 + gk, dst + j * 4096);
    }
  };

  bf16x8 a0[2][4], a1[2][4], b0[2][2], b1[2][2];

  auto readA = [&](bf16x8 (&aa)[2][4], const u16* LA, int hh) {
#pragma unroll
    for (int i = 0; i < 4; ++i) {
      int am = wm * 128 + hh * 64 + i * 16 + l15;
      const u16* p = LA + am * 64;
      aa[0][i] = *(const bf16x8*)(p + ((quad ^ (am & 7)) << 3));
      aa[1][i] = *(const bf16x8*)(p + (((4 + quad) ^ (am & 7)) << 3));
    }
  };
  auto readB = [&](bf16x8 (&bb)[2][2], const u16* LB, int hh) {
#pragma unroll
    for (int j = 0; j < 2; ++j) {
      int an = wn * 64 + hh * 32 + j * 16 + l15;
      const u16* p = LB + an * 64;
      bb[0][j] = *(const bf16x8*)(p + ((quad ^ (an & 7)) << 3));
      bb[1][j] = *(const bf16x8*)(p + (((4 + quad) ^ (an & 7)) << 3));
    }
  };

  stage(0, 2); stage(0, 3); stage(0, 0); stage(0, 1);
  stage(1, 2); stage(1, 3); stage(1, 0);
  asm volatile("s_waitcnt vmcnt(6)" ::: "memory");
  __builtin_amdgcn_s_barrier();
  readA(a0, lds, 0);
  readB(b0, lds + 16384, 0);

  for (int kt = 0; kt < NT; ++kt) {
    const u16* LA = lds + (kt & 1) * 32768;
    const u16* LB = LA + 16384;

    readB(b1, LB, 1);
    if (kt + 1 < NT) stage(kt + 1, 1);
    PHASE_MFMA(a0, b0, 0, 0, 4);
    __builtin_amdgcn_s_barrier();

    readA(a1, LA, 1);
    PHASE_MFMA(a0, b1, 0, 1, 8);
    __builtin_amdgcn_s_barrier();

    if (kt + 2 < NT) stage(kt + 2, 2);
    PHASE_MFMA(a1, b0, 1, 0, 0);
    __builtin_amdgcn_s_barrier();

    if (kt + 2 < NT) {
      stage(kt + 2, 3); stage(kt + 2, 0);
      asm volatile("s_waitcnt vmcnt(6)" ::: "memory");
    } else {
      asm volatile("s_waitcnt vmcnt(0)" ::: "memory");
    }
    __builtin_amdgcn_s_barrier();
    asm volatile("s_waitcnt lgkmcnt(0)" ::: "memory");
    __builtin_amdgcn_sched_barrier(0);
    if (kt + 1 < NT) {
      const u16* LAn = lds + ((kt + 1) & 1) * 32768;
      readA(a0, LAn, 0);
      readB(b0, LAn + 16384, 0);
    }
    __builtin_amdgcn_s_setprio(1);
#pragma unroll
    for (int kc = 0; kc < 2; ++kc)
#pragma unroll
      for (int i = 0; i < 4; ++i)
#pragma unroll
        for (int j = 0; j < 2; ++j)
          acc[4 + i][2 + j] = MFMA16(a1[kc][i], b1[kc][j], acc[4 + i][2 + j]);
    __builtin_amdgcn_s_setprio(0);
    __builtin_amdgcn_s_barrier();
  }

  // ---- epilogue: fp32 LDS bounce -> coalesced stores ----
  float* fl = (float*)lds;   // 128 x 256 fp32 = 128 KiB
  u16* VTp = Cv + (size_t)4194304;   // matsel==1 slot, transposed layout
#pragma unroll 1
  for (int half = 0; half < 2; ++half) {
    __syncthreads();
    if (wm == half) {
#pragma unroll
      for (int ni = 0; ni < 4; ++ni) {
        float bv = bias[bn + wn * 64 + ni * 16 + l15];
#pragma unroll
        for (int mi = 0; mi < 8; ++mi) {
#pragma unroll
          for (int r = 0; r < 4; ++r) {
            int lr = mi * 16 + quad * 4 + r;
            int c  = wn * 64 + ni * 16 + l15;
            int key = ((r ^ quad) & 3) << 4;
            fl[lr * 256 + (c ^ key)] = acc[mi][ni][r] + bv;
          }
        }
      }
    }
    __syncthreads();
    if (bn >= 1024 && bn < 2048) {
      // V block: emit transposed VT[bh][d][z]; bias already in fl.
      if (bm < 4096) {
        int bb = bm >> 8;
#pragma unroll 1
        for (int p = 0; p < 8; ++p) {
          int dl = p * 32 + (t >> 4);        // 0..255 (col within tile)
          int zl = (t & 15) * 8;             // 0..120
          int col = bn + dl;
          int hh2 = (col >> 6) & 15, dd = col & 63;
          u16 hv[8];
#pragma unroll
          for (int e = 0; e < 8; ++e) {
            int lr = zl + e;
            int key = ((lr & 3) ^ ((lr >> 2) & 3)) << 4;
            hv[e] = f2bf(fl[lr * 256 + (dl ^ key)]);
          }
          u16* vp = VTp + ((size_t)((bb << 4) + hh2) * 64 + dd) * 256 +
                    half * 128 + zl;
          *(ushort4*)vp = *(ushort4*)&hv[0];
          *(ushort4*)(vp + 4) = *(ushort4*)&hv[4];
        }
      }
    } else {
#pragma unroll 1
      for (int cc = 0; cc < 4; ++cc) {
        int col0 = bn + cc * 64;
#pragma unroll
        for (int rr = 0; rr < 4; ++rr) {
          int lr = w * 16 + rr * 4 + quad;
          int key = ((rr ^ quad) & 3) << 4;
          float4 v = *(const float4*)&fl[lr * 256 + ((cc * 64 + (l15 << 2)) ^ key)];
          int grow = bm + half * 128 + lr;
          if (col0 < 3072) {
            ushort4 hvv;
            hvv.x = f2bf(v.x); hvv.y = f2bf(v.y); hvv.z = f2bf(v.z); hvv.w = f2bf(v.w);
            int matsel = col0 >> 10;
            int hh2 = (col0 >> 6) & 15;
            if (grow < 4096) {
              int bb = grow >> 8, ss = grow & 255;
              *(ushort4*)(Cv + (size_t)matsel * 4194304 +
                          ((size_t)(((bb << 4) + hh2) << 8) + ss) * 64 + (l15 << 2)) = hvv;
            } else if (matsel == 2) {
              int pp = grow - 4096;
              *(ushort4*)(Cv + (size_t)3 * 4194304 +
                          ((size_t)((hh2 << 8) + pp)) * 64 + (l15 << 2)) = hvv;
            }
          } else if (col0 < 3104) {
#pragma unroll
            for (int e = 0; e < 4; ++e) {
              int col = col0 + (l15 << 2) + e;
              float vv = e == 0 ? v.x : e == 1 ? v.y : e == 2 ? v.z : v.w;
              if (col < 3088) {
                if (grow < 4096)
                  utb[((grow >> 8) * 16 + (col - 3072)) * 256 + (grow & 255)] = vv;
              } else if (col < 3104) {
                if (grow >= 4096)
                  dtb[(col - 3088) * 256 + (grow - 4096)] = vv;
              }
            }
          }
        }
      }
    }
  }
}

// ---------------- fused attention v4: wave-autonomous, zero main-loop barriers ----
// One block per (b,h), 8 waves. Wave w owns strips {w, 15-w} (16 rows each;
// (w+1)+(16-w)=17 z-tile tasks per wave — perfectly balanced). Per strip,
// all wave-local (in-order DS gives intra-wave ordering; no __syncthreads):
//   1. interleaved QK(j)/QR(j): K/RPKh fragments from GLOBAL (L2/L3-hot),
//      1-deep parity prefetch; scores to wave-private ScW[16][260] f32;
//      QR does the fused += at z=(j<<4)+l15+4*quad+r-15 (z>=0 guard).
//   2. softmax pass1 (max, masked z<=R), cross-quad shfl_xor reduce.
//   3. pass2: exp + bf16 pack -> PV A-fragment DIRECTLY in lane registers
//      (lane(l15,quad) owns row l15, z=kc*32+quad*8+e — exactly the MFMA
//      A-layout); V^T fragments streamed from global VT[bh][d][z];
//      sum reduce, rinv via __shfl transpose, coalesced u16 stores.
// All register arrays static-indexed (parity regs selected by compile-time
// unroll index — rule #20).
__global__ __launch_bounds__(512, 2) void attn_k(
    const u16* __restrict__ Qh, const u16* __restrict__ Kh,
    const u16* __restrict__ VT, const u16* __restrict__ RPKh,
    const float* __restrict__ ut, const float* __restrict__ dt,
    u16* __restrict__ vw) {
  __shared__ float ScW[8][16 * 260];   // 133 KB wave-private score tiles
  __shared__ float Ut[256], Dt[256];

  const int bh = blockIdx.x;           // b*16 + h
  const int h = bh & 15;
  const int b = bh >> 4;
  const size_t bh256 = (size_t)bh << 8;

  const int t = threadIdx.x, w = t >> 6, l = t & 63;
  const int l15 = l & 15, quad = l >> 4;

  if (t < 256) Ut[t] = ut[bh256 + t];
  else         Dt[t - 256] = dt[((size_t)h << 8) + (t - 256)];
  __syncthreads();

  float* scw = &ScW[w][0];

#pragma unroll 1
  for (int sidx = 0; sidx < 2; ++sidx) {
    const int s = sidx ? (15 - w) : w;   // wave-uniform strip index 0..15
    const int rB = s << 4;               // absolute base row

    // strip-head loads: qa, K tile 0, RP task 0
    bf16x8 qa0, qa1;
    {
      const u16* qp = Qh + (bh256 + rB + l15) * 64 + quad * 8;
      qa0 = *(const bf16x8*)qp;
      qa1 = *(const bf16x8*)(qp + 32);
    }
    bf16x8 kA0, kA1, kB0, kB1, rA0, rA1, rB0, rB1;
    {
      const u16* kp = Kh + (bh256 + l15) * 64 + quad * 8;
      kA0 = *(const bf16x8*)kp;
      kA1 = *(const bf16x8*)(kp + 32);
      const u16* rp = RPKh + (((size_t)h << 8) + 240 - rB + l15) * 64 + quad * 8;
      rA0 = *(const bf16x8*)rp;
      rA1 = *(const bf16x8*)(rp + 32);
    }

    // ---- interleaved QK(j) / QR(j), 1-deep parity prefetch ----
#pragma unroll
    for (int j = 0; j < 16; ++j) {
      if (j > s) break;
      if (j + 1 <= s) {
        const u16* kp = Kh + (bh256 + ((j + 1) << 4) + l15) * 64 + quad * 8;
        const u16* rp = RPKh + (((size_t)h << 8) + 240 - rB + ((j + 1) << 4) + l15) * 64 + quad * 8;
        if ((j + 1) & 1) {
          kB0 = *(const bf16x8*)kp; kB1 = *(const bf16x8*)(kp + 32);
          rB0 = *(const bf16x8*)rp; rB1 = *(const bf16x8*)(rp + 32);
        } else {
          kA0 = *(const bf16x8*)kp; kA1 = *(const bf16x8*)(kp + 32);
          rA0 = *(const bf16x8*)rp; rA1 = *(const bf16x8*)(rp + 32);
        }
      }
      bf16x8 k0 = (j & 1) ? kB0 : kA0;   // j compile-time -> static select
      bf16x8 k1 = (j & 1) ? kB1 : kA1;
      bf16x8 r0 = (j & 1) ? rB0 : rA0;
      bf16x8 r1 = (j & 1) ? rB1 : rA1;
      // QK(j): C[row=4q+r][z=16j+l15]
      {
        floatx4 acc = {};
        acc = MFMA16(qa0, k0, acc);
        acc = MFMA16(qa1, k1, acc);
        float u = Ut[(j << 4) + l15];
#pragma unroll
        for (int r = 0; r < 4; ++r)
          scw[(4 * quad + r) * 260 + (j << 4) + l15] = acc[r] + u;
      }
      // QR(j): += at z = 16j + l15 + 4quad + r - 15
      {
        floatx4 acc = {};
        acc = MFMA16(qa0, r0, acc);
        acc = MFMA16(qa1, r1, acc);
        float dv = Dt[240 - rB + (j << 4) + l15];
#pragma unroll
        for (int r = 0; r < 4; ++r) {
          int z = (j << 4) + l15 + 4 * quad + r - 15;
          if (z >= 0)
            scw[(4 * quad + r) * 260 + z] += acc[r] + dv;
        }
      }
    }

    // ---- softmax pass 1: masked max (lane owns row l15) ----
    const int kcmax = s >> 1;
    const int Rabs = rB + l15;           // causal bound z <= Rabs
    float m = -1e30f;
#pragma unroll
    for (int kc = 0; kc < 8; ++kc) {
      if (kc > kcmax) break;
      const float* sp = scw + l15 * 260 + kc * 32 + quad * 8;
      floatx4 v0 = *(const floatx4*)sp;
      floatx4 v1 = *(const floatx4*)(sp + 4);
#pragma unroll
      for (int e = 0; e < 4; ++e) {
        int z = kc * 32 + quad * 8 + e;
        if (z <= Rabs) m = fmaxf(m, v0[e]);
        if (z + 4 <= Rabs) m = fmaxf(m, v1[e]);
      }
    }
    m = fmaxf(m, __shfl_xor(m, 16));
    m = fmaxf(m, __shfl_xor(m, 32));
    m *= kScale;

    // ---- pass 2: exp + PV (V^T fragments from global, 1-deep prefetch) ----
    floatx4 oacc[4] = {};
    float sum = 0.f;
    bf16x8 vA[4], vB[4];
    {
      const u16* vp = VT + ((size_t)bh * 64 + l15) * 256 + quad * 8;
#pragma unroll
      for (int nt = 0; nt < 4; ++nt)
        vA[nt] = *(const bf16x8*)(vp + (size_t)nt * 16 * 256);
    }
#pragma unroll
    for (int kc = 0; kc < 8; ++kc) {
      if (kc > kcmax) break;
      if (kc + 1 <= kcmax) {
        const u16* vp = VT + ((size_t)bh * 64 + l15) * 256 + (kc + 1) * 32 + quad * 8;
        if ((kc + 1) & 1) {
#pragma unroll
          for (int nt = 0; nt < 4; ++nt)
            vB[nt] = *(const bf16x8*)(vp + (size_t)nt * 16 * 256);
        } else {
#pragma unroll
          for (int nt = 0; nt < 4; ++nt)
            vA[nt] = *(const bf16x8*)(vp + (size_t)nt * 16 * 256);
        }
      }
      const float* sp = scw + l15 * 260 + kc * 32 + quad * 8;
      floatx4 v0 = *(const floatx4*)sp;
      floatx4 v1 = *(const floatx4*)(sp + 4);
      bf16x8 pa;
#pragma unroll
      for (int e = 0; e < 4; ++e) {
        int z = kc * 32 + quad * 8 + e;
        float p0 = (z <= Rabs) ? __expf(v0[e] * kScale - m) : 0.f;
        float p1 = (z + 4 <= Rabs) ? __expf(v1[e] * kScale - m) : 0.f;
        sum += p0 + p1;
        pa[e] = (short)f2bf(p0);
        pa[e + 4] = (short)f2bf(p1);
      }
#pragma unroll
      for (int nt = 0; nt < 4; ++nt)
        oacc[nt] = MFMA16(pa, (kc & 1) ? vB[nt] : vA[nt], oacc[nt]);
    }
    sum += __shfl_xor(sum, 16);
    sum += __shfl_xor(sum, 32);
    float rinv = 1.f / sum;

    // ---- store: row = rB + 4quad + r; rinv transposed via shfl ----
#pragma unroll
    for (int r = 0; r < 4; ++r) {
      float rs = __shfl(rinv, 4 * quad + r);
      int row = rB + 4 * quad + r;
#pragma unroll
      for (int nt = 0; nt < 4; ++nt)
        vw[(size_t)(b * 256 + row) * 1024 + h * 64 + nt * 16 + l15] =
            f2bf(oacc[nt][r] * rs);
    }
  }
}

extern "C" void kernel_launch(void* const* d_in, const int* in_sizes, int n_in,
                              void* d_out, int out_size, void* d_ws, size_t ws_size,
                              hipStream_t stream) {
  const float* x  = (const float*)d_in[0];
  const float* Wq = (const float*)d_in[1];
  const float* bq = (const float*)d_in[2];
  const float* Wk = (const float*)d_in[3];
  const float* bk = (const float*)d_in[4];
  const float* Wv = (const float*)d_in[5];
  const float* bv = (const float*)d_in[6];
  const float* Wr = (const float*)d_in[7];
  const float* br = (const float*)d_in[8];
  const float* ub = (const float*)d_in[9];
  const float* vb = (const float*)d_in[10];
  const float* Wo = (const float*)d_in[11];
  const float* bo = (const float*)d_in[12];
  float* out = (float*)d_out;

  char* base = (char*)d_ws;
  size_t off = 0;
  auto alloc = [&](size_t bytes) {
    void* p = base + off;
    off += (bytes + 255) & ~(size_t)255;
    return p;
  };

  const size_t MAT = (size_t)4194304;  // 4096*1024
  u16*   xA    = (u16*)alloc((size_t)4352 * 1024 * 2);       // [x ; table]
  u16*   W3b   = (u16*)alloc((size_t)3328 * 1024 * 2);       // [Wq;Wv;Wk;UV;pad]
  u16*   Wob   = (u16*)alloc((size_t)1024 * 1024 * 2);
  float* b3    = (float*)alloc((size_t)3328 * 4);
  u16*   Ph    = (u16*)alloc((3 * MAT + 262144) * 2);        // Qh,VT,Kh,RPKh
  float* utb   = (float*)alloc((size_t)65536 * 4);
  float* dtb   = (float*)alloc((size_t)4096 * 4);
  u16*   vwb   = (u16*)alloc((size_t)4096 * 1024 * 2);

  u16* Qh   = Ph;
  u16* VTb  = Ph + MAT;       // transposed V: [bh][d][z]
  u16* Kh   = Ph + 2 * MAT;
  u16* RPKh = Ph + 3 * MAT;

  pack_k<<<dim3(8451), dim3(256), 0, stream>>>(x, Wq, Wk, Wv, Wo, bq, bk, bv,
                                               xA, W3b, Wob, b3);
  uv_fold_k<<<dim3(128), dim3(256), 0, stream>>>(Wr, br, ub, vb, W3b, b3);

  // fused Q|V^T|K + relpos-K + ut/dt projections: 4352 x 3328(pad) x 1024
  gemm256_k<<<dim3(221), dim3(512), 0, stream>>>(xA, W3b, b3, Ph,
                                                 1024, utb, dtb, 17, 13);

  // fused attention: one block per (b,h), wave-autonomous strips
  attn_k<<<dim3(256), dim3(512), 0, stream>>>(Qh, Kh, VTb, RPKh, utb, dtb, vwb);

  // output projection: 4096 x 1024 x 1024, fp32 out
  gemm_k<0><<<dim3(256), dim3(256), 0, stream>>>(vwb, Wob, bo, out,
                                                 4096, 1024, 1024, nullptr, nullptr,
                                                 32, 8);
}

// Round 8
// 200.666 us; speedup vs baseline: 1.6596x; 1.0447x over previous
//
#include <hip/hip_runtime.h>
#include <math.h>

constexpr int kB  = 16;
constexpr int kS  = 256;
constexpr int kD  = 1024;
constexpr int kH  = 16;
constexpr float kScale = 0.125f;  // 1/sqrt(64)

using bf16x8  = __attribute__((ext_vector_type(8))) short;
using floatx4 = __attribute__((ext_vector_type(4))) float;
typedef unsigned short u16;

__device__ __forceinline__ u16 f2bf(float x) {
  union { float f; unsigned u; } v; v.f = x;
  unsigned r = v.u + 0x7fffu + ((v.u >> 16) & 1u);
  return (u16)(r >> 16);
}
__device__ __forceinline__ float bf2f(u16 h) {
  union { unsigned u; float f; } v; v.u = ((unsigned)h) << 16;
  return v.f;
}

#define MFMA16(a, b, c) __builtin_amdgcn_mfma_f32_16x16x32_bf16((a), (b), (c), 0, 0, 0)
#define GLL16(gp, lp)                                                        \
  __builtin_amdgcn_global_load_lds(                                          \
      (const __attribute__((address_space(1))) unsigned int*)(gp),           \
      (__attribute__((address_space(3))) unsigned int*)(lp), 16, 0, 0)

// ---------------- pack + table: xA=[x;table], W3=[Wq;Wv;Wk], Wo, b3 ----------
__global__ __launch_bounds__(256) void pack_k(
    const float* __restrict__ x, const float* __restrict__ Wq,
    const float* __restrict__ Wk, const float* __restrict__ Wv,
    const float* __restrict__ Wo,
    const float* __restrict__ bq, const float* __restrict__ bk,
    const float* __restrict__ bv,
    u16* __restrict__ xA, u16* __restrict__ W3b, u16* __restrict__ Wob,
    float* __restrict__ b3) {
  size_t i = ((size_t)blockIdx.x * 256 + threadIdx.x) * 4;
  const size_t NX = (size_t)4194304, NW = (size_t)1048576;
  const size_t BEND = NX + 4 * NW + 3072;
  const float* src;
  u16* dst;
  size_t o;
  if (i < NX) {
    src = x; dst = xA; o = i;
  } else if (i < NX + 3 * NW) {
    size_t j = i - NX;
    int sel = (int)(j >> 20);
    o = j & (NW - 1);
    src = sel == 0 ? Wq : sel == 1 ? Wv : Wk;
    dst = W3b + (size_t)sel * NW;
  } else if (i < NX + 4 * NW) {
    o = i - NX - 3 * NW;
    src = Wo; dst = Wob;
  } else if (i < BEND) {
    size_t j = i - NX - 4 * NW;
    int sel = (int)(j >> 10);
    o = j & 1023;
    src = sel == 0 ? bq : sel == 1 ? bv : bk;
    *reinterpret_cast<float4*>(b3 + j) = *reinterpret_cast<const float4*>(src + o);
    return;
  } else if (i < BEND + 262144) {
    // sinusoid table rows p in [0,256), pos = p-255 -> xA rows 4096..4351
    size_t j = i - BEND;
    int p = (int)(j >> 10);
    int ibase = (int)(j & 1023);
    ushort4 r;
    u16* rr = (u16*)&r;
#pragma unroll
    for (int c = 0; c < 4; ++c) {
      int idx = ibase + c;
      float ex = (float)(2 * (idx / 2)) * (1.0f / 1024.0f);
      float scale = exp2f(ex * -13.287712379549449f);  // 10000^-ex
      float angle = (float)(p - 255) * scale;
      rr[c] = f2bf((idx & 1) ? cosf(angle) : sinf(angle));
    }
    *reinterpret_cast<ushort4*>(xA + NX + j) = r;
    return;
  } else {
    return;
  }
  float4 v = *reinterpret_cast<const float4*>(src + o);
  ushort4 r;
  r.x = f2bf(v.x); r.y = f2bf(v.y); r.z = f2bf(v.z); r.w = f2bf(v.w);
  *reinterpret_cast<ushort4*>(dst + o) = r;
}

// ---------------- rank-16 fold of Wr with u/v: W3b rows 3072..3103, b3 tail ------
__global__ __launch_bounds__(256) void uv_fold_k(
    const float* __restrict__ Wr, const float* __restrict__ br,
    const float* __restrict__ ub, const float* __restrict__ vb,
    u16* __restrict__ W3b, float* __restrict__ b3) {
  int gid = blockIdx.x * 256 + threadIdx.x;  // 32768
  int j = gid >> 10, c = gid & 1023;
  int h = j & 15;
  const float* bvec = (j < 16 ? ub : vb) + h * 64;
  const float* wcol = Wr + (size_t)(h * 64) * 1024 + c;
  float a = 0.f;
#pragma unroll
  for (int d = 0; d < 64; ++d) a += bvec[d] * wcol[(size_t)d * 1024];
  W3b[(size_t)(3072 + j) * 1024 + c] = f2bf(a);
  if (gid < 128) {
    float s = 0.f;
    if (gid < 32) {
      const float* bv2 = (gid < 16 ? ub : vb) + (gid & 15) * 64;
      const float* brp = br + (gid & 15) * 64;
      for (int d = 0; d < 64; ++d) s += bv2[d] * brp[d];
    }
    b3[3072 + gid] = s;
  }
}

// ---------------- legacy 128x128 bf16 MFMA GEMM (used for out-proj) ----------
template <int OUT_MODE>
__global__ __launch_bounds__(256) void gemm_k(
    const u16* __restrict__ A, const u16* __restrict__ W,
    const float* __restrict__ bias, void* __restrict__ Cv,
    int M, int N, int K, float* __restrict__ utb, float* __restrict__ dtb,
    int mTiles, int nTiles) {
  const int xcd = blockIdx.x & 7;
  const int li  = blockIdx.x >> 3;
  const int r0   = (xcd * mTiles) >> 3;
  const int rcnt = (((xcd + 1) * mTiles) >> 3) - r0;
  if (li >= rcnt * nTiles) return;   // uniform early-out (padded grid)
  const int bm = (r0 + li % rcnt) * 128;
  const int bn = (li / rcnt) * 128;

  __shared__ u16 Alds[128 * 64];
  __shared__ u16 Blds[128 * 64];
  const int t = threadIdx.x, w = t >> 6, l = t & 63;
  const int l15 = l & 15, quad = l >> 4;
  const int wm = w >> 1, wn = w & 1;
  const int lrow8 = l >> 3;
  const int kslot = l & 7;

  floatx4 acc[4][4] = {};

  for (int k0 = 0; k0 < K; k0 += 64) {
#pragma unroll
    for (int sg = 0; sg < 4; ++sg) {
      int mrow = sg * 32 + w * 8 + lrow8;
      int gk = (kslot ^ (mrow & 7)) << 3;
      GLL16(A + (size_t)(bm + mrow) * K + k0 + gk, Alds + (sg * 32 + w * 8) * 64);
      GLL16(W + (size_t)(bn + mrow) * K + k0 + gk, Blds + (sg * 32 + w * 8) * 64);
    }
    __syncthreads();
#pragma unroll
    for (int c = 0; c < 2; ++c) {
      bf16x8 af[4], bf[4];
#pragma unroll
      for (int mi = 0; mi < 4; ++mi) {
        int am = wm * 64 + mi * 16 + l15;
        af[mi] = *(const bf16x8*)(Alds + am * 64 + (((c * 4 + quad) ^ (am & 7)) << 3));
      }
#pragma unroll
      for (int ni = 0; ni < 4; ++ni) {
        int an = wn * 64 + ni * 16 + l15;
        bf[ni] = *(const bf16x8*)(Blds + an * 64 + (((c * 4 + quad) ^ (an & 7)) << 3));
      }
#pragma unroll
      for (int mi = 0; mi < 4; ++mi)
#pragma unroll
        for (int ni = 0; ni < 4; ++ni)
          acc[mi][ni] = MFMA16(af[mi], bf[ni], acc[mi][ni]);
    }
    __syncthreads();
  }

#pragma unroll
  for (int ni = 0; ni < 4; ++ni) {
    int col = bn + wn * 64 + ni * 16 + l15;
    float bv = bias[col];
#pragma unroll
    for (int mi = 0; mi < 4; ++mi) {
      int mrow = bm + wm * 64 + mi * 16 + quad * 4;
#pragma unroll
      for (int r = 0; r < 4; ++r) {
        float v = acc[mi][ni][r] + bv;
        int row = mrow + r;
        if (OUT_MODE == 0) {
          ((float*)Cv)[(size_t)row * N + col] = v;
        }
      }
    }
  }
}

// ---------------- 256x256 8-phase bf16 MFMA GEMM (T2+T3+T4+T5) ----------------
// Main loop unchanged (verified). Epilogue: fp32 LDS bounce; V blocks
// (bn in [1024,2048)) emit TRANSPOSED VT[bh][d][z]. Read mapping fixed
// (round-7 post-mortem): lane l owns column c=(w&3)*64+l -> per scalar-read
// instruction lr (and thus key) is wave-uniform, bank = (l^key)%32 is a
// bijection in l%32 -> 2 lanes/bank = conflict-free.
#define PHASE_MFMA(aa, bb, mh, nh, LG)                                         \
  do {                                                                         \
    __builtin_amdgcn_s_barrier();                                              \
    asm volatile("s_waitcnt lgkmcnt(" #LG ")" ::: "memory");                   \
    __builtin_amdgcn_sched_barrier(0);                                         \
    __builtin_amdgcn_s_setprio(1);                                             \
    _Pragma("unroll") for (int kc = 0; kc < 2; ++kc)                           \
        _Pragma("unroll") for (int i = 0; i < 4; ++i)                          \
            _Pragma("unroll") for (int j = 0; j < 2; ++j)                      \
                acc[(mh) * 4 + i][(nh) * 2 + j] = MFMA16(                      \
                    aa[kc][i], bb[kc][j], acc[(mh) * 4 + i][(nh) * 2 + j]);    \
    __builtin_amdgcn_s_setprio(0);                                             \
  } while (0)

__global__ __launch_bounds__(512, 2) void gemm256_k(
    const u16* __restrict__ A, const u16* __restrict__ W,
    const float* __restrict__ bias, u16* __restrict__ Cv,
    int K, float* __restrict__ utb, float* __restrict__ dtb,
    int mTiles, int nTiles) {
  const int nwg = mTiles * nTiles;
  const int qq = nwg >> 3, rr8 = nwg & 7;
  const int xcd = blockIdx.x & 7;
  const int wgid = (xcd < rr8 ? xcd * (qq + 1) : rr8 * (qq + 1) + (xcd - rr8) * qq)
                   + (blockIdx.x >> 3);
  const int bm = (wgid / nTiles) * 256;
  const int bn = (wgid % nTiles) * 256;

  __shared__ u16 lds[2 * 32768];     // 128 KiB: [buf][A 256x64 | B 256x64]

  const int t = threadIdx.x, w = t >> 6, l = t & 63;
  const int l15 = l & 15, quad = l >> 4;
  const int wm = w >> 2, wn = w & 3;

  const int NT = K >> 6;
  floatx4 acc[8][4] = {};

  auto stage = [&](int kt, int h) {
    const u16* srcm = (h < 2) ? A : W;
    const int baser = ((h < 2) ? bm : bn) + (h & 1) * 128;
    u16* dst = lds + (kt & 1) * 32768 + h * 8192 + w * 512;
    const int k0 = kt << 6;
#pragma unroll
    for (int j = 0; j < 2; ++j) {
      int sub = w * 8 + (l >> 3) + j * 64;
      int gk = ((l & 7) ^ (sub & 7)) << 3;
      GLL16(srcm + (size_t)(baser + sub) * K + k0 + gk, dst + j * 4096);
    }
  };

  bf16x8 a0[2][4], a1[2][4], b0[2][2], b1[2][2];

  auto readA = [&](bf16x8 (&aa)[2][4], const u16* LA, int hh) {
#pragma unroll
    for (int i = 0; i < 4; ++i) {
      int am = wm * 128 + hh * 64 + i * 16 + l15;
      const u16* p = LA + am * 64;
      aa[0][i] = *(const bf16x8*)(p + ((quad ^ (am & 7)) << 3));
      aa[1][i] = *(const bf16x8*)(p + (((4 + quad) ^ (am & 7)) << 3));
    }
  };
  auto readB = [&](bf16x8 (&bb)[2][2], const u16* LB, int hh) {
#pragma unroll
    for (int j = 0; j < 2; ++j) {
      int an = wn * 64 + hh * 32 + j * 16 + l15;
      const u16* p = LB + an * 64;
      bb[0][j] = *(const bf16x8*)(p + ((quad ^ (an & 7)) << 3));
      bb[1][j] = *(const bf16x8*)(p + (((4 + quad) ^ (an & 7)) << 3));
    }
  };

  stage(0, 2); stage(0, 3); stage(0, 0); stage(0, 1);
  stage(1, 2); stage(1, 3); stage(1, 0);
  asm volatile("s_waitcnt vmcnt(6)" ::: "memory");
  __builtin_amdgcn_s_barrier();
  readA(a0, lds, 0);
  readB(b0, lds + 16384, 0);

  for (int kt = 0; kt < NT; ++kt) {
    const u16* LA = lds + (kt & 1) * 32768;
    const u16* LB = LA + 16384;

    readB(b1, LB, 1);
    if (kt + 1 < NT) stage(kt + 1, 1);
    PHASE_MFMA(a0, b0, 0, 0, 4);
    __builtin_amdgcn_s_barrier();

    readA(a1, LA, 1);
    PHASE_MFMA(a0, b1, 0, 1, 8);
    __builtin_amdgcn_s_barrier();

    if (kt + 2 < NT) stage(kt + 2, 2);
    PHASE_MFMA(a1, b0, 1, 0, 0);
    __builtin_amdgcn_s_barrier();

    if (kt + 2 < NT) {
      stage(kt + 2, 3); stage(kt + 2, 0);
      asm volatile("s_waitcnt vmcnt(6)" ::: "memory");
    } else {
      asm volatile("s_waitcnt vmcnt(0)" ::: "memory");
    }
    __builtin_amdgcn_s_barrier();
    asm volatile("s_waitcnt lgkmcnt(0)" ::: "memory");
    __builtin_amdgcn_sched_barrier(0);
    if (kt + 1 < NT) {
      const u16* LAn = lds + ((kt + 1) & 1) * 32768;
      readA(a0, LAn, 0);
      readB(b0, LAn + 16384, 0);
    }
    __builtin_amdgcn_s_setprio(1);
#pragma unroll
    for (int kc = 0; kc < 2; ++kc)
#pragma unroll
      for (int i = 0; i < 4; ++i)
#pragma unroll
        for (int j = 0; j < 2; ++j)
          acc[4 + i][2 + j] = MFMA16(a1[kc][i], b1[kc][j], acc[4 + i][2 + j]);
    __builtin_amdgcn_s_setprio(0);
    __builtin_amdgcn_s_barrier();
  }

  // ---- epilogue: fp32 LDS bounce -> coalesced stores ----
  float* fl = (float*)lds;   // 128 x 256 fp32 = 128 KiB
  u16* VTp = Cv + (size_t)4194304;   // matsel==1 slot, transposed layout
#pragma unroll 1
  for (int half = 0; half < 2; ++half) {
    __syncthreads();
    if (wm == half) {
#pragma unroll
      for (int ni = 0; ni < 4; ++ni) {
        float bv = bias[bn + wn * 64 + ni * 16 + l15];
#pragma unroll
        for (int mi = 0; mi < 8; ++mi) {
#pragma unroll
          for (int r = 0; r < 4; ++r) {
            int lr = mi * 16 + quad * 4 + r;
            int c  = wn * 64 + ni * 16 + l15;
            int key = ((r ^ quad) & 3) << 4;
            fl[lr * 256 + (c ^ key)] = acc[mi][ni][r] + bv;
          }
        }
      }
    }
    __syncthreads();
    if (bn >= 1024 && bn < 2048) {
      // V block: emit transposed VT[bh][d][z]; bias already in fl.
      // Lane l owns column c=(w&3)*64+l; rows (w>>2)*64 + pp*8 .. +7.
      // Per-e read: lr wave-uniform -> key uniform -> bank=(l^key)%32,
      // bijective in l%32 -> 2 lanes/bank (free).
      if (bm < 4096) {
        int bb = bm >> 8;
        int c = (w & 3) * 64 + l;
        int rbase = (w >> 2) * 64;
        int col = bn + c;
        int hh2 = (col >> 6) & 15;
        u16* vpb = VTp + ((size_t)((bb << 4) + hh2) * 64 + (col & 63)) * 256 +
                   half * 128 + rbase;
#pragma unroll 1
        for (int pp = 0; pp < 8; ++pp) {
          int rb = rbase + pp * 8;
          u16 hv[8];
#pragma unroll
          for (int e = 0; e < 8; ++e) {
            int lr = rb + e;
            int key = ((lr & 3) ^ ((lr >> 2) & 3)) << 4;
            hv[e] = f2bf(fl[lr * 256 + (c ^ key)]);
          }
          *(ushort4*)(vpb + pp * 8) = *(ushort4*)&hv[0];
          *(ushort4*)(vpb + pp * 8 + 4) = *(ushort4*)&hv[4];
        }
      }
    } else {
#pragma unroll 1
      for (int cc = 0; cc < 4; ++cc) {
        int col0 = bn + cc * 64;
#pragma unroll
        for (int rr = 0; rr < 4; ++rr) {
          int lr = w * 16 + rr * 4 + quad;
          int key = ((rr ^ quad) & 3) << 4;
          float4 v = *(const float4*)&fl[lr * 256 + ((cc * 64 + (l15 << 2)) ^ key)];
          int grow = bm + half * 128 + lr;
          if (col0 < 3072) {
            ushort4 hvv;
            hvv.x = f2bf(v.x); hvv.y = f2bf(v.y); hvv.z = f2bf(v.z); hvv.w = f2bf(v.w);
            int matsel = col0 >> 10;
            int hh2 = (col0 >> 6) & 15;
            if (grow < 4096) {
              int bb = grow >> 8, ss = grow & 255;
              *(ushort4*)(Cv + (size_t)matsel * 4194304 +
                          ((size_t)(((bb << 4) + hh2) << 8) + ss) * 64 + (l15 << 2)) = hvv;
            } else if (matsel == 2) {
              int pp = grow - 4096;
              *(ushort4*)(Cv + (size_t)3 * 4194304 +
                          ((size_t)((hh2 << 8) + pp)) * 64 + (l15 << 2)) = hvv;
            }
          } else if (col0 < 3104) {
#pragma unroll
            for (int e = 0; e < 4; ++e) {
              int col = col0 + (l15 << 2) + e;
              float vv = e == 0 ? v.x : e == 1 ? v.y : e == 2 ? v.z : v.w;
              if (col < 3088) {
                if (grow < 4096)
                  utb[((grow >> 8) * 16 + (col - 3072)) * 256 + (grow & 255)] = vv;
              } else if (col < 3104) {
                if (grow >= 4096)
                  dtb[(col - 3088) * 256 + (grow - 4096)] = vv;
              }
            }
          }
        }
      }
    }
  }
}

// ---------------- fused attention v4: wave-autonomous, zero main-loop barriers ----
// (unchanged from round 7 — verified, ~28 us)
__global__ __launch_bounds__(512, 2) void attn_k(
    const u16* __restrict__ Qh, const u16* __restrict__ Kh,
    const u16* __restrict__ VT, const u16* __restrict__ RPKh,
    const float* __restrict__ ut, const float* __restrict__ dt,
    u16* __restrict__ vw) {
  __shared__ float ScW[8][16 * 260];   // 133 KB wave-private score tiles
  __shared__ float Ut[256], Dt[256];

  const int bh = blockIdx.x;           // b*16 + h
  const int h = bh & 15;
  const int b = bh >> 4;
  const size_t bh256 = (size_t)bh << 8;

  const int t = threadIdx.x, w = t >> 6, l = t & 63;
  const int l15 = l & 15, quad = l >> 4;

  if (t < 256) Ut[t] = ut[bh256 + t];
  else         Dt[t - 256] = dt[((size_t)h << 8) + (t - 256)];
  __syncthreads();

  float* scw = &ScW[w][0];

#pragma unroll 1
  for (int sidx = 0; sidx < 2; ++sidx) {
    const int s = sidx ? (15 - w) : w;   // wave-uniform strip index 0..15
    const int rB = s << 4;               // absolute base row

    // strip-head loads: qa, K tile 0, RP task 0
    bf16x8 qa0, qa1;
    {
      const u16* qp = Qh + (bh256 + rB + l15) * 64 + quad * 8;
      qa0 = *(const bf16x8*)qp;
      qa1 = *(const bf16x8*)(qp + 32);
    }
    bf16x8 kA0, kA1, kB0, kB1, rA0, rA1, rB0, rB1;
    {
      const u16* kp = Kh + (bh256 + l15) * 64 + quad * 8;
      kA0 = *(const bf16x8*)kp;
      kA1 = *(const bf16x8*)(kp + 32);
      const u16* rp = RPKh + (((size_t)h << 8) + 240 - rB + l15) * 64 + quad * 8;
      rA0 = *(const bf16x8*)rp;
      rA1 = *(const bf16x8*)(rp + 32);
    }

    // ---- interleaved QK(j) / QR(j), 1-deep parity prefetch ----
#pragma unroll
    for (int j = 0; j < 16; ++j) {
      if (j > s) break;
      if (j + 1 <= s) {
        const u16* kp = Kh + (bh256 + ((j + 1) << 4) + l15) * 64 + quad * 8;
        const u16* rp = RPKh + (((size_t)h << 8) + 240 - rB + ((j + 1) << 4) + l15) * 64 + quad * 8;
        if ((j + 1) & 1) {
          kB0 = *(const bf16x8*)kp; kB1 = *(const bf16x8*)(kp + 32);
          rB0 = *(const bf16x8*)rp; rB1 = *(const bf16x8*)(rp + 32);
        } else {
          kA0 = *(const bf16x8*)kp; kA1 = *(const bf16x8*)(kp + 32);
          rA0 = *(const bf16x8*)rp; rA1 = *(const bf16x8*)(rp + 32);
        }
      }
      bf16x8 k0 = (j & 1) ? kB0 : kA0;   // j compile-time -> static select
      bf16x8 k1 = (j & 1) ? kB1 : kA1;
      bf16x8 r0 = (j & 1) ? rB0 : rA0;
      bf16x8 r1 = (j & 1) ? rB1 : rA1;
      // QK(j): C[row=4q+r][z=16j+l15]
      {
        floatx4 acc = {};
        acc = MFMA16(qa0, k0, acc);
        acc = MFMA16(qa1, k1, acc);
        float u = Ut[(j << 4) + l15];
#pragma unroll
        for (int r = 0; r < 4; ++r)
          scw[(4 * quad + r) * 260 + (j << 4) + l15] = acc[r] + u;
      }
      // QR(j): += at z = 16j + l15 + 4quad + r - 15
      {
        floatx4 acc = {};
        acc = MFMA16(qa0, r0, acc);
        acc = MFMA16(qa1, r1, acc);
        float dv = Dt[240 - rB + (j << 4) + l15];
#pragma unroll
        for (int r = 0; r < 4; ++r) {
          int z = (j << 4) + l15 + 4 * quad + r - 15;
          if (z >= 0)
            scw[(4 * quad + r) * 260 + z] += acc[r] + dv;
        }
      }
    }

    // ---- softmax pass 1: masked max (lane owns row l15) ----
    const int kcmax = s >> 1;
    const int Rabs = rB + l15;           // causal bound z <= Rabs
    float m = -1e30f;
#pragma unroll
    for (int kc = 0; kc < 8; ++kc) {
      if (kc > kcmax) break;
      const float* sp = scw + l15 * 260 + kc * 32 + quad * 8;
      floatx4 v0 = *(const floatx4*)sp;
      floatx4 v1 = *(const floatx4*)(sp + 4);
#pragma unroll
      for (int e = 0; e < 4; ++e) {
        int z = kc * 32 + quad * 8 + e;
        if (z <= Rabs) m = fmaxf(m, v0[e]);
        if (z + 4 <= Rabs) m = fmaxf(m, v1[e]);
      }
    }
    m = fmaxf(m, __shfl_xor(m, 16));
    m = fmaxf(m, __shfl_xor(m, 32));
    m *= kScale;

    // ---- pass 2: exp + PV (V^T fragments from global, 1-deep prefetch) ----
    floatx4 oacc[4] = {};
    float sum = 0.f;
    bf16x8 vA[4], vB[4];
    {
      const u16* vp = VT + ((size_t)bh * 64 + l15) * 256 + quad * 8;
#pragma unroll
      for (int nt = 0; nt < 4; ++nt)
        vA[nt] = *(const bf16x8*)(vp + (size_t)nt * 16 * 256);
    }
#pragma unroll
    for (int kc = 0; kc < 8; ++kc) {
      if (kc > kcmax) break;
      if (kc + 1 <= kcmax) {
        const u16* vp = VT + ((size_t)bh * 64 + l15) * 256 + (kc + 1) * 32 + quad * 8;
        if ((kc + 1) & 1) {
#pragma unroll
          for (int nt = 0; nt < 4; ++nt)
            vB[nt] = *(const bf16x8*)(vp + (size_t)nt * 16 * 256);
        } else {
#pragma unroll
          for (int nt = 0; nt < 4; ++nt)
            vA[nt] = *(const bf16x8*)(vp + (size_t)nt * 16 * 256);
        }
      }
      const float* sp = scw + l15 * 260 + kc * 32 + quad * 8;
      floatx4 v0 = *(const floatx4*)sp;
      floatx4 v1 = *(const floatx4*)(sp + 4);
      bf16x8 pa;
#pragma unroll
      for (int e = 0; e < 4; ++e) {
        int z = kc * 32 + quad * 8 + e;
        float p0 = (z <= Rabs) ? __expf(v0[e] * kScale - m) : 0.f;
        float p1 = (z + 4 <= Rabs) ? __expf(v1[e] * kScale - m) : 0.f;
        sum += p0 + p1;
        pa[e] = (short)f2bf(p0);
        pa[e + 4] = (short)f2bf(p1);
      }
#pragma unroll
      for (int nt = 0; nt < 4; ++nt)
        oacc[nt] = MFMA16(pa, (kc & 1) ? vB[nt] : vA[nt], oacc[nt]);
    }
    sum += __shfl_xor(sum, 16);
    sum += __shfl_xor(sum, 32);
    float rinv = 1.f / sum;

    // ---- store: row = rB + 4quad + r; rinv transposed via shfl ----
#pragma unroll
    for (int r = 0; r < 4; ++r) {
      float rs = __shfl(rinv, 4 * quad + r);
      int row = rB + 4 * quad + r;
#pragma unroll
      for (int nt = 0; nt < 4; ++nt)
        vw[(size_t)(b * 256 + row) * 1024 + h * 64 + nt * 16 + l15] =
            f2bf(oacc[nt][r] * rs);
    }
  }
}

extern "C" void kernel_launch(void* const* d_in, const int* in_sizes, int n_in,
                              void* d_out, int out_size, void* d_ws, size_t ws_size,
                              hipStream_t stream) {
  const float* x  = (const float*)d_in[0];
  const float* Wq = (const float*)d_in[1];
  const float* bq = (const float*)d_in[2];
  const float* Wk = (const float*)d_in[3];
  const float* bk = (const float*)d_in[4];
  const float* Wv = (const float*)d_in[5];
  const float* bv = (const float*)d_in[6];
  const float* Wr = (const float*)d_in[7];
  const float* br = (const float*)d_in[8];
  const float* ub = (const float*)d_in[9];
  const float* vb = (const float*)d_in[10];
  const float* Wo = (const float*)d_in[11];
  const float* bo = (const float*)d_in[12];
  float* out = (float*)d_out;

  char* base = (char*)d_ws;
  size_t off = 0;
  auto alloc = [&](size_t bytes) {
    void* p = base + off;
    off += (bytes + 255) & ~(size_t)255;
    return p;
  };

  const size_t MAT = (size_t)4194304;  // 4096*1024
  u16*   xA    = (u16*)alloc((size_t)4352 * 1024 * 2);       // [x ; table]
  u16*   W3b   = (u16*)alloc((size_t)3328 * 1024 * 2);       // [Wq;Wv;Wk;UV;pad]
  u16*   Wob   = (u16*)alloc((size_t)1024 * 1024 * 2);
  float* b3    = (float*)alloc((size_t)3328 * 4);
  u16*   Ph    = (u16*)alloc((3 * MAT + 262144) * 2);        // Qh,VT,Kh,RPKh
  float* utb   = (float*)alloc((size_t)65536 * 4);
  float* dtb   = (float*)alloc((size_t)4096 * 4);
  u16*   vwb   = (u16*)alloc((size_t)4096 * 1024 * 2);

  u16* Qh   = Ph;
  u16* VTb  = Ph + MAT;       // transposed V: [bh][d][z]
  u16* Kh   = Ph + 2 * MAT;
  u16* RPKh = Ph + 3 * MAT;

  pack_k<<<dim3(8451), dim3(256), 0, stream>>>(x, Wq, Wk, Wv, Wo, bq, bk, bv,
                                               xA, W3b, Wob, b3);
  uv_fold_k<<<dim3(128), dim3(256), 0, stream>>>(Wr, br, ub, vb, W3b, b3);

  // fused Q|V^T|K + relpos-K + ut/dt projections: 4352 x 3328(pad) x 1024
  gemm256_k<<<dim3(221), dim3(512), 0, stream>>>(xA, W3b, b3, Ph,
                                                 1024, utb, dtb, 17, 13);

  // fused attention: one block per (b,h), wave-autonomous strips
  attn_k<<<dim3(256), dim3(512), 0, stream>>>(Qh, Kh, VTb, RPKh, utb, dtb, vwb);

  // output projection: 4096 x 1024 x 1024, fp32 out
  gemm_k<0><<<dim3(256), dim3(256), 0, stream>>>(vwb, Wob, bo, out,
                                                 4096, 1024, 1024, nullptr, nullptr,
                                                 32, 8);
}

// Round 9
// 195.946 us; speedup vs baseline: 1.6996x; 1.0241x over previous
//
#include <hip/hip_runtime.h>
#include <math.h>

constexpr int kB  = 16;
constexpr int kS  = 256;
constexpr int kD  = 1024;
constexpr int kH  = 16;
constexpr float kScale = 0.125f;  // 1/sqrt(64)

using bf16x8  = __attribute__((ext_vector_type(8))) short;
using floatx4 = __attribute__((ext_vector_type(4))) float;
typedef unsigned short u16;

__device__ __forceinline__ u16 f2bf(float x) {
  union { float f; unsigned u; } v; v.f = x;
  unsigned r = v.u + 0x7fffu + ((v.u >> 16) & 1u);
  return (u16)(r >> 16);
}
__device__ __forceinline__ float bf2f(u16 h) {
  union { unsigned u; float f; } v; v.u = ((unsigned)h) << 16;
  return v.f;
}

#define MFMA16(a, b, c) __builtin_amdgcn_mfma_f32_16x16x32_bf16((a), (b), (c), 0, 0, 0)
#define GLL16(gp, lp)                                                        \
  __builtin_amdgcn_global_load_lds(                                          \
      (const __attribute__((address_space(1))) unsigned int*)(gp),           \
      (__attribute__((address_space(3))) unsigned int*)(lp), 16, 0, 0)

// ------- pack + table + uv-fold (merged): blocks <8451 pack, >=8451 fold -------
__global__ __launch_bounds__(256) void pack_k(
    const float* __restrict__ x, const float* __restrict__ Wq,
    const float* __restrict__ Wk, const float* __restrict__ Wv,
    const float* __restrict__ Wo,
    const float* __restrict__ bq, const float* __restrict__ bk,
    const float* __restrict__ bv,
    const float* __restrict__ Wr, const float* __restrict__ br,
    const float* __restrict__ ub, const float* __restrict__ vb,
    u16* __restrict__ xA, u16* __restrict__ W3b, u16* __restrict__ Wob,
    float* __restrict__ b3) {
  if (blockIdx.x >= 8451) {
    // ---- rank-16 fold of Wr with u/v: W3b rows 3072..3103, b3 tail ----
    int gid = (blockIdx.x - 8451) * 256 + threadIdx.x;  // 32768
    int j = gid >> 10, c = gid & 1023;
    int h = j & 15;
    const float* bvec = (j < 16 ? ub : vb) + h * 64;
    const float* wcol = Wr + (size_t)(h * 64) * 1024 + c;
    float a = 0.f;
#pragma unroll
    for (int d = 0; d < 64; ++d) a += bvec[d] * wcol[(size_t)d * 1024];
    W3b[(size_t)(3072 + j) * 1024 + c] = f2bf(a);
    if (gid < 128) {
      float s = 0.f;
      if (gid < 32) {
        const float* bv2 = (gid < 16 ? ub : vb) + (gid & 15) * 64;
        const float* brp = br + (gid & 15) * 64;
        for (int d = 0; d < 64; ++d) s += bv2[d] * brp[d];
      }
      b3[3072 + gid] = s;
    }
    return;
  }
  size_t i = ((size_t)blockIdx.x * 256 + threadIdx.x) * 4;
  const size_t NX = (size_t)4194304, NW = (size_t)1048576;
  const size_t BEND = NX + 4 * NW + 3072;
  const float* src;
  u16* dst;
  size_t o;
  if (i < NX) {
    src = x; dst = xA; o = i;
  } else if (i < NX + 3 * NW) {
    size_t j = i - NX;
    int sel = (int)(j >> 20);
    o = j & (NW - 1);
    src = sel == 0 ? Wq : sel == 1 ? Wv : Wk;
    dst = W3b + (size_t)sel * NW;
  } else if (i < NX + 4 * NW) {
    o = i - NX - 3 * NW;
    src = Wo; dst = Wob;
  } else if (i < BEND) {
    size_t j = i - NX - 4 * NW;
    int sel = (int)(j >> 10);
    o = j & 1023;
    src = sel == 0 ? bq : sel == 1 ? bv : bk;
    *reinterpret_cast<float4*>(b3 + j) = *reinterpret_cast<const float4*>(src + o);
    return;
  } else if (i < BEND + 262144) {
    // sinusoid table rows p in [0,256), pos = p-255 -> xA rows 4096..4351
    size_t j = i - BEND;
    int p = (int)(j >> 10);
    int ibase = (int)(j & 1023);
    ushort4 r;
    u16* rr = (u16*)&r;
#pragma unroll
    for (int c = 0; c < 4; ++c) {
      int idx = ibase + c;
      float ex = (float)(2 * (idx / 2)) * (1.0f / 1024.0f);
      float scale = exp2f(ex * -13.287712379549449f);  // 10000^-ex
      float angle = (float)(p - 255) * scale;
      rr[c] = f2bf((idx & 1) ? cosf(angle) : sinf(angle));
    }
    *reinterpret_cast<ushort4*>(xA + NX + j) = r;
    return;
  } else {
    return;
  }
  float4 v = *reinterpret_cast<const float4*>(src + o);
  ushort4 r;
  r.x = f2bf(v.x); r.y = f2bf(v.y); r.z = f2bf(v.z); r.w = f2bf(v.w);
  *reinterpret_cast<ushort4*>(dst + o) = r;
}

// ---------------- out-proj 128x128 bf16 MFMA GEMM, 2-phase prefetch ----------
// T3-minimum (guide recipe): double-buffered LDS (64 KB -> 2 blocks/CU);
// stage(kt+1) issued BEFORE compute(kt); one vmcnt(0)+barrier per K-tile.
// Race audit: each wave's ds_reads of buf[kt&1] are consumed by its MFMAs
// (compiler lgkm waits) before its barrier arrival; iter kt+1's stage into
// buf[kt&1] starts only after that barrier -> safe.
__global__ __launch_bounds__(256) void gemm_k(
    const u16* __restrict__ A, const u16* __restrict__ W,
    const float* __restrict__ bias, float* __restrict__ Cv,
    int M, int N, int K, int mTiles, int nTiles) {
  const int xcd = blockIdx.x & 7;
  const int li  = blockIdx.x >> 3;
  const int r0   = (xcd * mTiles) >> 3;
  const int rcnt = (((xcd + 1) * mTiles) >> 3) - r0;
  if (li >= rcnt * nTiles) return;   // uniform early-out (padded grid)
  const int bm = (r0 + li % rcnt) * 128;
  const int bn = (li / rcnt) * 128;

  __shared__ u16 Alds[2][128 * 64];
  __shared__ u16 Blds[2][128 * 64];
  const int t = threadIdx.x, w = t >> 6, l = t & 63;
  const int l15 = l & 15, quad = l >> 4;
  const int wm = w >> 1, wn = w & 1;
  const int lrow8 = l >> 3;
  const int kslot = l & 7;
  const int NT = K >> 6;

  floatx4 acc[4][4] = {};

  auto stage = [&](int kt) {
    const int buf = kt & 1, k0 = kt << 6;
#pragma unroll
    for (int sg = 0; sg < 4; ++sg) {
      int mrow = sg * 32 + w * 8 + lrow8;
      int gk = (kslot ^ (mrow & 7)) << 3;
      GLL16(A + (size_t)(bm + mrow) * K + k0 + gk, Alds[buf] + (sg * 32 + w * 8) * 64);
      GLL16(W + (size_t)(bn + mrow) * K + k0 + gk, Blds[buf] + (sg * 32 + w * 8) * 64);
    }
  };

  stage(0);
  asm volatile("s_waitcnt vmcnt(0)" ::: "memory");
  __syncthreads();

  for (int kt = 0; kt < NT; ++kt) {
    if (kt + 1 < NT) stage(kt + 1);
    const u16* AL = Alds[kt & 1];
    const u16* BL = Blds[kt & 1];
#pragma unroll
    for (int c = 0; c < 2; ++c) {
      bf16x8 af[4], bf[4];
#pragma unroll
      for (int mi = 0; mi < 4; ++mi) {
        int am = wm * 64 + mi * 16 + l15;
        af[mi] = *(const bf16x8*)(AL + am * 64 + (((c * 4 + quad) ^ (am & 7)) << 3));
      }
#pragma unroll
      for (int ni = 0; ni < 4; ++ni) {
        int an = wn * 64 + ni * 16 + l15;
        bf[ni] = *(const bf16x8*)(BL + an * 64 + (((c * 4 + quad) ^ (an & 7)) << 3));
      }
#pragma unroll
      for (int mi = 0; mi < 4; ++mi)
#pragma unroll
        for (int ni = 0; ni < 4; ++ni)
          acc[mi][ni] = MFMA16(af[mi], bf[ni], acc[mi][ni]);
    }
    asm volatile("s_waitcnt vmcnt(0)" ::: "memory");
    __syncthreads();
  }

#pragma unroll
  for (int ni = 0; ni < 4; ++ni) {
    int col = bn + wn * 64 + ni * 16 + l15;
    float bv = bias[col];
#pragma unroll
    for (int mi = 0; mi < 4; ++mi) {
      int mrow = bm + wm * 64 + mi * 16 + quad * 4;
#pragma unroll
      for (int r = 0; r < 4; ++r) {
        Cv[(size_t)(mrow + r) * N + col] = acc[mi][ni][r] + bv;
      }
    }
  }
}

// ---------------- 256x256 8-phase bf16 MFMA GEMM (T2+T3+T4+T5) ----------------
// (unchanged from round 8 — verified: 49.8 us, 157K conflicts)
#define PHASE_MFMA(aa, bb, mh, nh, LG)                                         \
  do {                                                                         \
    __builtin_amdgcn_s_barrier();                                              \
    asm volatile("s_waitcnt lgkmcnt(" #LG ")" ::: "memory");                   \
    __builtin_amdgcn_sched_barrier(0);                                         \
    __builtin_amdgcn_s_setprio(1);                                             \
    _Pragma("unroll") for (int kc = 0; kc < 2; ++kc)                           \
        _Pragma("unroll") for (int i = 0; i < 4; ++i)                          \
            _Pragma("unroll") for (int j = 0; j < 2; ++j)                      \
                acc[(mh) * 4 + i][(nh) * 2 + j] = MFMA16(                      \
                    aa[kc][i], bb[kc][j], acc[(mh) * 4 + i][(nh) * 2 + j]);    \
    __builtin_amdgcn_s_setprio(0);                                             \
  } while (0)

__global__ __launch_bounds__(512, 2) void gemm256_k(
    const u16* __restrict__ A, const u16* __restrict__ W,
    const float* __restrict__ bias, u16* __restrict__ Cv,
    int K, float* __restrict__ utb, float* __restrict__ dtb,
    int mTiles, int nTiles) {
  const int nwg = mTiles * nTiles;
  const int qq = nwg >> 3, rr8 = nwg & 7;
  const int xcd = blockIdx.x & 7;
  const int wgid = (xcd < rr8 ? xcd * (qq + 1) : rr8 * (qq + 1) + (xcd - rr8) * qq)
                   + (blockIdx.x >> 3);
  const int bm = (wgid / nTiles) * 256;
  const int bn = (wgid % nTiles) * 256;

  __shared__ u16 lds[2 * 32768];     // 128 KiB: [buf][A 256x64 | B 256x64]

  const int t = threadIdx.x, w = t >> 6, l = t & 63;
  const int l15 = l & 15, quad = l >> 4;
  const int wm = w >> 2, wn = w & 3;

  const int NT = K >> 6;
  floatx4 acc[8][4] = {};

  auto stage = [&](int kt, int h) {
    const u16* srcm = (h < 2) ? A : W;
    const int baser = ((h < 2) ? bm : bn) + (h & 1) * 128;
    u16* dst = lds + (kt & 1) * 32768 + h * 8192 + w * 512;
    const int k0 = kt << 6;
#pragma unroll
    for (int j = 0; j < 2; ++j) {
      int sub = w * 8 + (l >> 3) + j * 64;
      int gk = ((l & 7) ^ (sub & 7)) << 3;
      GLL16(srcm + (size_t)(baser + sub) * K + k0 + gk, dst + j * 4096);
    }
  };

  bf16x8 a0[2][4], a1[2][4], b0[2][2], b1[2][2];

  auto readA = [&](bf16x8 (&aa)[2][4], const u16* LA, int hh) {
#pragma unroll
    for (int i = 0; i < 4; ++i) {
      int am = wm * 128 + hh * 64 + i * 16 + l15;
      const u16* p = LA + am * 64;
      aa[0][i] = *(const bf16x8*)(p + ((quad ^ (am & 7)) << 3));
      aa[1][i] = *(const bf16x8*)(p + (((4 + quad) ^ (am & 7)) << 3));
    }
  };
  auto readB = [&](bf16x8 (&bb)[2][2], const u16* LB, int hh) {
#pragma unroll
    for (int j = 0; j < 2; ++j) {
      int an = wn * 64 + hh * 32 + j * 16 + l15;
      const u16* p = LB + an * 64;
      bb[0][j] = *(const bf16x8*)(p + ((quad ^ (an & 7)) << 3));
      bb[1][j] = *(const bf16x8*)(p + (((4 + quad) ^ (an & 7)) << 3));
    }
  };

  stage(0, 2); stage(0, 3); stage(0, 0); stage(0, 1);
  stage(1, 2); stage(1, 3); stage(1, 0);
  asm volatile("s_waitcnt vmcnt(6)" ::: "memory");
  __builtin_amdgcn_s_barrier();
  readA(a0, lds, 0);
  readB(b0, lds + 16384, 0);

  for (int kt = 0; kt < NT; ++kt) {
    const u16* LA = lds + (kt & 1) * 32768;
    const u16* LB = LA + 16384;

    readB(b1, LB, 1);
    if (kt + 1 < NT) stage(kt + 1, 1);
    PHASE_MFMA(a0, b0, 0, 0, 4);
    __builtin_amdgcn_s_barrier();

    readA(a1, LA, 1);
    PHASE_MFMA(a0, b1, 0, 1, 8);
    __builtin_amdgcn_s_barrier();

    if (kt + 2 < NT) stage(kt + 2, 2);
    PHASE_MFMA(a1, b0, 1, 0, 0);
    __builtin_amdgcn_s_barrier();

    if (kt + 2 < NT) {
      stage(kt + 2, 3); stage(kt + 2, 0);
      asm volatile("s_waitcnt vmcnt(6)" ::: "memory");
    } else {
      asm volatile("s_waitcnt vmcnt(0)" ::: "memory");
    }
    __builtin_amdgcn_s_barrier();
    asm volatile("s_waitcnt lgkmcnt(0)" ::: "memory");
    __builtin_amdgcn_sched_barrier(0);
    if (kt + 1 < NT) {
      const u16* LAn = lds + ((kt + 1) & 1) * 32768;
      readA(a0, LAn, 0);
      readB(b0, LAn + 16384, 0);
    }
    __builtin_amdgcn_s_setprio(1);
#pragma unroll
    for (int kc = 0; kc < 2; ++kc)
#pragma unroll
      for (int i = 0; i < 4; ++i)
#pragma unroll
        for (int j = 0; j < 2; ++j)
          acc[4 + i][2 + j] = MFMA16(a1[kc][i], b1[kc][j], acc[4 + i][2 + j]);
    __builtin_amdgcn_s_setprio(0);
    __builtin_amdgcn_s_barrier();
  }

  // ---- epilogue: fp32 LDS bounce -> coalesced stores ----
  float* fl = (float*)lds;   // 128 x 256 fp32 = 128 KiB
  u16* VTp = Cv + (size_t)4194304;   // matsel==1 slot, transposed layout
#pragma unroll 1
  for (int half = 0; half < 2; ++half) {
    __syncthreads();
    if (wm == half) {
#pragma unroll
      for (int ni = 0; ni < 4; ++ni) {
        float bv = bias[bn + wn * 64 + ni * 16 + l15];
#pragma unroll
        for (int mi = 0; mi < 8; ++mi) {
#pragma unroll
          for (int r = 0; r < 4; ++r) {
            int lr = mi * 16 + quad * 4 + r;
            int c  = wn * 64 + ni * 16 + l15;
            int key = ((r ^ quad) & 3) << 4;
            fl[lr * 256 + (c ^ key)] = acc[mi][ni][r] + bv;
          }
        }
      }
    }
    __syncthreads();
    if (bn >= 1024 && bn < 2048) {
      // V block: emit transposed VT[bh][d][z]; bias already in fl.
      if (bm < 4096) {
        int bb = bm >> 8;
        int c = (w & 3) * 64 + l;
        int rbase = (w >> 2) * 64;
        int col = bn + c;
        int hh2 = (col >> 6) & 15;
        u16* vpb = VTp + ((size_t)((bb << 4) + hh2) * 64 + (col & 63)) * 256 +
                   half * 128 + rbase;
#pragma unroll 1
        for (int pp = 0; pp < 8; ++pp) {
          int rb = rbase + pp * 8;
          u16 hv[8];
#pragma unroll
          for (int e = 0; e < 8; ++e) {
            int lr = rb + e;
            int key = ((lr & 3) ^ ((lr >> 2) & 3)) << 4;
            hv[e] = f2bf(fl[lr * 256 + (c ^ key)]);
          }
          *(ushort4*)(vpb + pp * 8) = *(ushort4*)&hv[0];
          *(ushort4*)(vpb + pp * 8 + 4) = *(ushort4*)&hv[4];
        }
      }
    } else {
#pragma unroll 1
      for (int cc = 0; cc < 4; ++cc) {
        int col0 = bn + cc * 64;
#pragma unroll
        for (int rr = 0; rr < 4; ++rr) {
          int lr = w * 16 + rr * 4 + quad;
          int key = ((rr ^ quad) & 3) << 4;
          float4 v = *(const float4*)&fl[lr * 256 + ((cc * 64 + (l15 << 2)) ^ key)];
          int grow = bm + half * 128 + lr;
          if (col0 < 3072) {
            ushort4 hvv;
            hvv.x = f2bf(v.x); hvv.y = f2bf(v.y); hvv.z = f2bf(v.z); hvv.w = f2bf(v.w);
            int matsel = col0 >> 10;
            int hh2 = (col0 >> 6) & 15;
            if (grow < 4096) {
              int bb = grow >> 8, ss = grow & 255;
              *(ushort4*)(Cv + (size_t)matsel * 4194304 +
                          ((size_t)(((bb << 4) + hh2) << 8) + ss) * 64 + (l15 << 2)) = hvv;
            } else if (matsel == 2) {
              int pp = grow - 4096;
              *(ushort4*)(Cv + (size_t)3 * 4194304 +
                          ((size_t)((hh2 << 8) + pp)) * 64 + (l15 << 2)) = hvv;
            }
          } else if (col0 < 3104) {
#pragma unroll
            for (int e = 0; e < 4; ++e) {
              int col = col0 + (l15 << 2) + e;
              float vv = e == 0 ? v.x : e == 1 ? v.y : e == 2 ? v.z : v.w;
              if (col < 3088) {
                if (grow < 4096)
                  utb[((grow >> 8) * 16 + (col - 3072)) * 256 + (grow & 255)] = vv;
              } else if (col < 3104) {
                if (grow >= 4096)
                  dtb[(col - 3088) * 256 + (grow - 4096)] = vv;
              }
            }
          }
        }
      }
    }
  }
}

// ---------------- fused attention v4: wave-autonomous, zero main-loop barriers ----
// (unchanged from round 8 — verified)
__global__ __launch_bounds__(512, 2) void attn_k(
    const u16* __restrict__ Qh, const u16* __restrict__ Kh,
    const u16* __restrict__ VT, const u16* __restrict__ RPKh,
    const float* __restrict__ ut, const float* __restrict__ dt,
    u16* __restrict__ vw) {
  __shared__ float ScW[8][16 * 260];   // 133 KB wave-private score tiles
  __shared__ float Ut[256], Dt[256];

  const int bh = blockIdx.x;           // b*16 + h
  const int h = bh & 15;
  const int b = bh >> 4;
  const size_t bh256 = (size_t)bh << 8;

  const int t = threadIdx.x, w = t >> 6, l = t & 63;
  const int l15 = l & 15, quad = l >> 4;

  if (t < 256) Ut[t] = ut[bh256 + t];
  else         Dt[t - 256] = dt[((size_t)h << 8) + (t - 256)];
  __syncthreads();

  float* scw = &ScW[w][0];

#pragma unroll 1
  for (int sidx = 0; sidx < 2; ++sidx) {
    const int s = sidx ? (15 - w) : w;   // wave-uniform strip index 0..15
    const int rB = s << 4;               // absolute base row

    // strip-head loads: qa, K tile 0, RP task 0
    bf16x8 qa0, qa1;
    {
      const u16* qp = Qh + (bh256 + rB + l15) * 64 + quad * 8;
      qa0 = *(const bf16x8*)qp;
      qa1 = *(const bf16x8*)(qp + 32);
    }
    bf16x8 kA0, kA1, kB0, kB1, rA0, rA1, rB0, rB1;
    {
      const u16* kp = Kh + (bh256 + l15) * 64 + quad * 8;
      kA0 = *(const bf16x8*)kp;
      kA1 = *(const bf16x8*)(kp + 32);
      const u16* rp = RPKh + (((size_t)h << 8) + 240 - rB + l15) * 64 + quad * 8;
      rA0 = *(const bf16x8*)rp;
      rA1 = *(const bf16x8*)(rp + 32);
    }

    // ---- interleaved QK(j) / QR(j), 1-deep parity prefetch ----
#pragma unroll
    for (int j = 0; j < 16; ++j) {
      if (j > s) break;
      if (j + 1 <= s) {
        const u16* kp = Kh + (bh256 + ((j + 1) << 4) + l15) * 64 + quad * 8;
        const u16* rp = RPKh + (((size_t)h << 8) + 240 - rB + ((j + 1) << 4) + l15) * 64 + quad * 8;
        if ((j + 1) & 1) {
          kB0 = *(const bf16x8*)kp; kB1 = *(const bf16x8*)(kp + 32);
          rB0 = *(const bf16x8*)rp; rB1 = *(const bf16x8*)(rp + 32);
        } else {
          kA0 = *(const bf16x8*)kp; kA1 = *(const bf16x8*)(kp + 32);
          rA0 = *(const bf16x8*)rp; rA1 = *(const bf16x8*)(rp + 32);
        }
      }
      bf16x8 k0 = (j & 1) ? kB0 : kA0;   // j compile-time -> static select
      bf16x8 k1 = (j & 1) ? kB1 : kA1;
      bf16x8 r0 = (j & 1) ? rB0 : rA0;
      bf16x8 r1 = (j & 1) ? rB1 : rA1;
      // QK(j): C[row=4q+r][z=16j+l15]
      {
        floatx4 acc = {};
        acc = MFMA16(qa0, k0, acc);
        acc = MFMA16(qa1, k1, acc);
        float u = Ut[(j << 4) + l15];
#pragma unroll
        for (int r = 0; r < 4; ++r)
          scw[(4 * quad + r) * 260 + (j << 4) + l15] = acc[r] + u;
      }
      // QR(j): += at z = 16j + l15 + 4quad + r - 15
      {
        floatx4 acc = {};
        acc = MFMA16(qa0, r0, acc);
        acc = MFMA16(qa1, r1, acc);
        float dv = Dt[240 - rB + (j << 4) + l15];
#pragma unroll
        for (int r = 0; r < 4; ++r) {
          int z = (j << 4) + l15 + 4 * quad + r - 15;
          if (z >= 0)
            scw[(4 * quad + r) * 260 + z] += acc[r] + dv;
        }
      }
    }

    // ---- softmax pass 1: masked max (lane owns row l15) ----
    const int kcmax = s >> 1;
    const int Rabs = rB + l15;           // causal bound z <= Rabs
    float m = -1e30f;
#pragma unroll
    for (int kc = 0; kc < 8; ++kc) {
      if (kc > kcmax) break;
      const float* sp = scw + l15 * 260 + kc * 32 + quad * 8;
      floatx4 v0 = *(const floatx4*)sp;
      floatx4 v1 = *(const floatx4*)(sp + 4);
#pragma unroll
      for (int e = 0; e < 4; ++e) {
        int z = kc * 32 + quad * 8 + e;
        if (z <= Rabs) m = fmaxf(m, v0[e]);
        if (z + 4 <= Rabs) m = fmaxf(m, v1[e]);
      }
    }
    m = fmaxf(m, __shfl_xor(m, 16));
    m = fmaxf(m, __shfl_xor(m, 32));
    m *= kScale;

    // ---- pass 2: exp + PV (V^T fragments from global, 1-deep prefetch) ----
    floatx4 oacc[4] = {};
    float sum = 0.f;
    bf16x8 vA[4], vB[4];
    {
      const u16* vp = VT + ((size_t)bh * 64 + l15) * 256 + quad * 8;
#pragma unroll
      for (int nt = 0; nt < 4; ++nt)
        vA[nt] = *(const bf16x8*)(vp + (size_t)nt * 16 * 256);
    }
#pragma unroll
    for (int kc = 0; kc < 8; ++kc) {
      if (kc > kcmax) break;
      if (kc + 1 <= kcmax) {
        const u16* vp = VT + ((size_t)bh * 64 + l15) * 256 + (kc + 1) * 32 + quad * 8;
        if ((kc + 1) & 1) {
#pragma unroll
          for (int nt = 0; nt < 4; ++nt)
            vB[nt] = *(const bf16x8*)(vp + (size_t)nt * 16 * 256);
        } else {
#pragma unroll
          for (int nt = 0; nt < 4; ++nt)
            vA[nt] = *(const bf16x8*)(vp + (size_t)nt * 16 * 256);
        }
      }
      const float* sp = scw + l15 * 260 + kc * 32 + quad * 8;
      floatx4 v0 = *(const floatx4*)sp;
      floatx4 v1 = *(const floatx4*)(sp + 4);
      bf16x8 pa;
#pragma unroll
      for (int e = 0; e < 4; ++e) {
        int z = kc * 32 + quad * 8 + e;
        float p0 = (z <= Rabs) ? __expf(v0[e] * kScale - m) : 0.f;
        float p1 = (z + 4 <= Rabs) ? __expf(v1[e] * kScale - m) : 0.f;
        sum += p0 + p1;
        pa[e] = (short)f2bf(p0);
        pa[e + 4] = (short)f2bf(p1);
      }
#pragma unroll
      for (int nt = 0; nt < 4; ++nt)
        oacc[nt] = MFMA16(pa, (kc & 1) ? vB[nt] : vA[nt], oacc[nt]);
    }
    sum += __shfl_xor(sum, 16);
    sum += __shfl_xor(sum, 32);
    float rinv = 1.f / sum;

    // ---- store: row = rB + 4quad + r; rinv transposed via shfl ----
#pragma unroll
    for (int r = 0; r < 4; ++r) {
      float rs = __shfl(rinv, 4 * quad + r);
      int row = rB + 4 * quad + r;
#pragma unroll
      for (int nt = 0; nt < 4; ++nt)
        vw[(size_t)(b * 256 + row) * 1024 + h * 64 + nt * 16 + l15] =
            f2bf(oacc[nt][r] * rs);
    }
  }
}

extern "C" void kernel_launch(void* const* d_in, const int* in_sizes, int n_in,
                              void* d_out, int out_size, void* d_ws, size_t ws_size,
                              hipStream_t stream) {
  const float* x  = (const float*)d_in[0];
  const float* Wq = (const float*)d_in[1];
  const float* bq = (const float*)d_in[2];
  const float* Wk = (const float*)d_in[3];
  const float* bk = (const float*)d_in[4];
  const float* Wv = (const float*)d_in[5];
  const float* bv = (const float*)d_in[6];
  const float* Wr = (const float*)d_in[7];
  const float* br = (const float*)d_in[8];
  const float* ub = (const float*)d_in[9];
  const float* vb = (const float*)d_in[10];
  const float* Wo = (const float*)d_in[11];
  const float* bo = (const float*)d_in[12];
  float* out = (float*)d_out;

  char* base = (char*)d_ws;
  size_t off = 0;
  auto alloc = [&](size_t bytes) {
    void* p = base + off;
    off += (bytes + 255) & ~(size_t)255;
    return p;
  };

  const size_t MAT = (size_t)4194304;  // 4096*1024
  u16*   xA    = (u16*)alloc((size_t)4352 * 1024 * 2);       // [x ; table]
  u16*   W3b   = (u16*)alloc((size_t)3328 * 1024 * 2);       // [Wq;Wv;Wk;UV;pad]
  u16*   Wob   = (u16*)alloc((size_t)1024 * 1024 * 2);
  float* b3    = (float*)alloc((size_t)3328 * 4);
  u16*   Ph    = (u16*)alloc((3 * MAT + 262144) * 2);        // Qh,VT,Kh,RPKh
  float* utb   = (float*)alloc((size_t)65536 * 4);
  float* dtb   = (float*)alloc((size_t)4096 * 4);
  u16*   vwb   = (u16*)alloc((size_t)4096 * 1024 * 2);

  u16* Qh   = Ph;
  u16* VTb  = Ph + MAT;       // transposed V: [bh][d][z]
  u16* Kh   = Ph + 2 * MAT;
  u16* RPKh = Ph + 3 * MAT;

  // pack + table + uv-fold merged: 8451 pack blocks + 128 fold blocks
  pack_k<<<dim3(8579), dim3(256), 0, stream>>>(x, Wq, Wk, Wv, Wo, bq, bk, bv,
                                               Wr, br, ub, vb,
                                               xA, W3b, Wob, b3);

  // fused Q|V^T|K + relpos-K + ut/dt projections: 4352 x 3328(pad) x 1024
  gemm256_k<<<dim3(221), dim3(512), 0, stream>>>(xA, W3b, b3, Ph,
                                                 1024, utb, dtb, 17, 13);

  // fused attention: one block per (b,h), wave-autonomous strips
  attn_k<<<dim3(256), dim3(512), 0, stream>>>(Qh, Kh, VTb, RPKh, utb, dtb, vwb);

  // output projection: 4096 x 1024 x 1024, fp32 out, 2-phase prefetch
  gemm_k<<<dim3(256), dim3(256), 0, stream>>>(vwb, Wob, bo, out,
                                              4096, 1024, 1024, 32, 8);
}

// Round 10
// 189.087 us; speedup vs baseline: 1.7612x; 1.0363x over previous
//
#include <hip/hip_runtime.h>
#include <math.h>

constexpr int kB  = 16;
constexpr int kS  = 256;
constexpr int kD  = 1024;
constexpr int kH  = 16;
constexpr float kScale = 0.125f;  // 1/sqrt(64)

using bf16x8  = __attribute__((ext_vector_type(8))) short;
using floatx4 = __attribute__((ext_vector_type(4))) float;
typedef unsigned short u16;

__device__ __forceinline__ u16 f2bf(float x) {
  union { float f; unsigned u; } v; v.f = x;
  unsigned r = v.u + 0x7fffu + ((v.u >> 16) & 1u);
  return (u16)(r >> 16);
}
__device__ __forceinline__ float bf2f(u16 h) {
  union { unsigned u; float f; } v; v.u = ((unsigned)h) << 16;
  return v.f;
}

#define MFMA16(a, b, c) __builtin_amdgcn_mfma_f32_16x16x32_bf16((a), (b), (c), 0, 0, 0)
#define GLL16(gp, lp)                                                        \
  __builtin_amdgcn_global_load_lds(                                          \
      (const __attribute__((address_space(1))) unsigned int*)(gp),           \
      (__attribute__((address_space(3))) unsigned int*)(lp), 16, 0, 0)

// ------- pack + table + uv-fold (merged): blocks <8451 pack, >=8451 fold -------
__global__ __launch_bounds__(256) void pack_k(
    const float* __restrict__ x, const float* __restrict__ Wq,
    const float* __restrict__ Wk, const float* __restrict__ Wv,
    const float* __restrict__ Wo,
    const float* __restrict__ bq, const float* __restrict__ bk,
    const float* __restrict__ bv,
    const float* __restrict__ Wr, const float* __restrict__ br,
    const float* __restrict__ ub, const float* __restrict__ vb,
    u16* __restrict__ xA, u16* __restrict__ W3b, u16* __restrict__ Wob,
    float* __restrict__ b3) {
  if (blockIdx.x >= 8451) {
    // ---- rank-16 fold of Wr with u/v: W3b rows 3072..3103, b3 tail ----
    int gid = (blockIdx.x - 8451) * 256 + threadIdx.x;  // 32768
    int j = gid >> 10, c = gid & 1023;
    int h = j & 15;
    const float* bvec = (j < 16 ? ub : vb) + h * 64;
    const float* wcol = Wr + (size_t)(h * 64) * 1024 + c;
    float a = 0.f;
#pragma unroll
    for (int d = 0; d < 64; ++d) a += bvec[d] * wcol[(size_t)d * 1024];
    W3b[(size_t)(3072 + j) * 1024 + c] = f2bf(a);
    if (gid < 128) {
      float s = 0.f;
      if (gid < 32) {
        const float* bv2 = (gid < 16 ? ub : vb) + (gid & 15) * 64;
        const float* brp = br + (gid & 15) * 64;
        for (int d = 0; d < 64; ++d) s += bv2[d] * brp[d];
      }
      b3[3072 + gid] = s;
    }
    return;
  }
  size_t i = ((size_t)blockIdx.x * 256 + threadIdx.x) * 4;
  const size_t NX = (size_t)4194304, NW = (size_t)1048576;
  const size_t BEND = NX + 4 * NW + 3072;
  const float* src;
  u16* dst;
  size_t o;
  if (i < NX) {
    src = x; dst = xA; o = i;
  } else if (i < NX + 3 * NW) {
    size_t j = i - NX;
    int sel = (int)(j >> 20);
    o = j & (NW - 1);
    src = sel == 0 ? Wq : sel == 1 ? Wv : Wk;
    dst = W3b + (size_t)sel * NW;
  } else if (i < NX + 4 * NW) {
    o = i - NX - 3 * NW;
    src = Wo; dst = Wob;
  } else if (i < BEND) {
    size_t j = i - NX - 4 * NW;
    int sel = (int)(j >> 10);
    o = j & 1023;
    src = sel == 0 ? bq : sel == 1 ? bv : bk;
    *reinterpret_cast<float4*>(b3 + j) = *reinterpret_cast<const float4*>(src + o);
    return;
  } else if (i < BEND + 262144) {
    // sinusoid table rows p in [0,256), pos = p-255 -> xA rows 4096..4351
    size_t j = i - BEND;
    int p = (int)(j >> 10);
    int ibase = (int)(j & 1023);
    ushort4 r;
    u16* rr = (u16*)&r;
#pragma unroll
    for (int c = 0; c < 4; ++c) {
      int idx = ibase + c;
      float ex = (float)(2 * (idx / 2)) * (1.0f / 1024.0f);
      float scale = exp2f(ex * -13.287712379549449f);  // 10000^-ex
      float angle = (float)(p - 255) * scale;
      rr[c] = f2bf((idx & 1) ? cosf(angle) : sinf(angle));
    }
    *reinterpret_cast<ushort4*>(xA + NX + j) = r;
    return;
  } else {
    return;
  }
  float4 v = *reinterpret_cast<const float4*>(src + o);
  ushort4 r;
  r.x = f2bf(v.x); r.y = f2bf(v.y); r.z = f2bf(v.z); r.w = f2bf(v.w);
  *reinterpret_cast<ushort4*>(dst + o) = r;
}

// ---------------- out-proj 128x128 bf16 MFMA GEMM, 2-phase prefetch ----------
__global__ __launch_bounds__(256) void gemm_k(
    const u16* __restrict__ A, const u16* __restrict__ W,
    const float* __restrict__ bias, float* __restrict__ Cv,
    int M, int N, int K, int mTiles, int nTiles) {
  const int xcd = blockIdx.x & 7;
  const int li  = blockIdx.x >> 3;
  const int r0   = (xcd * mTiles) >> 3;
  const int rcnt = (((xcd + 1) * mTiles) >> 3) - r0;
  if (li >= rcnt * nTiles) return;   // uniform early-out (padded grid)
  const int bm = (r0 + li % rcnt) * 128;
  const int bn = (li / rcnt) * 128;

  __shared__ u16 Alds[2][128 * 64];
  __shared__ u16 Blds[2][128 * 64];
  const int t = threadIdx.x, w = t >> 6, l = t & 63;
  const int l15 = l & 15, quad = l >> 4;
  const int wm = w >> 1, wn = w & 1;
  const int lrow8 = l >> 3;
  const int kslot = l & 7;
  const int NT = K >> 6;

  floatx4 acc[4][4] = {};

  auto stage = [&](int kt) {
    const int buf = kt & 1, k0 = kt << 6;
#pragma unroll
    for (int sg = 0; sg < 4; ++sg) {
      int mrow = sg * 32 + w * 8 + lrow8;
      int gk = (kslot ^ (mrow & 7)) << 3;
      GLL16(A + (size_t)(bm + mrow) * K + k0 + gk, Alds[buf] + (sg * 32 + w * 8) * 64);
      GLL16(W + (size_t)(bn + mrow) * K + k0 + gk, Blds[buf] + (sg * 32 + w * 8) * 64);
    }
  };

  stage(0);
  asm volatile("s_waitcnt vmcnt(0)" ::: "memory");
  __syncthreads();

  for (int kt = 0; kt < NT; ++kt) {
    if (kt + 1 < NT) stage(kt + 1);
    const u16* AL = Alds[kt & 1];
    const u16* BL = Blds[kt & 1];
#pragma unroll
    for (int c = 0; c < 2; ++c) {
      bf16x8 af[4], bf[4];
#pragma unroll
      for (int mi = 0; mi < 4; ++mi) {
        int am = wm * 64 + mi * 16 + l15;
        af[mi] = *(const bf16x8*)(AL + am * 64 + (((c * 4 + quad) ^ (am & 7)) << 3));
      }
#pragma unroll
      for (int ni = 0; ni < 4; ++ni) {
        int an = wn * 64 + ni * 16 + l15;
        bf[ni] = *(const bf16x8*)(BL + an * 64 + (((c * 4 + quad) ^ (an & 7)) << 3));
      }
#pragma unroll
      for (int mi = 0; mi < 4; ++mi)
#pragma unroll
        for (int ni = 0; ni < 4; ++ni)
          acc[mi][ni] = MFMA16(af[mi], bf[ni], acc[mi][ni]);
    }
    asm volatile("s_waitcnt vmcnt(0)" ::: "memory");
    __syncthreads();
  }

#pragma unroll
  for (int ni = 0; ni < 4; ++ni) {
    int col = bn + wn * 64 + ni * 16 + l15;
    float bv = bias[col];
#pragma unroll
    for (int mi = 0; mi < 4; ++mi) {
      int mrow = bm + wm * 64 + mi * 16 + quad * 4;
#pragma unroll
      for (int r = 0; r < 4; ++r) {
        Cv[(size_t)(mrow + r) * N + col] = acc[mi][ni][r] + bv;
      }
    }
  }
}

// -------- fused QVK 128x128 bf16 GEMM, 2-phase prefetch, 2 blocks/CU ---------
// Round-10 change: replaces the 256^2 8-phase kernel. Mechanism: 64 KB LDS ->
// 2 co-resident blocks/CU (m114/m97 cross-block overlap fills barrier/wait
// stalls; 221-block 256^2 config had 1 block/CU + 35 idle CUs). Main loop =
// the round-9-verified out-proj skeleton. Epilogue = multi-tensor (Q/K
// head-major, VT transposed, utb/dtb) via fp32 LDS bounce (64 KB, full tile);
// XOR keys identical family to the verified 256^2 epilogue (writer 2-way
// free; reader pattern == measured-clean gemm256 reader; VT (l^key)%32
// bijective -> free).
__global__ __launch_bounds__(256) void gemmqvk_k(
    const u16* __restrict__ A, const u16* __restrict__ W,
    const float* __restrict__ bias, u16* __restrict__ Cv,
    int K, float* __restrict__ utb, float* __restrict__ dtb,
    int mTiles, int nTiles) {
  // bijective XCD swizzle (m204)
  const int nwg = mTiles * nTiles;
  const int qq = nwg >> 3, rr8 = nwg & 7;
  const int xcd = blockIdx.x & 7;
  const int wgid = (xcd < rr8 ? xcd * (qq + 1) : rr8 * (qq + 1) + (xcd - rr8) * qq)
                   + (blockIdx.x >> 3);
  const int bm = (wgid / nTiles) * 128;
  const int bn = (wgid % nTiles) * 128;

  __shared__ u16 lds[32768];   // 64 KB: [buf:2][A 128x64 | B 128x64]

  const int t = threadIdx.x, w = t >> 6, l = t & 63;
  const int l15 = l & 15, quad = l >> 4;
  const int wm = w >> 1, wn = w & 1;
  const int lrow8 = l >> 3;
  const int kslot = l & 7;
  const int NT = K >> 6;

  floatx4 acc[4][4] = {};

  auto stage = [&](int kt) {
    const int k0 = kt << 6;
    u16* base = lds + (kt & 1) * 16384;
#pragma unroll
    for (int sg = 0; sg < 4; ++sg) {
      int mrow = sg * 32 + w * 8 + lrow8;
      int gk = (kslot ^ (mrow & 7)) << 3;
      GLL16(A + (size_t)(bm + mrow) * K + k0 + gk, base + (sg * 32 + w * 8) * 64);
      GLL16(W + (size_t)(bn + mrow) * K + k0 + gk, base + 8192 + (sg * 32 + w * 8) * 64);
    }
  };

  stage(0);
  asm volatile("s_waitcnt vmcnt(0)" ::: "memory");
  __syncthreads();

  for (int kt = 0; kt < NT; ++kt) {
    if (kt + 1 < NT) stage(kt + 1);
    const u16* AL = lds + (kt & 1) * 16384;
    const u16* BL = AL + 8192;
#pragma unroll
    for (int c = 0; c < 2; ++c) {
      bf16x8 af[4], bf[4];
#pragma unroll
      for (int mi = 0; mi < 4; ++mi) {
        int am = wm * 64 + mi * 16 + l15;
        af[mi] = *(const bf16x8*)(AL + am * 64 + (((c * 4 + quad) ^ (am & 7)) << 3));
      }
#pragma unroll
      for (int ni = 0; ni < 4; ++ni) {
        int an = wn * 64 + ni * 16 + l15;
        bf[ni] = *(const bf16x8*)(BL + an * 64 + (((c * 4 + quad) ^ (an & 7)) << 3));
      }
#pragma unroll
      for (int mi = 0; mi < 4; ++mi)
#pragma unroll
        for (int ni = 0; ni < 4; ++ni)
          acc[mi][ni] = MFMA16(af[mi], bf[ni], acc[mi][ni]);
    }
    asm volatile("s_waitcnt vmcnt(0)" ::: "memory");
    __syncthreads();
  }

  // ---- epilogue: fp32 LDS bounce (full 128x128 tile) -> multi-tensor stores
  float* fl = (float*)lds;   // 128 x 128 fp32 = 64 KB
#pragma unroll
  for (int ni = 0; ni < 4; ++ni) {
    float bv = bias[bn + wn * 64 + ni * 16 + l15];
#pragma unroll
    for (int mi = 0; mi < 4; ++mi) {
#pragma unroll
      for (int r = 0; r < 4; ++r) {
        int lr = wm * 64 + mi * 16 + quad * 4 + r;
        int c  = wn * 64 + ni * 16 + l15;
        int key = ((r ^ quad) & 3) << 4;
        fl[lr * 128 + (c ^ key)] = acc[mi][ni][r] + bv;
      }
    }
  }
  __syncthreads();

  u16* VTp = Cv + (size_t)4194304;   // matsel==1 slot, transposed layout
  if (bn >= 1024 && bn < 2048) {
    // V tile: emit transposed VT[bh][d][z]; bias already in fl.
    if (bm < 4096) {
      int bb = bm >> 8;
      int zb = bm & 128;               // 0 or 128 within the (b,h) block
      int c = (w & 1) * 64 + l;        // lane owns one column 0..127
      int rbase = (w >> 1) * 64;       // rows 0-63 / 64-127
      int col = bn + c;
      int hh2 = (col >> 6) & 15;
      u16* vpb = VTp + ((size_t)((bb << 4) + hh2) * 64 + (col & 63)) * 256 +
                 zb + rbase;
#pragma unroll 1
      for (int pp = 0; pp < 8; ++pp) {
        int rb = rbase + pp * 8;
        u16 hv[8];
#pragma unroll
        for (int e = 0; e < 8; ++e) {
          int lr = rb + e;
          int key = ((lr & 3) ^ ((lr >> 2) & 3)) << 4;
          hv[e] = f2bf(fl[lr * 128 + (c ^ key)]);
        }
        *(ushort4*)(vpb + pp * 8) = *(ushort4*)&hv[0];
        *(ushort4*)(vpb + pp * 8 + 4) = *(ushort4*)&hv[4];
      }
    }
  } else {
    // wave w owns rows w*32 .. w*32+31
#pragma unroll 1
    for (int cc = 0; cc < 2; ++cc) {
      int col0 = bn + cc * 64;
#pragma unroll
      for (int rr = 0; rr < 8; ++rr) {
        int lr = w * 32 + rr * 4 + quad;
        int key = ((rr ^ quad) & 3) << 4;
        float4 v = *(const float4*)&fl[lr * 128 + ((cc * 64 + (l15 << 2)) ^ key)];
        int grow = bm + lr;
        if (col0 < 3072) {
          ushort4 hvv;
          hvv.x = f2bf(v.x); hvv.y = f2bf(v.y); hvv.z = f2bf(v.z); hvv.w = f2bf(v.w);
          int matsel = col0 >> 10;       // 0=Q, 2=K (V handled above)
          int hh2 = (col0 >> 6) & 15;
          if (grow < 4096) {
            int bb = grow >> 8, ss = grow & 255;
            *(ushort4*)(Cv + (size_t)matsel * 4194304 +
                        ((size_t)(((bb << 4) + hh2) << 8) + ss) * 64 + (l15 << 2)) = hvv;
          } else if (matsel == 2) {      // table @ Wk^T -> RPKh
            int pp = grow - 4096;
            *(ushort4*)(Cv + (size_t)3 * 4194304 +
                        ((size_t)((hh2 << 8) + pp)) * 64 + (l15 << 2)) = hvv;
          }
        } else if (col0 < 3104) {        // cols 3072..3135 chunk: utb/dtb
#pragma unroll
          for (int e = 0; e < 4; ++e) {
            int col = col0 + (l15 << 2) + e;
            float vv = e == 0 ? v.x : e == 1 ? v.y : e == 2 ? v.z : v.w;
            if (col < 3088) {
              if (grow < 4096)
                utb[((grow >> 8) * 16 + (col - 3072)) * 256 + (grow & 255)] = vv;
            } else if (col < 3104) {
              if (grow >= 4096)
                dtb[(col - 3088) * 256 + (grow - 4096)] = vv;
            }
          }
        }
        // col0 >= 3136 (N-pad): discarded
      }
    }
  }
}

// ---------------- fused attention v4: wave-autonomous, zero main-loop barriers ----
// (unchanged — verified)
__global__ __launch_bounds__(512, 2) void attn_k(
    const u16* __restrict__ Qh, const u16* __restrict__ Kh,
    const u16* __restrict__ VT, const u16* __restrict__ RPKh,
    const float* __restrict__ ut, const float* __restrict__ dt,
    u16* __restrict__ vw) {
  __shared__ float ScW[8][16 * 260];   // 133 KB wave-private score tiles
  __shared__ float Ut[256], Dt[256];

  const int bh = blockIdx.x;           // b*16 + h
  const int h = bh & 15;
  const int b = bh >> 4;
  const size_t bh256 = (size_t)bh << 8;

  const int t = threadIdx.x, w = t >> 6, l = t & 63;
  const int l15 = l & 15, quad = l >> 4;

  if (t < 256) Ut[t] = ut[bh256 + t];
  else         Dt[t - 256] = dt[((size_t)h << 8) + (t - 256)];
  __syncthreads();

  float* scw = &ScW[w][0];

#pragma unroll 1
  for (int sidx = 0; sidx < 2; ++sidx) {
    const int s = sidx ? (15 - w) : w;   // wave-uniform strip index 0..15
    const int rB = s << 4;               // absolute base row

    // strip-head loads: qa, K tile 0, RP task 0
    bf16x8 qa0, qa1;
    {
      const u16* qp = Qh + (bh256 + rB + l15) * 64 + quad * 8;
      qa0 = *(const bf16x8*)qp;
      qa1 = *(const bf16x8*)(qp + 32);
    }
    bf16x8 kA0, kA1, kB0, kB1, rA0, rA1, rB0, rB1;
    {
      const u16* kp = Kh + (bh256 + l15) * 64 + quad * 8;
      kA0 = *(const bf16x8*)kp;
      kA1 = *(const bf16x8*)(kp + 32);
      const u16* rp = RPKh + (((size_t)h << 8) + 240 - rB + l15) * 64 + quad * 8;
      rA0 = *(const bf16x8*)rp;
      rA1 = *(const bf16x8*)(rp + 32);
    }

    // ---- interleaved QK(j) / QR(j), 1-deep parity prefetch ----
#pragma unroll
    for (int j = 0; j < 16; ++j) {
      if (j > s) break;
      if (j + 1 <= s) {
        const u16* kp = Kh + (bh256 + ((j + 1) << 4) + l15) * 64 + quad * 8;
        const u16* rp = RPKh + (((size_t)h << 8) + 240 - rB + ((j + 1) << 4) + l15) * 64 + quad * 8;
        if ((j + 1) & 1) {
          kB0 = *(const bf16x8*)kp; kB1 = *(const bf16x8*)(kp + 32);
          rB0 = *(const bf16x8*)rp; rB1 = *(const bf16x8*)(rp + 32);
        } else {
          kA0 = *(const bf16x8*)kp; kA1 = *(const bf16x8*)(kp + 32);
          rA0 = *(const bf16x8*)rp; rA1 = *(const bf16x8*)(rp + 32);
        }
      }
      bf16x8 k0 = (j & 1) ? kB0 : kA0;   // j compile-time -> static select
      bf16x8 k1 = (j & 1) ? kB1 : kA1;
      bf16x8 r0 = (j & 1) ? rB0 : rA0;
      bf16x8 r1 = (j & 1) ? rB1 : rA1;
      // QK(j): C[row=4q+r][z=16j+l15]
      {
        floatx4 acc = {};
        acc = MFMA16(qa0, k0, acc);
        acc = MFMA16(qa1, k1, acc);
        float u = Ut[(j << 4) + l15];
#pragma unroll
        for (int r = 0; r < 4; ++r)
          scw[(4 * quad + r) * 260 + (j << 4) + l15] = acc[r] + u;
      }
      // QR(j): += at z = 16j + l15 + 4quad + r - 15
      {
        floatx4 acc = {};
        acc = MFMA16(qa0, r0, acc);
        acc = MFMA16(qa1, r1, acc);
        float dv = Dt[240 - rB + (j << 4) + l15];
#pragma unroll
        for (int r = 0; r < 4; ++r) {
          int z = (j << 4) + l15 + 4 * quad + r - 15;
          if (z >= 0)
            scw[(4 * quad + r) * 260 + z] += acc[r] + dv;
        }
      }
    }

    // ---- softmax pass 1: masked max (lane owns row l15) ----
    const int kcmax = s >> 1;
    const int Rabs = rB + l15;           // causal bound z <= Rabs
    float m = -1e30f;
#pragma unroll
    for (int kc = 0; kc < 8; ++kc) {
      if (kc > kcmax) break;
      const float* sp = scw + l15 * 260 + kc * 32 + quad * 8;
      floatx4 v0 = *(const floatx4*)sp;
      floatx4 v1 = *(const floatx4*)(sp + 4);
#pragma unroll
      for (int e = 0; e < 4; ++e) {
        int z = kc * 32 + quad * 8 + e;
        if (z <= Rabs) m = fmaxf(m, v0[e]);
        if (z + 4 <= Rabs) m = fmaxf(m, v1[e]);
      }
    }
    m = fmaxf(m, __shfl_xor(m, 16));
    m = fmaxf(m, __shfl_xor(m, 32));
    m *= kScale;

    // ---- pass 2: exp + PV (V^T fragments from global, 1-deep prefetch) ----
    floatx4 oacc[4] = {};
    float sum = 0.f;
    bf16x8 vA[4], vB[4];
    {
      const u16* vp = VT + ((size_t)bh * 64 + l15) * 256 + quad * 8;
#pragma unroll
      for (int nt = 0; nt < 4; ++nt)
        vA[nt] = *(const bf16x8*)(vp + (size_t)nt * 16 * 256);
    }
#pragma unroll
    for (int kc = 0; kc < 8; ++kc) {
      if (kc > kcmax) break;
      if (kc + 1 <= kcmax) {
        const u16* vp = VT + ((size_t)bh * 64 + l15) * 256 + (kc + 1) * 32 + quad * 8;
        if ((kc + 1) & 1) {
#pragma unroll
          for (int nt = 0; nt < 4; ++nt)
            vB[nt] = *(const bf16x8*)(vp + (size_t)nt * 16 * 256);
        } else {
#pragma unroll
          for (int nt = 0; nt < 4; ++nt)
            vA[nt] = *(const bf16x8*)(vp + (size_t)nt * 16 * 256);
        }
      }
      const float* sp = scw + l15 * 260 + kc * 32 + quad * 8;
      floatx4 v0 = *(const floatx4*)sp;
      floatx4 v1 = *(const floatx4*)(sp + 4);
      bf16x8 pa;
#pragma unroll
      for (int e = 0; e < 4; ++e) {
        int z = kc * 32 + quad * 8 + e;
        float p0 = (z <= Rabs) ? __expf(v0[e] * kScale - m) : 0.f;
        float p1 = (z + 4 <= Rabs) ? __expf(v1[e] * kScale - m) : 0.f;
        sum += p0 + p1;
        pa[e] = (short)f2bf(p0);
        pa[e + 4] = (short)f2bf(p1);
      }
#pragma unroll
      for (int nt = 0; nt < 4; ++nt)
        oacc[nt] = MFMA16(pa, (kc & 1) ? vB[nt] : vA[nt], oacc[nt]);
    }
    sum += __shfl_xor(sum, 16);
    sum += __shfl_xor(sum, 32);
    float rinv = 1.f / sum;

    // ---- store: row = rB + 4quad + r; rinv transposed via shfl ----
#pragma unroll
    for (int r = 0; r < 4; ++r) {
      float rs = __shfl(rinv, 4 * quad + r);
      int row = rB + 4 * quad + r;
#pragma unroll
      for (int nt = 0; nt < 4; ++nt)
        vw[(size_t)(b * 256 + row) * 1024 + h * 64 + nt * 16 + l15] =
            f2bf(oacc[nt][r] * rs);
    }
  }
}

extern "C" void kernel_launch(void* const* d_in, const int* in_sizes, int n_in,
                              void* d_out, int out_size, void* d_ws, size_t ws_size,
                              hipStream_t stream) {
  const float* x  = (const float*)d_in[0];
  const float* Wq = (const float*)d_in[1];
  const float* bq = (const float*)d_in[2];
  const float* Wk = (const float*)d_in[3];
  const float* bk = (const float*)d_in[4];
  const float* Wv = (const float*)d_in[5];
  const float* bv = (const float*)d_in[6];
  const float* Wr = (const float*)d_in[7];
  const float* br = (const float*)d_in[8];
  const float* ub = (const float*)d_in[9];
  const float* vb = (const float*)d_in[10];
  const float* Wo = (const float*)d_in[11];
  const float* bo = (const float*)d_in[12];
  float* out = (float*)d_out;

  char* base = (char*)d_ws;
  size_t off = 0;
  auto alloc = [&](size_t bytes) {
    void* p = base + off;
    off += (bytes + 255) & ~(size_t)255;
    return p;
  };

  const size_t MAT = (size_t)4194304;  // 4096*1024
  u16*   xA    = (u16*)alloc((size_t)4352 * 1024 * 2);       // [x ; table]
  u16*   W3b   = (u16*)alloc((size_t)3328 * 1024 * 2);       // [Wq;Wv;Wk;UV;pad]
  u16*   Wob   = (u16*)alloc((size_t)1024 * 1024 * 2);
  float* b3    = (float*)alloc((size_t)3328 * 4);
  u16*   Ph    = (u16*)alloc((3 * MAT + 262144) * 2);        // Qh,VT,Kh,RPKh
  float* utb   = (float*)alloc((size_t)65536 * 4);
  float* dtb   = (float*)alloc((size_t)4096 * 4);
  u16*   vwb   = (u16*)alloc((size_t)4096 * 1024 * 2);

  u16* Qh   = Ph;
  u16* VTb  = Ph + MAT;       // transposed V: [bh][d][z]
  u16* Kh   = Ph + 2 * MAT;
  u16* RPKh = Ph + 3 * MAT;

  // pack + table + uv-fold merged: 8451 pack blocks + 128 fold blocks
  pack_k<<<dim3(8579), dim3(256), 0, stream>>>(x, Wq, Wk, Wv, Wo, bq, bk, bv,
                                               Wr, br, ub, vb,
                                               xA, W3b, Wob, b3);

  // fused Q|V^T|K + relpos-K + ut/dt projections: 4352 x 3328(pad) x 1024
  // 128^2 tiles: mTiles=34, nTiles=26 -> 884 blocks, 2 blocks/CU co-resident
  gemmqvk_k<<<dim3(884), dim3(256), 0, stream>>>(xA, W3b, b3, Ph,
                                                 1024, utb, dtb, 34, 26);

  // fused attention: one block per (b,h), wave-autonomous strips
  attn_k<<<dim3(256), dim3(512), 0, stream>>>(Qh, Kh, VTb, RPKh, utb, dtb, vwb);

  // output projection: 4096 x 1024 x 1024, fp32 out, 2-phase prefetch
  gemm_k<<<dim3(256), dim3(256), 0, stream>>>(vwb, Wob, bo, out,
                                              4096, 1024, 1024, 32, 8);
}

// Round 11
// 187.355 us; speedup vs baseline: 1.7775x; 1.0092x over previous
//
#include <hip/hip_runtime.h>
#include <math.h>

constexpr int kB  = 16;
constexpr int kS  = 256;
constexpr int kD  = 1024;
constexpr int kH  = 16;
constexpr float kScale = 0.125f;  // 1/sqrt(64)

using bf16x8  = __attribute__((ext_vector_type(8))) short;
using floatx4 = __attribute__((ext_vector_type(4))) float;
typedef unsigned short u16;

__device__ __forceinline__ u16 f2bf(float x) {
  union { float f; unsigned u; } v; v.f = x;
  unsigned r = v.u + 0x7fffu + ((v.u >> 16) & 1u);
  return (u16)(r >> 16);
}
__device__ __forceinline__ float bf2f(u16 h) {
  union { unsigned u; float f; } v; v.u = ((unsigned)h) << 16;
  return v.f;
}

#define MFMA16(a, b, c) __builtin_amdgcn_mfma_f32_16x16x32_bf16((a), (b), (c), 0, 0, 0)
#define GLL16(gp, lp)                                                        \
  __builtin_amdgcn_global_load_lds(                                          \
      (const __attribute__((address_space(1))) unsigned int*)(gp),           \
      (__attribute__((address_space(3))) unsigned int*)(lp), 16, 0, 0)

// ------- pack + table + uv-fold (merged): blocks <8451 pack, >=8451 fold -------
__global__ __launch_bounds__(256) void pack_k(
    const float* __restrict__ x, const float* __restrict__ Wq,
    const float* __restrict__ Wk, const float* __restrict__ Wv,
    const float* __restrict__ Wo,
    const float* __restrict__ bq, const float* __restrict__ bk,
    const float* __restrict__ bv,
    const float* __restrict__ Wr, const float* __restrict__ br,
    const float* __restrict__ ub, const float* __restrict__ vb,
    u16* __restrict__ xA, u16* __restrict__ W3b, u16* __restrict__ Wob,
    float* __restrict__ b3) {
  if (blockIdx.x >= 8451) {
    // ---- rank-16 fold of Wr with u/v: W3b rows 3072..3103, b3 tail ----
    int gid = (blockIdx.x - 8451) * 256 + threadIdx.x;  // 32768
    int j = gid >> 10, c = gid & 1023;
    int h = j & 15;
    const float* bvec = (j < 16 ? ub : vb) + h * 64;
    const float* wcol = Wr + (size_t)(h * 64) * 1024 + c;
    float a = 0.f;
#pragma unroll
    for (int d = 0; d < 64; ++d) a += bvec[d] * wcol[(size_t)d * 1024];
    W3b[(size_t)(3072 + j) * 1024 + c] = f2bf(a);
    if (gid < 128) {
      float s = 0.f;
      if (gid < 32) {
        const float* bv2 = (gid < 16 ? ub : vb) + (gid & 15) * 64;
        const float* brp = br + (gid & 15) * 64;
        for (int d = 0; d < 64; ++d) s += bv2[d] * brp[d];
      }
      b3[3072 + gid] = s;
    }
    return;
  }
  size_t i = ((size_t)blockIdx.x * 256 + threadIdx.x) * 4;
  const size_t NX = (size_t)4194304, NW = (size_t)1048576;
  const size_t BEND = NX + 4 * NW + 3072;
  const float* src;
  u16* dst;
  size_t o;
  if (i < NX) {
    src = x; dst = xA; o = i;
  } else if (i < NX + 3 * NW) {
    size_t j = i - NX;
    int sel = (int)(j >> 20);
    o = j & (NW - 1);
    src = sel == 0 ? Wq : sel == 1 ? Wv : Wk;
    dst = W3b + (size_t)sel * NW;
  } else if (i < NX + 4 * NW) {
    o = i - NX - 3 * NW;
    src = Wo; dst = Wob;
  } else if (i < BEND) {
    size_t j = i - NX - 4 * NW;
    int sel = (int)(j >> 10);
    o = j & 1023;
    src = sel == 0 ? bq : sel == 1 ? bv : bk;
    *reinterpret_cast<float4*>(b3 + j) = *reinterpret_cast<const float4*>(src + o);
    return;
  } else if (i < BEND + 262144) {
    // sinusoid table rows p in [0,256), pos = p-255 -> xA rows 4096..4351
    size_t j = i - BEND;
    int p = (int)(j >> 10);
    int ibase = (int)(j & 1023);
    ushort4 r;
    u16* rr = (u16*)&r;
#pragma unroll
    for (int c = 0; c < 4; ++c) {
      int idx = ibase + c;
      float ex = (float)(2 * (idx / 2)) * (1.0f / 1024.0f);
      float scale = exp2f(ex * -13.287712379549449f);  // 10000^-ex
      float angle = (float)(p - 255) * scale;
      rr[c] = f2bf((idx & 1) ? cosf(angle) : sinf(angle));
    }
    *reinterpret_cast<ushort4*>(xA + NX + j) = r;
    return;
  } else {
    return;
  }
  float4 v = *reinterpret_cast<const float4*>(src + o);
  ushort4 r;
  r.x = f2bf(v.x); r.y = f2bf(v.y); r.z = f2bf(v.z); r.w = f2bf(v.w);
  *reinterpret_cast<ushort4*>(dst + o) = r;
}

// -------- out-proj 128x128 bf16 MFMA GEMM, 3-buffer depth-2 pipeline ---------
// Grid = 256 tiles = 1 block/CU (co-residency impossible), so latency must be
// hidden in-block: 3 LDS buffers (96 KB), stage(kt+3) issued after the
// post-compute barrier of iter kt, counted vmcnt at loop head:
//   at iter-kt head, outstanding = stages kt+1,kt+2 (16 loads) -> vmcnt(16)
//   proves stage(kt) resident; edges degrade 16->8->0.
// Stage->use distance = 2 full iterations (> HBM latency).
__global__ __launch_bounds__(256) void gemm_k(
    const u16* __restrict__ A, const u16* __restrict__ W,
    const float* __restrict__ bias, float* __restrict__ Cv,
    int M, int N, int K, int mTiles, int nTiles) {
  const int xcd = blockIdx.x & 7;
  const int li  = blockIdx.x >> 3;
  const int r0   = (xcd * mTiles) >> 3;
  const int rcnt = (((xcd + 1) * mTiles) >> 3) - r0;
  if (li >= rcnt * nTiles) return;   // uniform early-out (padded grid)
  const int bm = (r0 + li % rcnt) * 128;
  const int bn = (li / rcnt) * 128;

  __shared__ u16 Alds[3][128 * 64];
  __shared__ u16 Blds[3][128 * 64];
  const int t = threadIdx.x, w = t >> 6, l = t & 63;
  const int l15 = l & 15, quad = l >> 4;
  const int wm = w >> 1, wn = w & 1;
  const int lrow8 = l >> 3;
  const int kslot = l & 7;
  const int NT = K >> 6;

  floatx4 acc[4][4] = {};

  auto stage = [&](int kt) {
    const int buf = kt % 3, k0 = kt << 6;
#pragma unroll
    for (int sg = 0; sg < 4; ++sg) {
      int mrow = sg * 32 + w * 8 + lrow8;
      int gk = (kslot ^ (mrow & 7)) << 3;
      GLL16(A + (size_t)(bm + mrow) * K + k0 + gk, Alds[buf] + (sg * 32 + w * 8) * 64);
      GLL16(W + (size_t)(bn + mrow) * K + k0 + gk, Blds[buf] + (sg * 32 + w * 8) * 64);
    }
  };

  stage(0); stage(1); stage(2);

  for (int kt = 0; kt < NT; ++kt) {
    if (kt + 2 < NT) {
      asm volatile("s_waitcnt vmcnt(16)" ::: "memory");
    } else if (kt + 1 < NT) {
      asm volatile("s_waitcnt vmcnt(8)" ::: "memory");
    } else {
      asm volatile("s_waitcnt vmcnt(0)" ::: "memory");
    }
    __builtin_amdgcn_s_barrier();
    __builtin_amdgcn_sched_barrier(0);
    const u16* AL = Alds[kt % 3];
    const u16* BL = Blds[kt % 3];
#pragma unroll
    for (int c = 0; c < 2; ++c) {
      bf16x8 af[4], bf[4];
#pragma unroll
      for (int mi = 0; mi < 4; ++mi) {
        int am = wm * 64 + mi * 16 + l15;
        af[mi] = *(const bf16x8*)(AL + am * 64 + (((c * 4 + quad) ^ (am & 7)) << 3));
      }
#pragma unroll
      for (int ni = 0; ni < 4; ++ni) {
        int an = wn * 64 + ni * 16 + l15;
        bf[ni] = *(const bf16x8*)(BL + an * 64 + (((c * 4 + quad) ^ (an & 7)) << 3));
      }
#pragma unroll
      for (int mi = 0; mi < 4; ++mi)
#pragma unroll
        for (int ni = 0; ni < 4; ++ni)
          acc[mi][ni] = MFMA16(af[mi], bf[ni], acc[mi][ni]);
    }
    __builtin_amdgcn_s_barrier();   // all reads of buf[kt%3] done (all waves)
    if (kt + 3 < NT) stage(kt + 3); // overwrites buf[kt%3] -- safe after barrier
  }

#pragma unroll
  for (int ni = 0; ni < 4; ++ni) {
    int col = bn + wn * 64 + ni * 16 + l15;
    float bv = bias[col];
#pragma unroll
    for (int mi = 0; mi < 4; ++mi) {
      int mrow = bm + wm * 64 + mi * 16 + quad * 4;
#pragma unroll
      for (int r = 0; r < 4; ++r) {
        Cv[(size_t)(mrow + r) * N + col] = acc[mi][ni][r] + bv;
      }
    }
  }
}

// -------- fused QVK 128x128 bf16 GEMM, 2 blocks/CU, counted-vmcnt 2-phase ----
// Round-11 change: T4 counted vmcnt. Wait for buf[kt] at LOOP HEAD with
// vmcnt(8) (stage(kt+1)'s 8 loads stay in flight; never drain to 0 in steady
// state); stage(kt+2) issued after the post-compute barrier -> each stage has
// a FULL iteration of flight time instead of just the compute phase.
// Count audit: at iter-kt head, issued = stages 0..kt+1; vmcnt(8) leaves only
// the newest 8 (= stage(kt+1)) -> stage(kt) proven resident. kt=NT-1: vmcnt(0).
// Restage target buf[kt&1] protected by post-compute barrier (all waves' ds
// reads complete before their MFMA consumption, hence before barrier arrival).
__global__ __launch_bounds__(256) void gemmqvk_k(
    const u16* __restrict__ A, const u16* __restrict__ W,
    const float* __restrict__ bias, u16* __restrict__ Cv,
    int K, float* __restrict__ utb, float* __restrict__ dtb,
    int mTiles, int nTiles) {
  // bijective XCD swizzle (m204)
  const int nwg = mTiles * nTiles;
  const int qq = nwg >> 3, rr8 = nwg & 7;
  const int xcd = blockIdx.x & 7;
  const int wgid = (xcd < rr8 ? xcd * (qq + 1) : rr8 * (qq + 1) + (xcd - rr8) * qq)
                   + (blockIdx.x >> 3);
  const int bm = (wgid / nTiles) * 128;
  const int bn = (wgid % nTiles) * 128;

  __shared__ u16 lds[32768];   // 64 KB: [buf:2][A 128x64 | B 128x64]

  const int t = threadIdx.x, w = t >> 6, l = t & 63;
  const int l15 = l & 15, quad = l >> 4;
  const int wm = w >> 1, wn = w & 1;
  const int lrow8 = l >> 3;
  const int kslot = l & 7;
  const int NT = K >> 6;

  floatx4 acc[4][4] = {};

  auto stage = [&](int kt) {
    const int k0 = kt << 6;
    u16* base = lds + (kt & 1) * 16384;
#pragma unroll
    for (int sg = 0; sg < 4; ++sg) {
      int mrow = sg * 32 + w * 8 + lrow8;
      int gk = (kslot ^ (mrow & 7)) << 3;
      GLL16(A + (size_t)(bm + mrow) * K + k0 + gk, base + (sg * 32 + w * 8) * 64);
      GLL16(W + (size_t)(bn + mrow) * K + k0 + gk, base + 8192 + (sg * 32 + w * 8) * 64);
    }
  };

  stage(0);
  stage(1);

  for (int kt = 0; kt < NT; ++kt) {
    if (kt + 1 < NT) {
      asm volatile("s_waitcnt vmcnt(8)" ::: "memory");
    } else {
      asm volatile("s_waitcnt vmcnt(0)" ::: "memory");
    }
    __builtin_amdgcn_s_barrier();
    __builtin_amdgcn_sched_barrier(0);
    const u16* AL = lds + (kt & 1) * 16384;
    const u16* BL = AL + 8192;
#pragma unroll
    for (int c = 0; c < 2; ++c) {
      bf16x8 af[4], bf[4];
#pragma unroll
      for (int mi = 0; mi < 4; ++mi) {
        int am = wm * 64 + mi * 16 + l15;
        af[mi] = *(const bf16x8*)(AL + am * 64 + (((c * 4 + quad) ^ (am & 7)) << 3));
      }
#pragma unroll
      for (int ni = 0; ni < 4; ++ni) {
        int an = wn * 64 + ni * 16 + l15;
        bf[ni] = *(const bf16x8*)(BL + an * 64 + (((c * 4 + quad) ^ (an & 7)) << 3));
      }
#pragma unroll
      for (int mi = 0; mi < 4; ++mi)
#pragma unroll
        for (int ni = 0; ni < 4; ++ni)
          acc[mi][ni] = MFMA16(af[mi], bf[ni], acc[mi][ni]);
    }
    __builtin_amdgcn_s_barrier();   // all reads of buf[kt&1] done (all waves)
    if (kt + 2 < NT) stage(kt + 2); // overwrites buf[kt&1] -- safe after barrier
  }

  // ---- epilogue: fp32 LDS bounce (full 128x128 tile) -> multi-tensor stores
  // (loop's final barrier = all waves done computing -> fl writes safe)
  float* fl = (float*)lds;   // 128 x 128 fp32 = 64 KB
#pragma unroll
  for (int ni = 0; ni < 4; ++ni) {
    float bv = bias[bn + wn * 64 + ni * 16 + l15];
#pragma unroll
    for (int mi = 0; mi < 4; ++mi) {
#pragma unroll
      for (int r = 0; r < 4; ++r) {
        int lr = wm * 64 + mi * 16 + quad * 4 + r;
        int c  = wn * 64 + ni * 16 + l15;
        int key = ((r ^ quad) & 3) << 4;
        fl[lr * 128 + (c ^ key)] = acc[mi][ni][r] + bv;
      }
    }
  }
  __syncthreads();

  u16* VTp = Cv + (size_t)4194304;   // matsel==1 slot, transposed layout
  if (bn >= 1024 && bn < 2048) {
    // V tile: emit transposed VT[bh][d][z]; bias already in fl.
    if (bm < 4096) {
      int bb = bm >> 8;
      int zb = bm & 128;               // 0 or 128 within the (b,h) block
      int c = (w & 1) * 64 + l;        // lane owns one column 0..127
      int rbase = (w >> 1) * 64;       // rows 0-63 / 64-127
      int col = bn + c;
      int hh2 = (col >> 6) & 15;
      u16* vpb = VTp + ((size_t)((bb << 4) + hh2) * 64 + (col & 63)) * 256 +
                 zb + rbase;
#pragma unroll 1
      for (int pp = 0; pp < 8; ++pp) {
        int rb = rbase + pp * 8;
        u16 hv[8];
#pragma unroll
        for (int e = 0; e < 8; ++e) {
          int lr = rb + e;
          int key = ((lr & 3) ^ ((lr >> 2) & 3)) << 4;
          hv[e] = f2bf(fl[lr * 128 + (c ^ key)]);
        }
        *(ushort4*)(vpb + pp * 8) = *(ushort4*)&hv[0];
        *(ushort4*)(vpb + pp * 8 + 4) = *(ushort4*)&hv[4];
      }
    }
  } else {
    // wave w owns rows w*32 .. w*32+31
#pragma unroll 1
    for (int cc = 0; cc < 2; ++cc) {
      int col0 = bn + cc * 64;
#pragma unroll
      for (int rr = 0; rr < 8; ++rr) {
        int lr = w * 32 + rr * 4 + quad;
        int key = ((rr ^ quad) & 3) << 4;
        float4 v = *(const float4*)&fl[lr * 128 + ((cc * 64 + (l15 << 2)) ^ key)];
        int grow = bm + lr;
        if (col0 < 3072) {
          ushort4 hvv;
          hvv.x = f2bf(v.x); hvv.y = f2bf(v.y); hvv.z = f2bf(v.z); hvv.w = f2bf(v.w);
          int matsel = col0 >> 10;       // 0=Q, 2=K (V handled above)
          int hh2 = (col0 >> 6) & 15;
          if (grow < 4096) {
            int bb = grow >> 8, ss = grow & 255;
            *(ushort4*)(Cv + (size_t)matsel * 4194304 +
                        ((size_t)(((bb << 4) + hh2) << 8) + ss) * 64 + (l15 << 2)) = hvv;
          } else if (matsel == 2) {      // table @ Wk^T -> RPKh
            int pp = grow - 4096;
            *(ushort4*)(Cv + (size_t)3 * 4194304 +
                        ((size_t)((hh2 << 8) + pp)) * 64 + (l15 << 2)) = hvv;
          }
        } else if (col0 < 3104) {        // cols 3072..3135 chunk: utb/dtb
#pragma unroll
          for (int e = 0; e < 4; ++e) {
            int col = col0 + (l15 << 2) + e;
            float vv = e == 0 ? v.x : e == 1 ? v.y : e == 2 ? v.z : v.w;
            if (col < 3088) {
              if (grow < 4096)
                utb[((grow >> 8) * 16 + (col - 3072)) * 256 + (grow & 255)] = vv;
            } else if (col < 3104) {
              if (grow >= 4096)
                dtb[(col - 3088) * 256 + (grow - 4096)] = vv;
            }
          }
        }
        // col0 >= 3136 (N-pad): discarded
      }
    }
  }
}

// ---------------- fused attention v4: wave-autonomous, zero main-loop barriers ----
// (unchanged — verified)
__global__ __launch_bounds__(512, 2) void attn_k(
    const u16* __restrict__ Qh, const u16* __restrict__ Kh,
    const u16* __restrict__ VT, const u16* __restrict__ RPKh,
    const float* __restrict__ ut, const float* __restrict__ dt,
    u16* __restrict__ vw) {
  __shared__ float ScW[8][16 * 260];   // 133 KB wave-private score tiles
  __shared__ float Ut[256], Dt[256];

  const int bh = blockIdx.x;           // b*16 + h
  const int h = bh & 15;
  const int b = bh >> 4;
  const size_t bh256 = (size_t)bh << 8;

  const int t = threadIdx.x, w = t >> 6, l = t & 63;
  const int l15 = l & 15, quad = l >> 4;

  if (t < 256) Ut[t] = ut[bh256 + t];
  else         Dt[t - 256] = dt[((size_t)h << 8) + (t - 256)];
  __syncthreads();

  float* scw = &ScW[w][0];

#pragma unroll 1
  for (int sidx = 0; sidx < 2; ++sidx) {
    const int s = sidx ? (15 - w) : w;   // wave-uniform strip index 0..15
    const int rB = s << 4;               // absolute base row

    // strip-head loads: qa, K tile 0, RP task 0
    bf16x8 qa0, qa1;
    {
      const u16* qp = Qh + (bh256 + rB + l15) * 64 + quad * 8;
      qa0 = *(const bf16x8*)qp;
      qa1 = *(const bf16x8*)(qp + 32);
    }
    bf16x8 kA0, kA1, kB0, kB1, rA0, rA1, rB0, rB1;
    {
      const u16* kp = Kh + (bh256 + l15) * 64 + quad * 8;
      kA0 = *(const bf16x8*)kp;
      kA1 = *(const bf16x8*)(kp + 32);
      const u16* rp = RPKh + (((size_t)h << 8) + 240 - rB + l15) * 64 + quad * 8;
      rA0 = *(const bf16x8*)rp;
      rA1 = *(const bf16x8*)(rp + 32);
    }

    // ---- interleaved QK(j) / QR(j), 1-deep parity prefetch ----
#pragma unroll
    for (int j = 0; j < 16; ++j) {
      if (j > s) break;
      if (j + 1 <= s) {
        const u16* kp = Kh + (bh256 + ((j + 1) << 4) + l15) * 64 + quad * 8;
        const u16* rp = RPKh + (((size_t)h << 8) + 240 - rB + ((j + 1) << 4) + l15) * 64 + quad * 8;
        if ((j + 1) & 1) {
          kB0 = *(const bf16x8*)kp; kB1 = *(const bf16x8*)(kp + 32);
          rB0 = *(const bf16x8*)rp; rB1 = *(const bf16x8*)(rp + 32);
        } else {
          kA0 = *(const bf16x8*)kp; kA1 = *(const bf16x8*)(kp + 32);
          rA0 = *(const bf16x8*)rp; rA1 = *(const bf16x8*)(rp + 32);
        }
      }
      bf16x8 k0 = (j & 1) ? kB0 : kA0;   // j compile-time -> static select
      bf16x8 k1 = (j & 1) ? kB1 : kA1;
      bf16x8 r0 = (j & 1) ? rB0 : rA0;
      bf16x8 r1 = (j & 1) ? rB1 : rA1;
      // QK(j): C[row=4q+r][z=16j+l15]
      {
        floatx4 acc = {};
        acc = MFMA16(qa0, k0, acc);
        acc = MFMA16(qa1, k1, acc);
        float u = Ut[(j << 4) + l15];
#pragma unroll
        for (int r = 0; r < 4; ++r)
          scw[(4 * quad + r) * 260 + (j << 4) + l15] = acc[r] + u;
      }
      // QR(j): += at z = 16j + l15 + 4quad + r - 15
      {
        floatx4 acc = {};
        acc = MFMA16(qa0, r0, acc);
        acc = MFMA16(qa1, r1, acc);
        float dv = Dt[240 - rB + (j << 4) + l15];
#pragma unroll
        for (int r = 0; r < 4; ++r) {
          int z = (j << 4) + l15 + 4 * quad + r - 15;
          if (z >= 0)
            scw[(4 * quad + r) * 260 + z] += acc[r] + dv;
        }
      }
    }

    // ---- softmax pass 1: masked max (lane owns row l15) ----
    const int kcmax = s >> 1;
    const int Rabs = rB + l15;           // causal bound z <= Rabs
    float m = -1e30f;
#pragma unroll
    for (int kc = 0; kc < 8; ++kc) {
      if (kc > kcmax) break;
      const float* sp = scw + l15 * 260 + kc * 32 + quad * 8;
      floatx4 v0 = *(const floatx4*)sp;
      floatx4 v1 = *(const floatx4*)(sp + 4);
#pragma unroll
      for (int e = 0; e < 4; ++e) {
        int z = kc * 32 + quad * 8 + e;
        if (z <= Rabs) m = fmaxf(m, v0[e]);
        if (z + 4 <= Rabs) m = fmaxf(m, v1[e]);
      }
    }
    m = fmaxf(m, __shfl_xor(m, 16));
    m = fmaxf(m, __shfl_xor(m, 32));
    m *= kScale;

    // ---- pass 2: exp + PV (V^T fragments from global, 1-deep prefetch) ----
    floatx4 oacc[4] = {};
    float sum = 0.f;
    bf16x8 vA[4], vB[4];
    {
      const u16* vp = VT + ((size_t)bh * 64 + l15) * 256 + quad * 8;
#pragma unroll
      for (int nt = 0; nt < 4; ++nt)
        vA[nt] = *(const bf16x8*)(vp + (size_t)nt * 16 * 256);
    }
#pragma unroll
    for (int kc = 0; kc < 8; ++kc) {
      if (kc > kcmax) break;
      if (kc + 1 <= kcmax) {
        const u16* vp = VT + ((size_t)bh * 64 + l15) * 256 + (kc + 1) * 32 + quad * 8;
        if ((kc + 1) & 1) {
#pragma unroll
          for (int nt = 0; nt < 4; ++nt)
            vB[nt] = *(const bf16x8*)(vp + (size_t)nt * 16 * 256);
        } else {
#pragma unroll
          for (int nt = 0; nt < 4; ++nt)
            vA[nt] = *(const bf16x8*)(vp + (size_t)nt * 16 * 256);
        }
      }
      const float* sp = scw + l15 * 260 + kc * 32 + quad * 8;
      floatx4 v0 = *(const floatx4*)sp;
      floatx4 v1 = *(const floatx4*)(sp + 4);
      bf16x8 pa;
#pragma unroll
      for (int e = 0; e < 4; ++e) {
        int z = kc * 32 + quad * 8 + e;
        float p0 = (z <= Rabs) ? __expf(v0[e] * kScale - m) : 0.f;
        float p1 = (z + 4 <= Rabs) ? __expf(v1[e] * kScale - m) : 0.f;
        sum += p0 + p1;
        pa[e] = (short)f2bf(p0);
        pa[e + 4] = (short)f2bf(p1);
      }
#pragma unroll
      for (int nt = 0; nt < 4; ++nt)
        oacc[nt] = MFMA16(pa, (kc & 1) ? vB[nt] : vA[nt], oacc[nt]);
    }
    sum += __shfl_xor(sum, 16);
    sum += __shfl_xor(sum, 32);
    float rinv = 1.f / sum;

    // ---- store: row = rB + 4quad + r; rinv transposed via shfl ----
#pragma unroll
    for (int r = 0; r < 4; ++r) {
      float rs = __shfl(rinv, 4 * quad + r);
      int row = rB + 4 * quad + r;
#pragma unroll
      for (int nt = 0; nt < 4; ++nt)
        vw[(size_t)(b * 256 + row) * 1024 + h * 64 + nt * 16 + l15] =
            f2bf(oacc[nt][r] * rs);
    }
  }
}

extern "C" void kernel_launch(void* const* d_in, const int* in_sizes, int n_in,
                              void* d_out, int out_size, void* d_ws, size_t ws_size,
                              hipStream_t stream) {
  const float* x  = (const float*)d_in[0];
  const float* Wq = (const float*)d_in[1];
  const float* bq = (const float*)d_in[2];
  const float* Wk = (const float*)d_in[3];
  const float* bk = (const float*)d_in[4];
  const float* Wv = (const float*)d_in[5];
  const float* bv = (const float*)d_in[6];
  const float* Wr = (const float*)d_in[7];
  const float* br = (const float*)d_in[8];
  const float* ub = (const float*)d_in[9];
  const float* vb = (const float*)d_in[10];
  const float* Wo = (const float*)d_in[11];
  const float* bo = (const float*)d_in[12];
  float* out = (float*)d_out;

  char* base = (char*)d_ws;
  size_t off = 0;
  auto alloc = [&](size_t bytes) {
    void* p = base + off;
    off += (bytes + 255) & ~(size_t)255;
    return p;
  };

  const size_t MAT = (size_t)4194304;  // 4096*1024
  u16*   xA    = (u16*)alloc((size_t)4352 * 1024 * 2);       // [x ; table]
  u16*   W3b   = (u16*)alloc((size_t)3328 * 1024 * 2);       // [Wq;Wv;Wk;UV;pad]
  u16*   Wob   = (u16*)alloc((size_t)1024 * 1024 * 2);
  float* b3    = (float*)alloc((size_t)3328 * 4);
  u16*   Ph    = (u16*)alloc((3 * MAT + 262144) * 2);        // Qh,VT,Kh,RPKh
  float* utb   = (float*)alloc((size_t)65536 * 4);
  float* dtb   = (float*)alloc((size_t)4096 * 4);
  u16*   vwb   = (u16*)alloc((size_t)4096 * 1024 * 2);

  u16* Qh   = Ph;
  u16* VTb  = Ph + MAT;       // transposed V: [bh][d][z]
  u16* Kh   = Ph + 2 * MAT;
  u16* RPKh = Ph + 3 * MAT;

  // pack + table + uv-fold merged: 8451 pack blocks + 128 fold blocks
  pack_k<<<dim3(8579), dim3(256), 0, stream>>>(x, Wq, Wk, Wv, Wo, bq, bk, bv,
                                               Wr, br, ub, vb,
                                               xA, W3b, Wob, b3);

  // fused Q|V^T|K + relpos-K + ut/dt projections: 4352 x 3328(pad) x 1024
  // 128^2 tiles: mTiles=34, nTiles=26 -> 884 blocks, 2 blocks/CU co-resident
  gemmqvk_k<<<dim3(884), dim3(256), 0, stream>>>(xA, W3b, b3, Ph,
                                                 1024, utb, dtb, 34, 26);

  // fused attention: one block per (b,h), wave-autonomous strips
  attn_k<<<dim3(256), dim3(512), 0, stream>>>(Qh, Kh, VTb, RPKh, utb, dtb, vwb);

  // output projection: 4096 x 1024 x 1024, fp32 out, 3-buffer depth-2 pipeline
  gemm_k<<<dim3(256), dim3(256), 0, stream>>>(vwb, Wob, bo, out,
                                              4096, 1024, 1024, 32, 8);
}